// Round 18
// baseline (463.493 us; speedup 1.0000x reference)
//
#include <hip/hip_runtime.h>
#include <hip/hip_bf16.h>
#include <hip/hip_fp16.h>
#include <math.h>

#define N_NODES 50000
#define N_EDGES 1600000
#define IN_DIM 16
#define HID 64
#define NBLK 6250          // N_EDGES / 256
#define NB1 49             // level-1 scatter buckets (dst>>10)

typedef __attribute__((ext_vector_type(8))) _Float16 half8v;
typedef __attribute__((ext_vector_type(16))) float f32x16;

union H8 { uint4 u4; half8v v; };

__device__ __forceinline__ float lrelu(float v) { return v > 0.f ? v : 0.2f * v; }

__device__ __forceinline__ float wave_reduce_sum(float v) {
    #pragma unroll
    for (int off = 32; off > 0; off >>= 1) v += __shfl_down(v, off, 64);
    return v;
}

// monotone float<->uint mapping for max-keys (exact, deterministic)
__device__ __forceinline__ unsigned fkey(float f) {
    unsigned b = __float_as_uint(f);
    return (b & 0x80000000u) ? ~b : (b | 0x80000000u);
}
__device__ __forceinline__ float funkey(unsigned k) {
    return (k & 0x80000000u) ? __uint_as_float(k & 0x7fffffffu) : __uint_as_float(~k);
}

// k_prep: block 64 = qprep (qs/qd vectors); blocks 0..63 = f16 weight transpose rows
__global__ void k_prep(const float* __restrict__ W1, const float* __restrict__ as1,
                       const float* __restrict__ ad1, float* __restrict__ qs, float* __restrict__ qd,
                       const float* __restrict__ mW2, const float* __restrict__ mW3,
                       __half* __restrict__ W2th, __half* __restrict__ W3th) {
    int t = threadIdx.x;
    if (blockIdx.x == 64) {
        if (t < 32) {
            int i = t >> 1, h = t & 1;
            float s = 0.f, d = 0.f;
            for (int c = 0; c < 64; c++) {
                float w = W1[i * 128 + h * 64 + c];
                s = fmaf(w, as1[h * 64 + c], s);
                d = fmaf(w, ad1[h * 64 + c], d);
            }
            qs[i * 2 + h] = s; qd[i * 2 + h] = d;
        }
    } else {
        int b = blockIdx.x;
        W2th[b * 64 + t] = __float2half(mW2[t * 64 + b]);
        W3th[b * 64 + t] = __float2half(mW3[t * 64 + b]);
    }
}

// k1n: alpha terms per node
__global__ void k1n(const float* __restrict__ x, const float* __restrict__ qs,
                    const float* __restrict__ qd, float* __restrict__ al_s, float* __restrict__ al_d) {
    int n = blockIdx.x * 256 + threadIdx.x;
    if (n >= N_NODES) return;
    float s0 = 0.f, s1 = 0.f, d0 = 0.f, d1 = 0.f;
    #pragma unroll
    for (int i = 0; i < IN_DIM; i++) {
        float xv = x[n * IN_DIM + i];
        s0 = fmaf(xv, qs[i * 2 + 0], s0);
        s1 = fmaf(xv, qs[i * 2 + 1], s1);
        d0 = fmaf(xv, qd[i * 2 + 0], d0);
        d1 = fmaf(xv, qd[i * 2 + 1], d1);
    }
    al_s[n * 2 + 0] = s0; al_s[n * 2 + 1] = s1;
    al_d[n * 2 + 0] = d0; al_d[n * 2 + 1] = d1;
}

#define SCAN_B 256
__global__ void k_scan2(int* __restrict__ bsum, int nblocks) {
    __shared__ int sh[SCAN_B];
    int v = (threadIdx.x < nblocks) ? bsum[threadIdx.x] : 0;
    sh[threadIdx.x] = v;
    __syncthreads();
    for (int o = 1; o < SCAN_B; o <<= 1) {
        int t = (threadIdx.x >= o) ? sh[threadIdx.x - o] : 0;
        __syncthreads();
        sh[threadIdx.x] += t;
        __syncthreads();
    }
    if (threadIdx.x < nblocks) bsum[threadIdx.x] = sh[threadIdx.x] - v;
}

__global__ void g_scan1(const int* __restrict__ in, int* __restrict__ out,
                        int* __restrict__ bsum, int n) {
    __shared__ int sh[SCAN_B];
    int gid = blockIdx.x * SCAN_B + threadIdx.x;
    int v = (gid < n) ? in[gid] : 0;
    sh[threadIdx.x] = v;
    __syncthreads();
    for (int o = 1; o < SCAN_B; o <<= 1) {
        int t = (threadIdx.x >= o) ? sh[threadIdx.x - o] : 0;
        __syncthreads();
        sh[threadIdx.x] += t;
        __syncthreads();
    }
    int incl = sh[threadIdx.x];
    if (gid < n) out[gid] = incl - v;
    if (threadIdx.x == SCAN_B - 1) bsum[blockIdx.x] = incl;
}
__global__ void g_add(int* __restrict__ out, const int* __restrict__ bsum, int n) {
    int gid = blockIdx.x * SCAN_B + threadIdx.x;
    if (gid < n) out[gid] += bsum[blockIdx.x];
}

// ---- hierarchical CSR scatter ----
__global__ __launch_bounds__(256) void s_hist1(const int* __restrict__ dst,
                                               int* __restrict__ cnt1) {
    __shared__ int c[NB1];
    if (threadIdx.x < NB1) c[threadIdx.x] = 0;
    __syncthreads();
    int e = blockIdx.x * 256 + threadIdx.x;
    atomicAdd(&c[dst[e] >> 10], 1);
    __syncthreads();
    if (threadIdx.x < NB1) cnt1[threadIdx.x * NBLK + blockIdx.x] = c[threadIdx.x];
}

__global__ __launch_bounds__(256) void s_scatter1(const int* __restrict__ src,
                                                  const int* __restrict__ dst,
                                                  const int* __restrict__ basep1,
                                                  unsigned long long* __restrict__ tmp) {
    __shared__ int c[NB1], base[NB1];
    if (threadIdx.x < NB1) c[threadIdx.x] = 0;
    __syncthreads();
    int e = blockIdx.x * 256 + threadIdx.x;
    int d = dst[e], s = src[e];
    int k = d >> 10;
    int rank = atomicAdd(&c[k], 1);
    __syncthreads();
    if (threadIdx.x < NB1) base[threadIdx.x] = basep1[threadIdx.x * NBLK + blockIdx.x];
    __syncthreads();
    unsigned long long v = ((unsigned long long)e << 32) |
                           (((unsigned)d << 16) | (unsigned)s);
    tmp[base[k] + rank] = v;
}

// k_sort2c: one block per dst-bucket. Pass A: LDS deg count + layer-1 max keys
// (self-initialized). LDS scan -> offp. Pass B: scatter to exact CSR slots AND
// write layer-1 softmax weights w12 inline. No global atomics.
__global__ __launch_bounds__(1024) void k_sort2c(const unsigned long long* __restrict__ tmp,
                                                 const int* __restrict__ basep1,
                                                 const float* __restrict__ als,
                                                 const float* __restrict__ ald,
                                                 int* __restrict__ offp,
                                                 unsigned* __restrict__ ssd,
                                                 int* __restrict__ eid,
                                                 unsigned* __restrict__ m1k,
                                                 float2* __restrict__ w12) {
    __shared__ int cnt[1024];
    __shared__ unsigned mk0[1024], mk1[1024];
    int b = blockIdx.x, t = threadIdx.x;
    int d0 = b << 10;
    int nd = N_NODES - d0; if (nd > 1024) nd = 1024;
    cnt[t] = 0;
    if (t < nd) {
        int n = d0 + t;
        mk0[t] = fkey(lrelu(als[n * 2]     + ald[n * 2]));
        mk1[t] = fkey(lrelu(als[n * 2 + 1] + ald[n * 2 + 1]));
    }
    __syncthreads();
    int ebeg = basep1[b * NBLK];
    int eend = (b == NB1 - 1) ? N_EDGES : basep1[(b + 1) * NBLK];
    for (int i = ebeg + t; i < eend; i += 1024) {
        unsigned lo = (unsigned)tmp[i];
        int s = (int)(lo & 0xffffu);
        int dl = (int)(lo >> 16) - d0;
        atomicAdd(&cnt[dl], 1);
        atomicMax(&mk0[dl], fkey(lrelu(als[s * 2]     + ald[(d0 + dl) * 2])));
        atomicMax(&mk1[dl], fkey(lrelu(als[s * 2 + 1] + ald[(d0 + dl) * 2 + 1])));
    }
    __syncthreads();
    if (t < nd) { m1k[(d0 + t) * 2] = mk0[t]; m1k[(d0 + t) * 2 + 1] = mk1[t]; }
    int v = cnt[t];
    for (int o = 1; o < 1024; o <<= 1) {
        int tv = (t >= o) ? cnt[t - o] : 0;
        __syncthreads();
        cnt[t] += tv;
        __syncthreads();
    }
    int cur = ebeg + cnt[t] - v;     // exclusive prefix -> global CSR offset
    if (t < nd) offp[d0 + t] = cur;
    if (b == NB1 - 1 && t == 0) offp[N_NODES] = N_EDGES;
    __syncthreads();
    cnt[t] = cur;
    __syncthreads();
    for (int i = ebeg + t; i < eend; i += 1024) {
        unsigned long long v64 = tmp[i];
        unsigned lo = (unsigned)v64;
        int s = (int)(lo & 0xffffu);
        int dl = (int)(lo >> 16) - d0;
        int pos = atomicAdd(&cnt[dl], 1);
        ssd[pos] = lo;
        eid[pos] = (int)(v64 >> 32);
        float e0 = lrelu(als[s * 2]     + ald[(d0 + dl) * 2]);
        float e1 = lrelu(als[s * 2 + 1] + ald[(d0 + dl) * 2 + 1]);
        w12[pos] = make_float2(__expf(e0 - funkey(mk0[dl])), __expf(e1 - funkey(mk1[dl])));
    }
}

// b_mw2: per-256-dst-tile layer-2 max + weights (fused).
__global__ __launch_bounds__(256) void b_mw2(const unsigned* __restrict__ ssd,
                                             const int* __restrict__ offp,
                                             const float* __restrict__ als,
                                             const float* __restrict__ ald,
                                             unsigned* __restrict__ m2k,
                                             float* __restrict__ w2) {
    __shared__ unsigned mk[256];
    int d0 = blockIdx.x * 256, t = threadIdx.x;
    int nd = N_NODES - d0; if (nd > 256) nd = 256;
    if (t < nd) {
        int n = d0 + t;
        mk[t] = fkey(lrelu(als[n] + ald[n]));
    }
    __syncthreads();
    int ebeg = offp[d0], eend = offp[d0 + nd];
    for (int i = ebeg + t; i < eend; i += 256) {
        unsigned v = ssd[i];
        int s = (int)(v & 0xffffu), dl = (int)(v >> 16) - d0;
        atomicMax(&mk[dl], fkey(lrelu(als[s] + ald[d0 + dl])));
    }
    __syncthreads();
    if (t < nd) m2k[d0 + t] = mk[t];
    __syncthreads();
    for (int i = ebeg + t; i < eend; i += 256) {
        unsigned v = ssd[i];
        int s = (int)(v & 0xffffu), dl = (int)(v >> 16) - d0;
        float e = lrelu(als[s] + ald[d0 + dl]);
        w2[i] = __expf(e - funkey(mk[dl]));
    }
}

// ---- stable 7-bucket partition by src>>13 (keeps dst order within bucket) ----
__global__ __launch_bounds__(256) void p_hist(const unsigned* __restrict__ ssd, int* __restrict__ cnt) {
    __shared__ int c[7];
    if (threadIdx.x < 7) c[threadIdx.x] = 0;
    __syncthreads();
    int i = blockIdx.x * 256 + threadIdx.x;
    atomicAdd(&c[(ssd[i] & 0xffff) >> 13], 1);
    __syncthreads();
    if (threadIdx.x < 7) cnt[threadIdx.x * NBLK + blockIdx.x] = c[threadIdx.x];
}

__global__ __launch_bounds__(256) void p_scatter(
    const unsigned* __restrict__ ssd, const int* __restrict__ eid,
    const int* __restrict__ basep, unsigned* __restrict__ s2sd, int* __restrict__ e2) {
    __shared__ int wcnt[4][7];
    int wid = threadIdx.x >> 6, lane = threadIdx.x & 63;
    int i = blockIdx.x * 256 + threadIdx.x;
    unsigned v = ssd[i];
    int e = eid[i];
    int k = (v & 0xffff) >> 13;
    int rank = 0;
    #pragma unroll
    for (int kk = 0; kk < 7; kk++) {
        unsigned long long m = __ballot(k == kk);
        if (k == kk) rank = __popcll(m & ((1ull << lane) - 1ull));
        if (lane == kk) wcnt[wid][kk] = __popcll(m);
    }
    __syncthreads();
    int prev = 0;
    #pragma unroll
    for (int w = 0; w < 4; w++) if (w < wid) prev += wcnt[w][k];
    int pos = basep[k * NBLK + blockIdx.x] + prev + rank;
    s2sd[pos] = v; e2[pos] = e;
}

// K3n slim: layer-1 aggregation with precomputed weights; single pass.
__global__ void k3n(const float* __restrict__ x, const float* __restrict__ als,
                    const float* __restrict__ ald, const unsigned* __restrict__ m1k,
                    const int* __restrict__ off, const unsigned* __restrict__ ssd,
                    const float2* __restrict__ w12,
                    float* __restrict__ accx, float* __restrict__ denb) {
    int wid = threadIdx.x >> 6, lane = threadIdx.x & 63;
    int half = lane >> 5, sub = lane & 31, head = sub >> 4, ch = sub & 15;
    int d = blockIdx.x * 8 + wid * 2 + half;
    if (d >= N_NODES) return;
    int beg = off[d], end = off[d + 1];
    float m = funkey(m1k[d * 2 + head]);
    float es = lrelu(als[d * 2 + head] + ald[d * 2 + head]);
    float ws = __expf(es - m);
    float den0 = ws, den1 = 0.f;
    float a0 = ws * x[d * IN_DIM + ch], a1 = 0.f;
    int i = beg;
    for (; i + 7 < end; i += 8) {
        int sv[8]; float wv[8], xv[8];
        #pragma unroll
        for (int t = 0; t < 8; t++) sv[t] = (int)(ssd[i + t] & 0xffffu);
        #pragma unroll
        for (int t = 0; t < 8; t++) {
            float2 w2v = w12[i + t];
            wv[t] = head ? w2v.y : w2v.x;
        }
        #pragma unroll
        for (int t = 0; t < 8; t++) xv[t] = x[sv[t] * IN_DIM + ch];
        den0 += wv[0]; a0 = fmaf(wv[0], xv[0], a0);
        den1 += wv[1]; a1 = fmaf(wv[1], xv[1], a1);
        den0 += wv[2]; a0 = fmaf(wv[2], xv[2], a0);
        den1 += wv[3]; a1 = fmaf(wv[3], xv[3], a1);
        den0 += wv[4]; a0 = fmaf(wv[4], xv[4], a0);
        den1 += wv[5]; a1 = fmaf(wv[5], xv[5], a1);
        den0 += wv[6]; a0 = fmaf(wv[6], xv[6], a0);
        den1 += wv[7]; a1 = fmaf(wv[7], xv[7], a1);
    }
    for (; i < end; i++) {
        int s = (int)(ssd[i] & 0xffffu);
        float2 w2v = w12[i];
        float wv = head ? w2v.y : w2v.x;
        den0 += wv; a0 = fmaf(wv, x[s * IN_DIM + ch], a0);
    }
    accx[d * 32 + sub] = a0 + a1;
    if ((sub & 15) == 0) denb[d * 2 + head] = den0 + den1;
}

// K4n: fused out1-expand then @ W2 -> h2 (f16), al_s2/al_d2. Grid-stride.
__global__ __launch_bounds__(256) void k4n(
    const float* __restrict__ accx, const float* __restrict__ denb,
    const float* __restrict__ W1, const float* __restrict__ b1,
    const float* __restrict__ W2, const float* __restrict__ as2, const float* __restrict__ ad2,
    __half* __restrict__ h2h, float* __restrict__ al_s, float* __restrict__ al_d) {
    __shared__ float W1s[16 * 128];
    __shared__ float W2s[128 * 64];
    __shared__ float st[4][160];
    for (int t = threadIdx.x; t < 16 * 128; t += 256) W1s[t] = W1[t];
    for (int t = threadIdx.x; t < 128 * 64; t += 256) W2s[t] = W2[t];
    __syncthreads();
    int wid = threadIdx.x >> 6, lane = threadIdx.x & 63;
    for (int n = blockIdx.x * 4 + wid; n < N_NODES; n += gridDim.x * 4) {
        if (lane < 32) st[wid][lane] = accx[n * 32 + lane];
        float den0 = denb[n * 2], den1 = denb[n * 2 + 1];
        float ta = 0.f, tb = 0.f;
        #pragma unroll
        for (int i = 0; i < 16; i++) {
            ta = fmaf(st[wid][i],      W1s[i * 128 + lane],      ta);
            tb = fmaf(st[wid][16 + i], W1s[i * 128 + 64 + lane], tb);
        }
        ta = fmaxf(ta / den0 + b1[lane], 0.f);
        tb = fmaxf(tb / den1 + b1[64 + lane], 0.f);
        st[wid][32 + lane] = ta;
        st[wid][96 + lane] = tb;
        float acc = 0.f;
        #pragma unroll 8
        for (int k = 0; k < 128; k++) acc = fmaf(st[wid][32 + k], W2s[k * 64 + lane], acc);
        h2h[n * 64 + lane] = __float2half(acc);
        float ps = wave_reduce_sum(acc * as2[lane]);
        float pd = wave_reduce_sum(acc * ad2[lane]);
        if (lane == 0) { al_s[n] = ps; al_d[n] = pd; }
    }
}

// K5a slim: layer-2 aggregation with precomputed weights; single pass.
__global__ __launch_bounds__(64) void k5a(
    const __half* __restrict__ h2h, const float* __restrict__ als, const float* __restrict__ ald,
    const unsigned* __restrict__ m2k, const float* __restrict__ b2,
    const int* __restrict__ off, const unsigned* __restrict__ ssd,
    const float* __restrict__ w2, float* __restrict__ out2) {
    int d = blockIdx.x;
    int lane = threadIdx.x;
    int beg = off[d], end = off[d + 1];
    float m = funkey(m2k[d]);
    float es = lrelu(als[d] + ald[d]);
    float ws = __expf(es - m);
    float den0 = ws, den1 = 0.f;
    float a0 = ws * __half2float(h2h[d * 64 + lane]), a1 = 0.f;
    int i = beg;
    for (; i + 7 < end; i += 8) {
        int sv[8]; float wv[8], vv[8];
        #pragma unroll
        for (int t = 0; t < 8; t++) sv[t] = (int)(ssd[i + t] & 0xffffu);
        #pragma unroll
        for (int t = 0; t < 8; t++) wv[t] = w2[i + t];
        #pragma unroll
        for (int t = 0; t < 8; t++) vv[t] = __half2float(h2h[sv[t] * 64 + lane]);
        den0 += wv[0]; a0 = fmaf(wv[0], vv[0], a0);
        den1 += wv[1]; a1 = fmaf(wv[1], vv[1], a1);
        den0 += wv[2]; a0 = fmaf(wv[2], vv[2], a0);
        den1 += wv[3]; a1 = fmaf(wv[3], vv[3], a1);
        den0 += wv[4]; a0 = fmaf(wv[4], vv[4], a0);
        den1 += wv[5]; a1 = fmaf(wv[5], vv[5], a1);
        den0 += wv[6]; a0 = fmaf(wv[6], vv[6], a0);
        den1 += wv[7]; a1 = fmaf(wv[7], vv[7], a1);
    }
    for (; i < end; i++) {
        int s = (int)(ssd[i] & 0xffffu);
        float wv = w2[i];
        den0 += wv; a0 = fmaf(wv, __half2float(h2h[s * 64 + lane]), a0);
    }
    out2[d * 64 + lane] = fmaxf((a0 + a1) / (den0 + den1) + b2[lane], 0.f);
}

// K5b: U/V from out2 @ mW1; stored f16. Grid-stride persistent blocks.
__global__ __launch_bounds__(256) void k5b(const float* __restrict__ out2,
                                           const float* __restrict__ mW1,
                                           const float* __restrict__ mb1,
                                           __half* __restrict__ Uh, __half* __restrict__ Vh) {
    __shared__ float Ws[128 * 64];
    __shared__ float o2s[4][64];
    for (int t = threadIdx.x; t < 128 * 64; t += 256) Ws[t] = mW1[t];
    __syncthreads();
    int wid = threadIdx.x >> 6, lane = threadIdx.x & 63;
    for (int n = blockIdx.x * 4 + wid; n < N_NODES; n += gridDim.x * 4) {
        o2s[wid][lane] = out2[n * 64 + lane];
        float au = mb1[lane], av = 0.f;
        #pragma unroll 8
        for (int k = 0; k < 64; k++) {
            float ov = o2s[wid][k];
            au = fmaf(ov, Ws[k * 64 + lane], au);
            av = fmaf(ov, Ws[(64 + k) * 64 + lane], av);
        }
        Uh[n * 64 + lane] = __float2half(au);
        Vh[n * 64 + lane] = __float2half(av);
    }
}

// K7i: edge MLP via f16 MFMA, TWO independent 32-edge tiles per wave (2x MLP),
// single-product f16 weights in LDS, XCD swizzle.
__global__ __launch_bounds__(512) void k7i(
    const unsigned* __restrict__ s2sd, const int* __restrict__ e2,
    const __half* __restrict__ Uh, const __half* __restrict__ Vh,
    const __half* __restrict__ W2th, const __half* __restrict__ W3th,
    const float* __restrict__ mb2, const float* __restrict__ mb3,
    const float* __restrict__ mW4, const float* __restrict__ mb4,
    float* __restrict__ out)
{
    __shared__ unsigned short Wf[2][4096];
    __shared__ float mbS[3][64];
    const int t = threadIdx.x;
    {
        int mA = t >> 8, kb = (t >> 6) & 3, l = t & 63;
        int src = (mA * 32 + (l & 31)) * 64 + kb * 16 + (l >> 5) * 8;
        *(uint4*)&Wf[0][t * 8] = *(const uint4*)(W2th + src);
        *(uint4*)&Wf[1][t * 8] = *(const uint4*)(W3th + src);
        if (t < 64) mbS[0][t] = mb2[t];
        else if (t < 128) mbS[1][t - 64] = mb3[t - 64];
        else if (t < 192) mbS[2][t - 128] = mW4[t - 128];
    }
    __syncthreads();

    const int nb = gridDim.x, q8 = nb >> 3, r8 = nb & 7;
    const int xcd = blockIdx.x & 7, bidx = blockIdx.x >> 3;
    const int wg = (xcd < r8) ? xcd * (q8 + 1) + bidx
                              : r8 * (q8 + 1) + (xcd - r8) * q8 + bidx;

    const int wid = t >> 6, lane = t & 63;
    const int tbase = wg * 512 + wid * 64;      // two 32-edge tiles
    const int l31 = lane & 31;
    const int h = lane >> 5;
    const int ksub = h * 8;

    unsigned sdA = s2sd[tbase + l31];
    unsigned sdB = s2sd[tbase + 32 + l31];
    const __half* urowA = Uh + (size_t)(sdA & 0xffffu) * 64 + ksub;
    const __half* vrowA = Vh + (size_t)(sdA >> 16) * 64 + ksub;
    const __half* urowB = Uh + (size_t)(sdB & 0xffffu) * 64 + ksub;
    const __half* vrowB = Vh + (size_t)(sdB >> 16) * 64 + ksub;

    // ---- layer 2, bias init from LDS ----
    f32x16 c2A[2], c2B[2];
    #pragma unroll
    for (int mA = 0; mA < 2; mA++)
        #pragma unroll
        for (int q = 0; q < 4; q++) {
            float4 b = *(const float4*)&mbS[0][mA * 32 + 4 * h + q * 8];
            c2A[mA][q * 4 + 0] = b.x; c2A[mA][q * 4 + 1] = b.y;
            c2A[mA][q * 4 + 2] = b.z; c2A[mA][q * 4 + 3] = b.w;
            c2B[mA][q * 4 + 0] = b.x; c2B[mA][q * 4 + 1] = b.y;
            c2B[mA][q * 4 + 2] = b.z; c2B[mA][q * 4 + 3] = b.w;
        }

    #pragma unroll
    for (int kb = 0; kb < 4; kb++) {
        H8 uA, vA, uB, vB, zA, zB;
        uA.u4 = *(const uint4*)(urowA + kb * 16);
        vA.u4 = *(const uint4*)(vrowA + kb * 16);
        uB.u4 = *(const uint4*)(urowB + kb * 16);
        vB.u4 = *(const uint4*)(vrowB + kb * 16);
        {
            half8v sA = uA.v + vA.v;
            half8v sB = uB.v + vB.v;
            #pragma unroll
            for (int j = 0; j < 8; j++) {
                _Float16 a = sA[j];
                zA.v[j] = a > (_Float16)0 ? a : (_Float16)0;
                _Float16 bq = sB[j];
                zB.v[j] = bq > (_Float16)0 ? bq : (_Float16)0;
            }
        }
        #pragma unroll
        for (int mA = 0; mA < 2; mA++) {
            const int f = (mA * 4 + kb) * 64 + lane;
            half8v ah = *(const half8v*)&Wf[0][f * 8];
            c2A[mA] = __builtin_amdgcn_mfma_f32_32x32x16_f16(ah, zA.v, c2A[mA], 0, 0, 0);
            c2B[mA] = __builtin_amdgcn_mfma_f32_32x32x16_f16(ah, zB.v, c2B[mA], 0, 0, 0);
        }
    }

    // ---- refragment relu(c2) -> B3 f16 fragments (c2 dies here) ----
    half8v B3A[4], B3B[4];
    #pragma unroll
    for (int kbp = 0; kbp < 4; kbp++) {
        const int mAs = kbp >> 1, kbl = kbp & 1;
        half8v tA, tB;
        #pragma unroll
        for (int b = 0; b < 4; b++) {
            float u = fmaxf(c2A[mAs][8 * kbl + b], 0.f);
            float v = fmaxf(c2A[mAs][8 * kbl + 4 + b], 0.f);
            float su = __shfl_xor(u, 32, 64);
            float sv = __shfl_xor(v, 32, 64);
            tA[b]     = (_Float16)(h ? sv : u);
            tA[4 + b] = (_Float16)(h ? v : su);
            float u2 = fmaxf(c2B[mAs][8 * kbl + b], 0.f);
            float v2 = fmaxf(c2B[mAs][8 * kbl + 4 + b], 0.f);
            float su2 = __shfl_xor(u2, 32, 64);
            float sv2 = __shfl_xor(v2, 32, 64);
            tB[b]     = (_Float16)(h ? sv2 : u2);
            tB[4 + b] = (_Float16)(h ? v2 : su2);
        }
        B3A[kbp] = tA;
        B3B[kbp] = tB;
    }

    // ---- layer 3, bias init from LDS ----
    f32x16 c3A[2], c3B[2];
    #pragma unroll
    for (int mA = 0; mA < 2; mA++)
        #pragma unroll
        for (int q = 0; q < 4; q++) {
            float4 b = *(const float4*)&mbS[1][mA * 32 + 4 * h + q * 8];
            c3A[mA][q * 4 + 0] = b.x; c3A[mA][q * 4 + 1] = b.y;
            c3A[mA][q * 4 + 2] = b.z; c3A[mA][q * 4 + 3] = b.w;
            c3B[mA][q * 4 + 0] = b.x; c3B[mA][q * 4 + 1] = b.y;
            c3B[mA][q * 4 + 2] = b.z; c3B[mA][q * 4 + 3] = b.w;
        }

    #pragma unroll
    for (int kbp = 0; kbp < 4; kbp++) {
        #pragma unroll
        for (int mA = 0; mA < 2; mA++) {
            const int f = (mA * 4 + kbp) * 64 + lane;
            half8v ah = *(const half8v*)&Wf[1][f * 8];
            c3A[mA] = __builtin_amdgcn_mfma_f32_32x32x16_f16(ah, B3A[kbp], c3A[mA], 0, 0, 0);
            c3B[mA] = __builtin_amdgcn_mfma_f32_32x32x16_f16(ah, B3B[kbp], c3B[mA], 0, 0, 0);
        }
    }

    float pA = 0.f, pB = 0.f;
    #pragma unroll
    for (int mA = 0; mA < 2; mA++)
        #pragma unroll
        for (int q = 0; q < 4; q++) {
            float4 w4 = *(const float4*)&mbS[2][mA * 32 + 4 * h + q * 8];
            pA = fmaf(fmaxf(c3A[mA][q * 4 + 0], 0.f), w4.x, pA);
            pA = fmaf(fmaxf(c3A[mA][q * 4 + 1], 0.f), w4.y, pA);
            pA = fmaf(fmaxf(c3A[mA][q * 4 + 2], 0.f), w4.z, pA);
            pA = fmaf(fmaxf(c3A[mA][q * 4 + 3], 0.f), w4.w, pA);
            pB = fmaf(fmaxf(c3B[mA][q * 4 + 0], 0.f), w4.x, pB);
            pB = fmaf(fmaxf(c3B[mA][q * 4 + 1], 0.f), w4.y, pB);
            pB = fmaf(fmaxf(c3B[mA][q * 4 + 2], 0.f), w4.z, pB);
            pB = fmaf(fmaxf(c3B[mA][q * 4 + 3], 0.f), w4.w, pB);
        }
    pA += __shfl_xor(pA, 32, 64);
    pB += __shfl_xor(pB, 32, 64);
    int eA = e2[tbase + l31];
    int eB = e2[tbase + 32 + l31];
    if (lane < 32) {
        out[eA] = pA + mb4[0];
        out[eB] = pB + mb4[0];
    }
}

extern "C" void kernel_launch(void* const* d_in, const int* in_sizes, int n_in,
                              void* d_out, int out_size, void* d_ws, size_t ws_size,
                              hipStream_t stream) {
    const float* x   = (const float*)d_in[0];
    const int*   ei  = (const int*)d_in[1];
    const float* W1  = (const float*)d_in[2];
    const float* as1 = (const float*)d_in[3];
    const float* ad1 = (const float*)d_in[4];
    const float* b1  = (const float*)d_in[5];
    const float* W2  = (const float*)d_in[6];
    const float* as2 = (const float*)d_in[7];
    const float* ad2 = (const float*)d_in[8];
    const float* b2  = (const float*)d_in[9];
    const float* mW1 = (const float*)d_in[10];
    const float* mb1 = (const float*)d_in[11];
    const float* mW2 = (const float*)d_in[12];
    const float* mb2 = (const float*)d_in[13];
    const float* mW3 = (const float*)d_in[14];
    const float* mb3 = (const float*)d_in[15];
    const float* mW4 = (const float*)d_in[16];
    const float* mb4 = (const float*)d_in[17];
    float* out = (float*)d_out;
    const int* row = ei;             // src
    const int* col = ei + N_EDGES;   // dst

    char* w = (char*)d_ws;
    __half*   Uh    = (__half*)w;                     // 6.4 MB, k5b->k7i
    __half*   Vh    = (__half*)(w + 6400000);         // 6.4 MB, k5b->k7i
    float*    out2  = (float*)(w + 12800000);         // 12.8 MB, k5a->k5b
    __half*   h2h   = (__half*)(w + 25600000);        // 6.4 MB, k4n->k5a
    unsigned* ssd   = (unsigned*)(w + 32000000);      // 6.4 MB (CSR order, dst<<16|src)
    int*      eid   = (int*)(w + 38400000);           // 6.4 MB (dead after p_scatter)
    unsigned* s2sd  = (unsigned*)(w + 44800000);      // 6.4 MB (2D order)
    int*      eid2  = (int*)(w + 51200000);           // 6.4 MB
    int*      offp  = (int*)(w + 57800000);           // 0.2 MB + 4
    float*    al_s2 = (float*)(w + 58200064);
    float*    al_d2 = (float*)(w + 58400064);
    int*      bsum  = (int*)(w + 58600064);           // scan temps
    float*    qs    = (float*)(w + 58605056);
    float*    qd    = (float*)(w + 58605184);
    __half*   W2th  = (__half*)(w + 58605312);
    __half*   W3th  = W2th + 4096;                    // 16 KB total
    int*      cnt   = (int*)(w + 58638080);           // 7*NBLK*4 = 175 KB
    int*      basep = (int*)(w + 58813080);           // 175 KB -> ends 58,988,080
    int*      cnt1  = (int*)(w + 58988992);           // NB1*NBLK*4 = 1.225 MB
    int*      basep1= (int*)(w + 60214000);           // 1.225 MB
    int*      bsumA = (int*)(w + 61439008);           // ~5 KB
    unsigned* m1k   = (unsigned*)(w + 61500000);      // 0.4 MB (layer-1 max keys)
    unsigned* m2k   = (unsigned*)(w + 61900000);      // 0.2 MB (layer-2 max keys)
    // overlays:
    float*    accx  = (float*)(w + 12800000);         // k3n->k4n (inside out2)
    float*    denb  = (float*)(w + 19200000);
    float*    al_s1 = (float*)(w + 19600000);
    float*    al_d1 = (float*)(w + 20000000);
    unsigned long long* tmp = (unsigned long long*)(w + 44800000);  // overlays s2sd+eid2 (dead after k_sort2c)
    float2*   w12   = (float2*)(w + 62200000);        // 12.8 MB, k_sort2c->k3n (own region; tmp still live)
    float*    w2    = (float*)(w + 38400000);         // 6.4 MB, b_mw2->k5a (over eid; eid dead after p_scatter)

    k_prep<<<65, 64, 0, stream>>>(W1, as1, ad1, qs, qd, mW2, mW3, W2th, W3th);
    k1n<<<(N_NODES + 255) / 256, 256, 0, stream>>>(x, qs, qd, al_s1, al_d1);
    // per-block level-1 bucket counts (dst>>10)
    s_hist1<<<NBLK, 256, 0, stream>>>(col, cnt1);
    // level-1 bucket bases
    {
        int n1 = NB1 * NBLK;                          // 306250
        int nb1 = (n1 + SCAN_B - 1) / SCAN_B;         // 1197
        int nb2 = (nb1 + SCAN_B - 1) / SCAN_B;        // 5
        g_scan1<<<nb1, SCAN_B, 0, stream>>>(cnt1, basep1, bsumA, n1);
        g_scan1<<<nb2, SCAN_B, 0, stream>>>(bsumA, bsumA, bsum, nb1);
        k_scan2<<<1, SCAN_B, 0, stream>>>(bsum, nb2);
        g_add<<<nb2, SCAN_B, 0, stream>>>(bsumA, bsum, nb1);
        g_add<<<nb1, SCAN_B, 0, stream>>>(basep1, bsumA, n1);
    }
    // hierarchical scatter: edges -> bucket-major tmp -> per-bucket sort
    // (deg/offp + layer-1 max + w12 all produced inside k_sort2c)
    s_scatter1<<<NBLK, 256, 0, stream>>>(row, col, basep1, tmp);
    k_sort2c<<<NB1, 1024, 0, stream>>>(tmp, basep1, al_s1, al_d1, offp, ssd, eid, m1k, w12);
    k3n<<<N_NODES / 8, 256, 0, stream>>>(x, al_s1, al_d1, m1k, offp, ssd, w12, accx, denb);
    // 7-bucket src partition for k7i
    p_hist<<<NBLK, 256, 0, stream>>>(ssd, cnt);
    {
        int n = 7 * NBLK;                             // 43750
        int nbk = (n + SCAN_B - 1) / SCAN_B;          // 171
        g_scan1<<<nbk, SCAN_B, 0, stream>>>(cnt, basep, bsum, n);
        k_scan2<<<1, SCAN_B, 0, stream>>>(bsum, nbk);
        g_add<<<nbk, SCAN_B, 0, stream>>>(basep, bsum, n);
    }
    p_scatter<<<NBLK, 256, 0, stream>>>(ssd, eid, basep, s2sd, eid2);
    k4n<<<768, 256, 0, stream>>>(accx, denb, W1, b1, W2, as2, ad2, h2h, al_s2, al_d2);
    // layer-2 attention weights, then slim aggregation
    b_mw2<<<(N_NODES + 255) / 256, 256, 0, stream>>>(ssd, offp, al_s2, al_d2, m2k, w2);
    k5a<<<N_NODES, 64, 0, stream>>>(h2h, al_s2, al_d2, m2k, b2, offp, ssd, w2, out2);
    k5b<<<1024, 256, 0, stream>>>(out2, mW1, mb1, Uh, Vh);
    k7i<<<N_EDGES / 512, 512, 0, stream>>>(s2sd, eid2, Uh, Vh,
                                           W2th, W3th,
                                           mb2, mb3, mW4, mb4, out);
}

// Round 19
// 400.712 us; speedup vs baseline: 1.1567x; 1.1567x over previous
//
#include <hip/hip_runtime.h>
#include <hip/hip_bf16.h>
#include <hip/hip_fp16.h>
#include <math.h>

#define N_NODES 50000
#define N_EDGES 1600000
#define IN_DIM 16
#define HID 64
#define NBLK 6250          // N_EDGES / 256
#define NB1 49             // level-1 scatter buckets (dst>>10)

typedef __attribute__((ext_vector_type(8))) _Float16 half8v;
typedef __attribute__((ext_vector_type(16))) float f32x16;

union H8 { uint4 u4; half8v v; };

__device__ __forceinline__ float lrelu(float v) { return v > 0.f ? v : 0.2f * v; }

__device__ __forceinline__ float wave_reduce_sum(float v) {
    #pragma unroll
    for (int off = 32; off > 0; off >>= 1) v += __shfl_down(v, off, 64);
    return v;
}

// monotone float<->uint mapping for max-keys (exact, deterministic)
__device__ __forceinline__ unsigned fkey(float f) {
    unsigned b = __float_as_uint(f);
    return (b & 0x80000000u) ? ~b : (b | 0x80000000u);
}
__device__ __forceinline__ float funkey(unsigned k) {
    return (k & 0x80000000u) ? __uint_as_float(k & 0x7fffffffu) : __uint_as_float(~k);
}

// k_prep: block 64 = qprep (qs/qd vectors); blocks 0..63 = f16 weight transpose rows
__global__ void k_prep(const float* __restrict__ W1, const float* __restrict__ as1,
                       const float* __restrict__ ad1, float* __restrict__ qs, float* __restrict__ qd,
                       const float* __restrict__ mW2, const float* __restrict__ mW3,
                       __half* __restrict__ W2th, __half* __restrict__ W3th) {
    int t = threadIdx.x;
    if (blockIdx.x == 64) {
        if (t < 32) {
            int i = t >> 1, h = t & 1;
            float s = 0.f, d = 0.f;
            for (int c = 0; c < 64; c++) {
                float w = W1[i * 128 + h * 64 + c];
                s = fmaf(w, as1[h * 64 + c], s);
                d = fmaf(w, ad1[h * 64 + c], d);
            }
            qs[i * 2 + h] = s; qd[i * 2 + h] = d;
        }
    } else {
        int b = blockIdx.x;
        W2th[b * 64 + t] = __float2half(mW2[t * 64 + b]);
        W3th[b * 64 + t] = __float2half(mW3[t * 64 + b]);
    }
}

// k1n: alpha terms per node
__global__ void k1n(const float* __restrict__ x, const float* __restrict__ qs,
                    const float* __restrict__ qd, float* __restrict__ al_s, float* __restrict__ al_d) {
    int n = blockIdx.x * 256 + threadIdx.x;
    if (n >= N_NODES) return;
    float s0 = 0.f, s1 = 0.f, d0 = 0.f, d1 = 0.f;
    #pragma unroll
    for (int i = 0; i < IN_DIM; i++) {
        float xv = x[n * IN_DIM + i];
        s0 = fmaf(xv, qs[i * 2 + 0], s0);
        s1 = fmaf(xv, qs[i * 2 + 1], s1);
        d0 = fmaf(xv, qd[i * 2 + 0], d0);
        d1 = fmaf(xv, qd[i * 2 + 1], d1);
    }
    al_s[n * 2 + 0] = s0; al_s[n * 2 + 1] = s1;
    al_d[n * 2 + 0] = d0; al_d[n * 2 + 1] = d1;
}

#define SCAN_B 256
__global__ void k_scan2(int* __restrict__ bsum, int nblocks) {
    __shared__ int sh[SCAN_B];
    int v = (threadIdx.x < nblocks) ? bsum[threadIdx.x] : 0;
    sh[threadIdx.x] = v;
    __syncthreads();
    for (int o = 1; o < SCAN_B; o <<= 1) {
        int t = (threadIdx.x >= o) ? sh[threadIdx.x - o] : 0;
        __syncthreads();
        sh[threadIdx.x] += t;
        __syncthreads();
    }
    if (threadIdx.x < nblocks) bsum[threadIdx.x] = sh[threadIdx.x] - v;
}

__global__ void g_scan1(const int* __restrict__ in, int* __restrict__ out,
                        int* __restrict__ bsum, int n) {
    __shared__ int sh[SCAN_B];
    int gid = blockIdx.x * SCAN_B + threadIdx.x;
    int v = (gid < n) ? in[gid] : 0;
    sh[threadIdx.x] = v;
    __syncthreads();
    for (int o = 1; o < SCAN_B; o <<= 1) {
        int t = (threadIdx.x >= o) ? sh[threadIdx.x - o] : 0;
        __syncthreads();
        sh[threadIdx.x] += t;
        __syncthreads();
    }
    int incl = sh[threadIdx.x];
    if (gid < n) out[gid] = incl - v;
    if (threadIdx.x == SCAN_B - 1) bsum[blockIdx.x] = incl;
}
__global__ void g_add(int* __restrict__ out, const int* __restrict__ bsum, int n) {
    int gid = blockIdx.x * SCAN_B + threadIdx.x;
    if (gid < n) out[gid] += bsum[blockIdx.x];
}

// ---- hierarchical CSR scatter ----
__global__ __launch_bounds__(256) void s_hist1(const int* __restrict__ dst,
                                               int* __restrict__ cnt1) {
    __shared__ int c[NB1];
    if (threadIdx.x < NB1) c[threadIdx.x] = 0;
    __syncthreads();
    int e = blockIdx.x * 256 + threadIdx.x;
    atomicAdd(&c[dst[e] >> 10], 1);
    __syncthreads();
    if (threadIdx.x < NB1) cnt1[threadIdx.x * NBLK + blockIdx.x] = c[threadIdx.x];
}

__global__ __launch_bounds__(256) void s_scatter1(const int* __restrict__ src,
                                                  const int* __restrict__ dst,
                                                  const int* __restrict__ basep1,
                                                  unsigned long long* __restrict__ tmp) {
    __shared__ int c[NB1], base[NB1];
    if (threadIdx.x < NB1) c[threadIdx.x] = 0;
    __syncthreads();
    int e = blockIdx.x * 256 + threadIdx.x;
    int d = dst[e], s = src[e];
    int k = d >> 10;
    int rank = atomicAdd(&c[k], 1);
    __syncthreads();
    if (threadIdx.x < NB1) base[threadIdx.x] = basep1[threadIdx.x * NBLK + blockIdx.x];
    __syncthreads();
    unsigned long long v = ((unsigned long long)e << 32) |
                           (((unsigned)d << 16) | (unsigned)s);
    tmp[base[k] + rank] = v;
}

// k_sort2b: one block per dst-bucket. Pass A: LDS deg count; LDS scan -> offp;
// Pass B: scatter to exact CSR slots via LDS cursors. No global atomics.
__global__ __launch_bounds__(1024) void k_sort2b(const unsigned long long* __restrict__ tmp,
                                                 const int* __restrict__ basep1,
                                                 int* __restrict__ offp,
                                                 unsigned* __restrict__ ssd,
                                                 int* __restrict__ eid) {
    __shared__ int cnt[1024];
    int b = blockIdx.x, t = threadIdx.x;
    int d0 = b << 10;
    int nd = N_NODES - d0; if (nd > 1024) nd = 1024;
    cnt[t] = 0;
    __syncthreads();
    int ebeg = basep1[b * NBLK];
    int eend = (b == NB1 - 1) ? N_EDGES : basep1[(b + 1) * NBLK];
    for (int i = ebeg + t; i < eend; i += 1024) {
        unsigned lo = (unsigned)tmp[i];
        atomicAdd(&cnt[(lo >> 16) - d0], 1);
    }
    __syncthreads();
    int v = cnt[t];
    for (int o = 1; o < 1024; o <<= 1) {
        int tv = (t >= o) ? cnt[t - o] : 0;
        __syncthreads();
        cnt[t] += tv;
        __syncthreads();
    }
    int cur = ebeg + cnt[t] - v;     // exclusive prefix -> global CSR offset
    if (t < nd) offp[d0 + t] = cur;
    if (b == NB1 - 1 && t == 0) offp[N_NODES] = N_EDGES;
    __syncthreads();
    cnt[t] = cur;
    __syncthreads();
    for (int i = ebeg + t; i < eend; i += 1024) {
        unsigned long long v64 = tmp[i];
        unsigned lo = (unsigned)v64;
        int pos = atomicAdd(&cnt[(lo >> 16) - d0], 1);
        ssd[pos] = lo;
        eid[pos] = (int)(v64 >> 32);
    }
}

// b_mw1: per-256-dst-tile layer-1 max (LDS, self-init) + softmax weights (fused).
__global__ __launch_bounds__(256) void b_mw1(const unsigned* __restrict__ ssd,
                                             const int* __restrict__ offp,
                                             const float* __restrict__ als,
                                             const float* __restrict__ ald,
                                             unsigned* __restrict__ m1k,
                                             float2* __restrict__ w12) {
    __shared__ unsigned mk0[256], mk1[256];
    int d0 = blockIdx.x * 256, t = threadIdx.x;
    int nd = N_NODES - d0; if (nd > 256) nd = 256;
    if (t < nd) {
        int n = d0 + t;
        mk0[t] = fkey(lrelu(als[n * 2]     + ald[n * 2]));
        mk1[t] = fkey(lrelu(als[n * 2 + 1] + ald[n * 2 + 1]));
    }
    __syncthreads();
    int ebeg = offp[d0], eend = offp[d0 + nd];
    for (int i = ebeg + t; i < eend; i += 256) {
        unsigned v = ssd[i];
        int s = (int)(v & 0xffffu), dl = (int)(v >> 16) - d0;
        atomicMax(&mk0[dl], fkey(lrelu(als[s * 2]     + ald[(d0 + dl) * 2])));
        atomicMax(&mk1[dl], fkey(lrelu(als[s * 2 + 1] + ald[(d0 + dl) * 2 + 1])));
    }
    __syncthreads();
    if (t < nd) { m1k[(d0 + t) * 2] = mk0[t]; m1k[(d0 + t) * 2 + 1] = mk1[t]; }
    __syncthreads();
    for (int i = ebeg + t; i < eend; i += 256) {
        unsigned v = ssd[i];
        int s = (int)(v & 0xffffu), dl = (int)(v >> 16) - d0;
        float e0 = lrelu(als[s * 2]     + ald[(d0 + dl) * 2]);
        float e1 = lrelu(als[s * 2 + 1] + ald[(d0 + dl) * 2 + 1]);
        w12[i] = make_float2(__expf(e0 - funkey(mk0[dl])), __expf(e1 - funkey(mk1[dl])));
    }
}

// b_mw2: per-256-dst-tile layer-2 max + weights (fused).
__global__ __launch_bounds__(256) void b_mw2(const unsigned* __restrict__ ssd,
                                             const int* __restrict__ offp,
                                             const float* __restrict__ als,
                                             const float* __restrict__ ald,
                                             unsigned* __restrict__ m2k,
                                             float* __restrict__ w2) {
    __shared__ unsigned mk[256];
    int d0 = blockIdx.x * 256, t = threadIdx.x;
    int nd = N_NODES - d0; if (nd > 256) nd = 256;
    if (t < nd) {
        int n = d0 + t;
        mk[t] = fkey(lrelu(als[n] + ald[n]));
    }
    __syncthreads();
    int ebeg = offp[d0], eend = offp[d0 + nd];
    for (int i = ebeg + t; i < eend; i += 256) {
        unsigned v = ssd[i];
        int s = (int)(v & 0xffffu), dl = (int)(v >> 16) - d0;
        atomicMax(&mk[dl], fkey(lrelu(als[s] + ald[d0 + dl])));
    }
    __syncthreads();
    if (t < nd) m2k[d0 + t] = mk[t];
    __syncthreads();
    for (int i = ebeg + t; i < eend; i += 256) {
        unsigned v = ssd[i];
        int s = (int)(v & 0xffffu), dl = (int)(v >> 16) - d0;
        float e = lrelu(als[s] + ald[d0 + dl]);
        w2[i] = __expf(e - funkey(mk[dl]));
    }
}

// ---- stable 7-bucket partition by src>>13 (keeps dst order within bucket) ----
__global__ __launch_bounds__(256) void p_hist(const unsigned* __restrict__ ssd, int* __restrict__ cnt) {
    __shared__ int c[7];
    if (threadIdx.x < 7) c[threadIdx.x] = 0;
    __syncthreads();
    int i = blockIdx.x * 256 + threadIdx.x;
    atomicAdd(&c[(ssd[i] & 0xffff) >> 13], 1);
    __syncthreads();
    if (threadIdx.x < 7) cnt[threadIdx.x * NBLK + blockIdx.x] = c[threadIdx.x];
}

__global__ __launch_bounds__(256) void p_scatter(
    const unsigned* __restrict__ ssd, const int* __restrict__ eid,
    const int* __restrict__ basep, unsigned* __restrict__ s2sd, int* __restrict__ e2) {
    __shared__ int wcnt[4][7];
    int wid = threadIdx.x >> 6, lane = threadIdx.x & 63;
    int i = blockIdx.x * 256 + threadIdx.x;
    unsigned v = ssd[i];
    int e = eid[i];
    int k = (v & 0xffff) >> 13;
    int rank = 0;
    #pragma unroll
    for (int kk = 0; kk < 7; kk++) {
        unsigned long long m = __ballot(k == kk);
        if (k == kk) rank = __popcll(m & ((1ull << lane) - 1ull));
        if (lane == kk) wcnt[wid][kk] = __popcll(m);
    }
    __syncthreads();
    int prev = 0;
    #pragma unroll
    for (int w = 0; w < 4; w++) if (w < wid) prev += wcnt[w][k];
    int pos = basep[k * NBLK + blockIdx.x] + prev + rank;
    s2sd[pos] = v; e2[pos] = e;
}

// K3n slim: layer-1 aggregation with precomputed weights; single pass.
__global__ void k3n(const float* __restrict__ x, const float* __restrict__ als,
                    const float* __restrict__ ald, const unsigned* __restrict__ m1k,
                    const int* __restrict__ off, const unsigned* __restrict__ ssd,
                    const float2* __restrict__ w12,
                    float* __restrict__ accx, float* __restrict__ denb) {
    int wid = threadIdx.x >> 6, lane = threadIdx.x & 63;
    int half = lane >> 5, sub = lane & 31, head = sub >> 4, ch = sub & 15;
    int d = blockIdx.x * 8 + wid * 2 + half;
    if (d >= N_NODES) return;
    int beg = off[d], end = off[d + 1];
    float m = funkey(m1k[d * 2 + head]);
    float es = lrelu(als[d * 2 + head] + ald[d * 2 + head]);
    float ws = __expf(es - m);
    float den0 = ws, den1 = 0.f;
    float a0 = ws * x[d * IN_DIM + ch], a1 = 0.f;
    int i = beg;
    for (; i + 7 < end; i += 8) {
        int sv[8]; float wv[8], xv[8];
        #pragma unroll
        for (int t = 0; t < 8; t++) sv[t] = (int)(ssd[i + t] & 0xffffu);
        #pragma unroll
        for (int t = 0; t < 8; t++) {
            float2 w2v = w12[i + t];
            wv[t] = head ? w2v.y : w2v.x;
        }
        #pragma unroll
        for (int t = 0; t < 8; t++) xv[t] = x[sv[t] * IN_DIM + ch];
        den0 += wv[0]; a0 = fmaf(wv[0], xv[0], a0);
        den1 += wv[1]; a1 = fmaf(wv[1], xv[1], a1);
        den0 += wv[2]; a0 = fmaf(wv[2], xv[2], a0);
        den1 += wv[3]; a1 = fmaf(wv[3], xv[3], a1);
        den0 += wv[4]; a0 = fmaf(wv[4], xv[4], a0);
        den1 += wv[5]; a1 = fmaf(wv[5], xv[5], a1);
        den0 += wv[6]; a0 = fmaf(wv[6], xv[6], a0);
        den1 += wv[7]; a1 = fmaf(wv[7], xv[7], a1);
    }
    for (; i < end; i++) {
        int s = (int)(ssd[i] & 0xffffu);
        float2 w2v = w12[i];
        float wv = head ? w2v.y : w2v.x;
        den0 += wv; a0 = fmaf(wv, x[s * IN_DIM + ch], a0);
    }
    accx[d * 32 + sub] = a0 + a1;
    if ((sub & 15) == 0) denb[d * 2 + head] = den0 + den1;
}

// K4n: fused out1-expand then @ W2 -> h2 (f16), al_s2/al_d2. Grid-stride.
__global__ __launch_bounds__(256) void k4n(
    const float* __restrict__ accx, const float* __restrict__ denb,
    const float* __restrict__ W1, const float* __restrict__ b1,
    const float* __restrict__ W2, const float* __restrict__ as2, const float* __restrict__ ad2,
    __half* __restrict__ h2h, float* __restrict__ al_s, float* __restrict__ al_d) {
    __shared__ float W1s[16 * 128];
    __shared__ float W2s[128 * 64];
    __shared__ float st[4][160];
    for (int t = threadIdx.x; t < 16 * 128; t += 256) W1s[t] = W1[t];
    for (int t = threadIdx.x; t < 128 * 64; t += 256) W2s[t] = W2[t];
    __syncthreads();
    int wid = threadIdx.x >> 6, lane = threadIdx.x & 63;
    for (int n = blockIdx.x * 4 + wid; n < N_NODES; n += gridDim.x * 4) {
        if (lane < 32) st[wid][lane] = accx[n * 32 + lane];
        float den0 = denb[n * 2], den1 = denb[n * 2 + 1];
        float ta = 0.f, tb = 0.f;
        #pragma unroll
        for (int i = 0; i < 16; i++) {
            ta = fmaf(st[wid][i],      W1s[i * 128 + lane],      ta);
            tb = fmaf(st[wid][16 + i], W1s[i * 128 + 64 + lane], tb);
        }
        ta = fmaxf(ta / den0 + b1[lane], 0.f);
        tb = fmaxf(tb / den1 + b1[64 + lane], 0.f);
        st[wid][32 + lane] = ta;
        st[wid][96 + lane] = tb;
        float acc = 0.f;
        #pragma unroll 8
        for (int k = 0; k < 128; k++) acc = fmaf(st[wid][32 + k], W2s[k * 64 + lane], acc);
        h2h[n * 64 + lane] = __float2half(acc);
        float ps = wave_reduce_sum(acc * as2[lane]);
        float pd = wave_reduce_sum(acc * ad2[lane]);
        if (lane == 0) { al_s[n] = ps; al_d[n] = pd; }
    }
}

// K5a slim: layer-2 aggregation with precomputed weights; single pass.
__global__ __launch_bounds__(64) void k5a(
    const __half* __restrict__ h2h, const float* __restrict__ als, const float* __restrict__ ald,
    const unsigned* __restrict__ m2k, const float* __restrict__ b2,
    const int* __restrict__ off, const unsigned* __restrict__ ssd,
    const float* __restrict__ w2, float* __restrict__ out2) {
    int d = blockIdx.x;
    int lane = threadIdx.x;
    int beg = off[d], end = off[d + 1];
    float m = funkey(m2k[d]);
    float es = lrelu(als[d] + ald[d]);
    float ws = __expf(es - m);
    float den0 = ws, den1 = 0.f;
    float a0 = ws * __half2float(h2h[d * 64 + lane]), a1 = 0.f;
    int i = beg;
    for (; i + 7 < end; i += 8) {
        int sv[8]; float wv[8], vv[8];
        #pragma unroll
        for (int t = 0; t < 8; t++) sv[t] = (int)(ssd[i + t] & 0xffffu);
        #pragma unroll
        for (int t = 0; t < 8; t++) wv[t] = w2[i + t];
        #pragma unroll
        for (int t = 0; t < 8; t++) vv[t] = __half2float(h2h[sv[t] * 64 + lane]);
        den0 += wv[0]; a0 = fmaf(wv[0], vv[0], a0);
        den1 += wv[1]; a1 = fmaf(wv[1], vv[1], a1);
        den0 += wv[2]; a0 = fmaf(wv[2], vv[2], a0);
        den1 += wv[3]; a1 = fmaf(wv[3], vv[3], a1);
        den0 += wv[4]; a0 = fmaf(wv[4], vv[4], a0);
        den1 += wv[5]; a1 = fmaf(wv[5], vv[5], a1);
        den0 += wv[6]; a0 = fmaf(wv[6], vv[6], a0);
        den1 += wv[7]; a1 = fmaf(wv[7], vv[7], a1);
    }
    for (; i < end; i++) {
        int s = (int)(ssd[i] & 0xffffu);
        float wv = w2[i];
        den0 += wv; a0 = fmaf(wv, __half2float(h2h[s * 64 + lane]), a0);
    }
    out2[d * 64 + lane] = fmaxf((a0 + a1) / (den0 + den1) + b2[lane], 0.f);
}

// K5b: U/V from out2 @ mW1; stored f16. Grid-stride persistent blocks.
__global__ __launch_bounds__(256) void k5b(const float* __restrict__ out2,
                                           const float* __restrict__ mW1,
                                           const float* __restrict__ mb1,
                                           __half* __restrict__ Uh, __half* __restrict__ Vh) {
    __shared__ float Ws[128 * 64];
    __shared__ float o2s[4][64];
    for (int t = threadIdx.x; t < 128 * 64; t += 256) Ws[t] = mW1[t];
    __syncthreads();
    int wid = threadIdx.x >> 6, lane = threadIdx.x & 63;
    for (int n = blockIdx.x * 4 + wid; n < N_NODES; n += gridDim.x * 4) {
        o2s[wid][lane] = out2[n * 64 + lane];
        float au = mb1[lane], av = 0.f;
        #pragma unroll 8
        for (int k = 0; k < 64; k++) {
            float ov = o2s[wid][k];
            au = fmaf(ov, Ws[k * 64 + lane], au);
            av = fmaf(ov, Ws[(64 + k) * 64 + lane], av);
        }
        Uh[n * 64 + lane] = __float2half(au);
        Vh[n * 64 + lane] = __float2half(av);
    }
}

// K7i: edge MLP via f16 MFMA, TWO independent 32-edge tiles per wave (2x MLP),
// single-product f16 weights in LDS, XCD swizzle.
__global__ __launch_bounds__(512) void k7i(
    const unsigned* __restrict__ s2sd, const int* __restrict__ e2,
    const __half* __restrict__ Uh, const __half* __restrict__ Vh,
    const __half* __restrict__ W2th, const __half* __restrict__ W3th,
    const float* __restrict__ mb2, const float* __restrict__ mb3,
    const float* __restrict__ mW4, const float* __restrict__ mb4,
    float* __restrict__ out)
{
    __shared__ unsigned short Wf[2][4096];
    __shared__ float mbS[3][64];
    const int t = threadIdx.x;
    {
        int mA = t >> 8, kb = (t >> 6) & 3, l = t & 63;
        int src = (mA * 32 + (l & 31)) * 64 + kb * 16 + (l >> 5) * 8;
        *(uint4*)&Wf[0][t * 8] = *(const uint4*)(W2th + src);
        *(uint4*)&Wf[1][t * 8] = *(const uint4*)(W3th + src);
        if (t < 64) mbS[0][t] = mb2[t];
        else if (t < 128) mbS[1][t - 64] = mb3[t - 64];
        else if (t < 192) mbS[2][t - 128] = mW4[t - 128];
    }
    __syncthreads();

    const int nb = gridDim.x, q8 = nb >> 3, r8 = nb & 7;
    const int xcd = blockIdx.x & 7, bidx = blockIdx.x >> 3;
    const int wg = (xcd < r8) ? xcd * (q8 + 1) + bidx
                              : r8 * (q8 + 1) + (xcd - r8) * q8 + bidx;

    const int wid = t >> 6, lane = t & 63;
    const int tbase = wg * 512 + wid * 64;      // two 32-edge tiles
    const int l31 = lane & 31;
    const int h = lane >> 5;
    const int ksub = h * 8;

    unsigned sdA = s2sd[tbase + l31];
    unsigned sdB = s2sd[tbase + 32 + l31];
    const __half* urowA = Uh + (size_t)(sdA & 0xffffu) * 64 + ksub;
    const __half* vrowA = Vh + (size_t)(sdA >> 16) * 64 + ksub;
    const __half* urowB = Uh + (size_t)(sdB & 0xffffu) * 64 + ksub;
    const __half* vrowB = Vh + (size_t)(sdB >> 16) * 64 + ksub;

    // ---- layer 2, bias init from LDS ----
    f32x16 c2A[2], c2B[2];
    #pragma unroll
    for (int mA = 0; mA < 2; mA++)
        #pragma unroll
        for (int q = 0; q < 4; q++) {
            float4 b = *(const float4*)&mbS[0][mA * 32 + 4 * h + q * 8];
            c2A[mA][q * 4 + 0] = b.x; c2A[mA][q * 4 + 1] = b.y;
            c2A[mA][q * 4 + 2] = b.z; c2A[mA][q * 4 + 3] = b.w;
            c2B[mA][q * 4 + 0] = b.x; c2B[mA][q * 4 + 1] = b.y;
            c2B[mA][q * 4 + 2] = b.z; c2B[mA][q * 4 + 3] = b.w;
        }

    #pragma unroll
    for (int kb = 0; kb < 4; kb++) {
        H8 uA, vA, uB, vB, zA, zB;
        uA.u4 = *(const uint4*)(urowA + kb * 16);
        vA.u4 = *(const uint4*)(vrowA + kb * 16);
        uB.u4 = *(const uint4*)(urowB + kb * 16);
        vB.u4 = *(const uint4*)(vrowB + kb * 16);
        {
            half8v sA = uA.v + vA.v;
            half8v sB = uB.v + vB.v;
            #pragma unroll
            for (int j = 0; j < 8; j++) {
                _Float16 a = sA[j];
                zA.v[j] = a > (_Float16)0 ? a : (_Float16)0;
                _Float16 bq = sB[j];
                zB.v[j] = bq > (_Float16)0 ? bq : (_Float16)0;
            }
        }
        #pragma unroll
        for (int mA = 0; mA < 2; mA++) {
            const int f = (mA * 4 + kb) * 64 + lane;
            half8v ah = *(const half8v*)&Wf[0][f * 8];
            c2A[mA] = __builtin_amdgcn_mfma_f32_32x32x16_f16(ah, zA.v, c2A[mA], 0, 0, 0);
            c2B[mA] = __builtin_amdgcn_mfma_f32_32x32x16_f16(ah, zB.v, c2B[mA], 0, 0, 0);
        }
    }

    // ---- refragment relu(c2) -> B3 f16 fragments (c2 dies here) ----
    half8v B3A[4], B3B[4];
    #pragma unroll
    for (int kbp = 0; kbp < 4; kbp++) {
        const int mAs = kbp >> 1, kbl = kbp & 1;
        half8v tA, tB;
        #pragma unroll
        for (int b = 0; b < 4; b++) {
            float u = fmaxf(c2A[mAs][8 * kbl + b], 0.f);
            float v = fmaxf(c2A[mAs][8 * kbl + 4 + b], 0.f);
            float su = __shfl_xor(u, 32, 64);
            float sv = __shfl_xor(v, 32, 64);
            tA[b]     = (_Float16)(h ? sv : u);
            tA[4 + b] = (_Float16)(h ? v : su);
            float u2 = fmaxf(c2B[mAs][8 * kbl + b], 0.f);
            float v2 = fmaxf(c2B[mAs][8 * kbl + 4 + b], 0.f);
            float su2 = __shfl_xor(u2, 32, 64);
            float sv2 = __shfl_xor(v2, 32, 64);
            tB[b]     = (_Float16)(h ? sv2 : u2);
            tB[4 + b] = (_Float16)(h ? v2 : su2);
        }
        B3A[kbp] = tA;
        B3B[kbp] = tB;
    }

    // ---- layer 3, bias init from LDS ----
    f32x16 c3A[2], c3B[2];
    #pragma unroll
    for (int mA = 0; mA < 2; mA++)
        #pragma unroll
        for (int q = 0; q < 4; q++) {
            float4 b = *(const float4*)&mbS[1][mA * 32 + 4 * h + q * 8];
            c3A[mA][q * 4 + 0] = b.x; c3A[mA][q * 4 + 1] = b.y;
            c3A[mA][q * 4 + 2] = b.z; c3A[mA][q * 4 + 3] = b.w;
            c3B[mA][q * 4 + 0] = b.x; c3B[mA][q * 4 + 1] = b.y;
            c3B[mA][q * 4 + 2] = b.z; c3B[mA][q * 4 + 3] = b.w;
        }

    #pragma unroll
    for (int kbp = 0; kbp < 4; kbp++) {
        #pragma unroll
        for (int mA = 0; mA < 2; mA++) {
            const int f = (mA * 4 + kbp) * 64 + lane;
            half8v ah = *(const half8v*)&Wf[1][f * 8];
            c3A[mA] = __builtin_amdgcn_mfma_f32_32x32x16_f16(ah, B3A[kbp], c3A[mA], 0, 0, 0);
            c3B[mA] = __builtin_amdgcn_mfma_f32_32x32x16_f16(ah, B3B[kbp], c3B[mA], 0, 0, 0);
        }
    }

    float pA = 0.f, pB = 0.f;
    #pragma unroll
    for (int mA = 0; mA < 2; mA++)
        #pragma unroll
        for (int q = 0; q < 4; q++) {
            float4 w4 = *(const float4*)&mbS[2][mA * 32 + 4 * h + q * 8];
            pA = fmaf(fmaxf(c3A[mA][q * 4 + 0], 0.f), w4.x, pA);
            pA = fmaf(fmaxf(c3A[mA][q * 4 + 1], 0.f), w4.y, pA);
            pA = fmaf(fmaxf(c3A[mA][q * 4 + 2], 0.f), w4.z, pA);
            pA = fmaf(fmaxf(c3A[mA][q * 4 + 3], 0.f), w4.w, pA);
            pB = fmaf(fmaxf(c3B[mA][q * 4 + 0], 0.f), w4.x, pB);
            pB = fmaf(fmaxf(c3B[mA][q * 4 + 1], 0.f), w4.y, pB);
            pB = fmaf(fmaxf(c3B[mA][q * 4 + 2], 0.f), w4.z, pB);
            pB = fmaf(fmaxf(c3B[mA][q * 4 + 3], 0.f), w4.w, pB);
        }
    pA += __shfl_xor(pA, 32, 64);
    pB += __shfl_xor(pB, 32, 64);
    int eA = e2[tbase + l31];
    int eB = e2[tbase + 32 + l31];
    if (lane < 32) {
        out[eA] = pA + mb4[0];
        out[eB] = pB + mb4[0];
    }
}

extern "C" void kernel_launch(void* const* d_in, const int* in_sizes, int n_in,
                              void* d_out, int out_size, void* d_ws, size_t ws_size,
                              hipStream_t stream) {
    const float* x   = (const float*)d_in[0];
    const int*   ei  = (const int*)d_in[1];
    const float* W1  = (const float*)d_in[2];
    const float* as1 = (const float*)d_in[3];
    const float* ad1 = (const float*)d_in[4];
    const float* b1  = (const float*)d_in[5];
    const float* W2  = (const float*)d_in[6];
    const float* as2 = (const float*)d_in[7];
    const float* ad2 = (const float*)d_in[8];
    const float* b2  = (const float*)d_in[9];
    const float* mW1 = (const float*)d_in[10];
    const float* mb1 = (const float*)d_in[11];
    const float* mW2 = (const float*)d_in[12];
    const float* mb2 = (const float*)d_in[13];
    const float* mW3 = (const float*)d_in[14];
    const float* mb3 = (const float*)d_in[15];
    const float* mW4 = (const float*)d_in[16];
    const float* mb4 = (const float*)d_in[17];
    float* out = (float*)d_out;
    const int* row = ei;             // src
    const int* col = ei + N_EDGES;   // dst

    char* w = (char*)d_ws;
    __half*   Uh    = (__half*)w;                     // 6.4 MB, k5b->k7i
    __half*   Vh    = (__half*)(w + 6400000);         // 6.4 MB, k5b->k7i
    float*    out2  = (float*)(w + 12800000);         // 12.8 MB, k5a->k5b
    __half*   h2h   = (__half*)(w + 25600000);        // 6.4 MB, k4n->k5a
    unsigned* ssd   = (unsigned*)(w + 32000000);      // 6.4 MB (CSR order, dst<<16|src)
    int*      eid   = (int*)(w + 38400000);           // 6.4 MB (dead after p_scatter)
    unsigned* s2sd  = (unsigned*)(w + 44800000);      // 6.4 MB (2D order)
    int*      eid2  = (int*)(w + 51200000);           // 6.4 MB
    int*      offp  = (int*)(w + 57800000);           // 0.2 MB + 4
    float*    al_s2 = (float*)(w + 58200064);
    float*    al_d2 = (float*)(w + 58400064);
    int*      bsum  = (int*)(w + 58600064);           // scan temps
    float*    qs    = (float*)(w + 58605056);
    float*    qd    = (float*)(w + 58605184);
    __half*   W2th  = (__half*)(w + 58605312);
    __half*   W3th  = W2th + 4096;                    // 16 KB total
    int*      cnt   = (int*)(w + 58638080);           // 7*NBLK*4 = 175 KB
    int*      basep = (int*)(w + 58813080);           // 175 KB -> ends 58,988,080
    int*      cnt1  = (int*)(w + 58988992);           // NB1*NBLK*4 = 1.225 MB
    int*      basep1= (int*)(w + 60214000);           // 1.225 MB
    int*      bsumA = (int*)(w + 61439008);           // ~5 KB
    unsigned* m1k   = (unsigned*)(w + 61500000);      // 0.4 MB (layer-1 max keys)
    unsigned* m2k   = (unsigned*)(w + 61900000);      // 0.2 MB (layer-2 max keys)
    // overlays:
    float*    accx  = (float*)(w + 12800000);         // k3n->k4n (inside out2)
    float*    denb  = (float*)(w + 19200000);
    float*    al_s1 = (float*)(w + 19600000);
    float*    al_d1 = (float*)(w + 20000000);
    unsigned long long* tmp = (unsigned long long*)(w + 44800000);  // overlays s2sd+eid2 (dead after k_sort2b)
    float2*   w12   = (float2*)(w + 44800000);        // 12.8 MB, b_mw1->k3n (over tmp; dead before p_scatter)
    float*    w2    = (float*)(w + 38400000);         // 6.4 MB, b_mw2->k5a (over eid; eid dead after p_scatter)

    k_prep<<<65, 64, 0, stream>>>(W1, as1, ad1, qs, qd, mW2, mW3, W2th, W3th);
    k1n<<<(N_NODES + 255) / 256, 256, 0, stream>>>(x, qs, qd, al_s1, al_d1);
    // per-block level-1 bucket counts (dst>>10)
    s_hist1<<<NBLK, 256, 0, stream>>>(col, cnt1);
    // level-1 bucket bases
    {
        int n1 = NB1 * NBLK;                          // 306250
        int nb1 = (n1 + SCAN_B - 1) / SCAN_B;         // 1197
        int nb2 = (nb1 + SCAN_B - 1) / SCAN_B;        // 5
        g_scan1<<<nb1, SCAN_B, 0, stream>>>(cnt1, basep1, bsumA, n1);
        g_scan1<<<nb2, SCAN_B, 0, stream>>>(bsumA, bsumA, bsum, nb1);
        k_scan2<<<1, SCAN_B, 0, stream>>>(bsum, nb2);
        g_add<<<nb2, SCAN_B, 0, stream>>>(bsumA, bsum, nb1);
        g_add<<<nb1, SCAN_B, 0, stream>>>(basep1, bsumA, n1);
    }
    // hierarchical scatter: edges -> bucket-major tmp -> per-bucket sort (deg+offp internal)
    s_scatter1<<<NBLK, 256, 0, stream>>>(row, col, basep1, tmp);
    k_sort2b<<<NB1, 1024, 0, stream>>>(tmp, basep1, offp, ssd, eid);
    // layer-1 attention weights (bucket-local max + weights), then slim aggregation
    b_mw1<<<(N_NODES + 255) / 256, 256, 0, stream>>>(ssd, offp, al_s1, al_d1, m1k, w12);
    k3n<<<N_NODES / 8, 256, 0, stream>>>(x, al_s1, al_d1, m1k, offp, ssd, w12, accx, denb);
    // 7-bucket src partition for k7i (w12 now dead; s2sd/eid2 overwrite it)
    p_hist<<<NBLK, 256, 0, stream>>>(ssd, cnt);
    {
        int n = 7 * NBLK;                             // 43750
        int nbk = (n + SCAN_B - 1) / SCAN_B;          // 171
        g_scan1<<<nbk, SCAN_B, 0, stream>>>(cnt, basep, bsum, n);
        k_scan2<<<1, SCAN_B, 0, stream>>>(bsum, nbk);
        g_add<<<nbk, SCAN_B, 0, stream>>>(basep, bsum, n);
    }
    p_scatter<<<NBLK, 256, 0, stream>>>(ssd, eid, basep, s2sd, eid2);
    k4n<<<768, 256, 0, stream>>>(accx, denb, W1, b1, W2, as2, ad2, h2h, al_s2, al_d2);
    // layer-2 attention weights, then slim aggregation
    b_mw2<<<(N_NODES + 255) / 256, 256, 0, stream>>>(ssd, offp, al_s2, al_d2, m2k, w2);
    k5a<<<N_NODES, 64, 0, stream>>>(h2h, al_s2, al_d2, m2k, b2, offp, ssd, w2, out2);
    k5b<<<1024, 256, 0, stream>>>(out2, mW1, mb1, Uh, Vh);
    k7i<<<N_EDGES / 512, 512, 0, stream>>>(s2sd, eid2, Uh, Vh,
                                           W2th, W3th,
                                           mb2, mb3, mW4, mb4, out);
}

// Round 20
// 376.130 us; speedup vs baseline: 1.2323x; 1.0654x over previous
//
#include <hip/hip_runtime.h>
#include <hip/hip_bf16.h>
#include <hip/hip_fp16.h>
#include <math.h>

#define N_NODES 50000
#define N_EDGES 1600000
#define IN_DIM 16
#define HID 64
#define NBLK 6250          // N_EDGES / 256
#define NB1 49             // level-1 scatter buckets (dst>>10)

typedef __attribute__((ext_vector_type(8))) _Float16 half8v;
typedef __attribute__((ext_vector_type(16))) float f32x16;

union H8 { uint4 u4; half8v v; };

__device__ __forceinline__ float lrelu(float v) { return v > 0.f ? v : 0.2f * v; }

__device__ __forceinline__ float wave_reduce_sum(float v) {
    #pragma unroll
    for (int off = 32; off > 0; off >>= 1) v += __shfl_down(v, off, 64);
    return v;
}

// monotone float<->uint mapping for max-keys (exact, deterministic)
__device__ __forceinline__ unsigned fkey(float f) {
    unsigned b = __float_as_uint(f);
    return (b & 0x80000000u) ? ~b : (b | 0x80000000u);
}
__device__ __forceinline__ float funkey(unsigned k) {
    return (k & 0x80000000u) ? __uint_as_float(k & 0x7fffffffu) : __uint_as_float(~k);
}

// k_prep: block 64 = qprep (qs/qd vectors); blocks 0..63 = f16 weight transpose rows
__global__ void k_prep(const float* __restrict__ W1, const float* __restrict__ as1,
                       const float* __restrict__ ad1, float* __restrict__ qs, float* __restrict__ qd,
                       const float* __restrict__ mW2, const float* __restrict__ mW3,
                       __half* __restrict__ W2th, __half* __restrict__ W3th) {
    int t = threadIdx.x;
    if (blockIdx.x == 64) {
        if (t < 32) {
            int i = t >> 1, h = t & 1;
            float s = 0.f, d = 0.f;
            for (int c = 0; c < 64; c++) {
                float w = W1[i * 128 + h * 64 + c];
                s = fmaf(w, as1[h * 64 + c], s);
                d = fmaf(w, ad1[h * 64 + c], d);
            }
            qs[i * 2 + h] = s; qd[i * 2 + h] = d;
        }
    } else {
        int b = blockIdx.x;
        W2th[b * 64 + t] = __float2half(mW2[t * 64 + b]);
        W3th[b * 64 + t] = __float2half(mW3[t * 64 + b]);
    }
}

// k1n: alpha terms per node
__global__ void k1n(const float* __restrict__ x, const float* __restrict__ qs,
                    const float* __restrict__ qd, float* __restrict__ al_s, float* __restrict__ al_d) {
    int n = blockIdx.x * 256 + threadIdx.x;
    if (n >= N_NODES) return;
    float s0 = 0.f, s1 = 0.f, d0 = 0.f, d1 = 0.f;
    #pragma unroll
    for (int i = 0; i < IN_DIM; i++) {
        float xv = x[n * IN_DIM + i];
        s0 = fmaf(xv, qs[i * 2 + 0], s0);
        s1 = fmaf(xv, qs[i * 2 + 1], s1);
        d0 = fmaf(xv, qd[i * 2 + 0], d0);
        d1 = fmaf(xv, qd[i * 2 + 1], d1);
    }
    al_s[n * 2 + 0] = s0; al_s[n * 2 + 1] = s1;
    al_d[n * 2 + 0] = d0; al_d[n * 2 + 1] = d1;
}

#define SCAN_B 256
__global__ void k_scan2(int* __restrict__ bsum, int nblocks) {
    __shared__ int sh[SCAN_B];
    int v = (threadIdx.x < nblocks) ? bsum[threadIdx.x] : 0;
    sh[threadIdx.x] = v;
    __syncthreads();
    for (int o = 1; o < SCAN_B; o <<= 1) {
        int t = (threadIdx.x >= o) ? sh[threadIdx.x - o] : 0;
        __syncthreads();
        sh[threadIdx.x] += t;
        __syncthreads();
    }
    if (threadIdx.x < nblocks) bsum[threadIdx.x] = sh[threadIdx.x] - v;
}

__global__ void g_scan1(const int* __restrict__ in, int* __restrict__ out,
                        int* __restrict__ bsum, int n) {
    __shared__ int sh[SCAN_B];
    int gid = blockIdx.x * SCAN_B + threadIdx.x;
    int v = (gid < n) ? in[gid] : 0;
    sh[threadIdx.x] = v;
    __syncthreads();
    for (int o = 1; o < SCAN_B; o <<= 1) {
        int t = (threadIdx.x >= o) ? sh[threadIdx.x - o] : 0;
        __syncthreads();
        sh[threadIdx.x] += t;
        __syncthreads();
    }
    int incl = sh[threadIdx.x];
    if (gid < n) out[gid] = incl - v;
    if (threadIdx.x == SCAN_B - 1) bsum[blockIdx.x] = incl;
}
__global__ void g_add(int* __restrict__ out, const int* __restrict__ bsum, int n) {
    int gid = blockIdx.x * SCAN_B + threadIdx.x;
    if (gid < n) out[gid] += bsum[blockIdx.x];
}

// ---- hierarchical CSR scatter ----
__global__ __launch_bounds__(256) void s_hist1(const int* __restrict__ dst,
                                               int* __restrict__ cnt1) {
    __shared__ int c[NB1];
    if (threadIdx.x < NB1) c[threadIdx.x] = 0;
    __syncthreads();
    int e = blockIdx.x * 256 + threadIdx.x;
    atomicAdd(&c[dst[e] >> 10], 1);
    __syncthreads();
    if (threadIdx.x < NB1) cnt1[threadIdx.x * NBLK + blockIdx.x] = c[threadIdx.x];
}

__global__ __launch_bounds__(256) void s_scatter1(const int* __restrict__ src,
                                                  const int* __restrict__ dst,
                                                  const int* __restrict__ basep1,
                                                  unsigned long long* __restrict__ tmp) {
    __shared__ int c[NB1], base[NB1];
    if (threadIdx.x < NB1) c[threadIdx.x] = 0;
    __syncthreads();
    int e = blockIdx.x * 256 + threadIdx.x;
    int d = dst[e], s = src[e];
    int k = d >> 10;
    int rank = atomicAdd(&c[k], 1);
    __syncthreads();
    if (threadIdx.x < NB1) base[threadIdx.x] = basep1[threadIdx.x * NBLK + blockIdx.x];
    __syncthreads();
    unsigned long long v = ((unsigned long long)e << 32) |
                           (((unsigned)d << 16) | (unsigned)s);
    tmp[base[k] + rank] = v;
}

// k_sort2b: one block per dst-bucket. Pass A: LDS deg count; LDS scan -> offp;
// Pass B: scatter to exact CSR slots via LDS cursors. No global atomics.
__global__ __launch_bounds__(1024) void k_sort2b(const unsigned long long* __restrict__ tmp,
                                                 const int* __restrict__ basep1,
                                                 int* __restrict__ offp,
                                                 unsigned* __restrict__ ssd,
                                                 int* __restrict__ eid) {
    __shared__ int cnt[1024];
    int b = blockIdx.x, t = threadIdx.x;
    int d0 = b << 10;
    int nd = N_NODES - d0; if (nd > 1024) nd = 1024;
    cnt[t] = 0;
    __syncthreads();
    int ebeg = basep1[b * NBLK];
    int eend = (b == NB1 - 1) ? N_EDGES : basep1[(b + 1) * NBLK];
    for (int i = ebeg + t; i < eend; i += 1024) {
        unsigned lo = (unsigned)tmp[i];
        atomicAdd(&cnt[(lo >> 16) - d0], 1);
    }
    __syncthreads();
    int v = cnt[t];
    for (int o = 1; o < 1024; o <<= 1) {
        int tv = (t >= o) ? cnt[t - o] : 0;
        __syncthreads();
        cnt[t] += tv;
        __syncthreads();
    }
    int cur = ebeg + cnt[t] - v;     // exclusive prefix -> global CSR offset
    if (t < nd) offp[d0 + t] = cur;
    if (b == NB1 - 1 && t == 0) offp[N_NODES] = N_EDGES;
    __syncthreads();
    cnt[t] = cur;
    __syncthreads();
    for (int i = ebeg + t; i < eend; i += 1024) {
        unsigned long long v64 = tmp[i];
        unsigned lo = (unsigned)v64;
        int pos = atomicAdd(&cnt[(lo >> 16) - d0], 1);
        ssd[pos] = lo;
        eid[pos] = (int)(v64 >> 32);
    }
}

// b_mw1: per-256-dst-tile layer-1 max (LDS, self-init) + softmax weights (fused).
__global__ __launch_bounds__(256) void b_mw1(const unsigned* __restrict__ ssd,
                                             const int* __restrict__ offp,
                                             const float* __restrict__ als,
                                             const float* __restrict__ ald,
                                             unsigned* __restrict__ m1k,
                                             float2* __restrict__ w12) {
    __shared__ unsigned mk0[256], mk1[256];
    int d0 = blockIdx.x * 256, t = threadIdx.x;
    int nd = N_NODES - d0; if (nd > 256) nd = 256;
    if (t < nd) {
        int n = d0 + t;
        mk0[t] = fkey(lrelu(als[n * 2]     + ald[n * 2]));
        mk1[t] = fkey(lrelu(als[n * 2 + 1] + ald[n * 2 + 1]));
    }
    __syncthreads();
    int ebeg = offp[d0], eend = offp[d0 + nd];
    for (int i = ebeg + t; i < eend; i += 256) {
        unsigned v = ssd[i];
        int s = (int)(v & 0xffffu), dl = (int)(v >> 16) - d0;
        atomicMax(&mk0[dl], fkey(lrelu(als[s * 2]     + ald[(d0 + dl) * 2])));
        atomicMax(&mk1[dl], fkey(lrelu(als[s * 2 + 1] + ald[(d0 + dl) * 2 + 1])));
    }
    __syncthreads();
    if (t < nd) { m1k[(d0 + t) * 2] = mk0[t]; m1k[(d0 + t) * 2 + 1] = mk1[t]; }
    __syncthreads();
    for (int i = ebeg + t; i < eend; i += 256) {
        unsigned v = ssd[i];
        int s = (int)(v & 0xffffu), dl = (int)(v >> 16) - d0;
        float e0 = lrelu(als[s * 2]     + ald[(d0 + dl) * 2]);
        float e1 = lrelu(als[s * 2 + 1] + ald[(d0 + dl) * 2 + 1]);
        w12[i] = make_float2(__expf(e0 - funkey(mk0[dl])), __expf(e1 - funkey(mk1[dl])));
    }
}

// ---- stable 7-bucket partition by src>>13 (keeps dst order within bucket) ----
__global__ __launch_bounds__(256) void p_hist(const unsigned* __restrict__ ssd, int* __restrict__ cnt) {
    __shared__ int c[7];
    if (threadIdx.x < 7) c[threadIdx.x] = 0;
    __syncthreads();
    int i = blockIdx.x * 256 + threadIdx.x;
    atomicAdd(&c[(ssd[i] & 0xffff) >> 13], 1);
    __syncthreads();
    if (threadIdx.x < 7) cnt[threadIdx.x * NBLK + blockIdx.x] = c[threadIdx.x];
}

__global__ __launch_bounds__(256) void p_scatter(
    const unsigned* __restrict__ ssd, const int* __restrict__ eid,
    const int* __restrict__ basep, unsigned* __restrict__ s2sd, int* __restrict__ e2) {
    __shared__ int wcnt[4][7];
    int wid = threadIdx.x >> 6, lane = threadIdx.x & 63;
    int i = blockIdx.x * 256 + threadIdx.x;
    unsigned v = ssd[i];
    int e = eid[i];
    int k = (v & 0xffff) >> 13;
    int rank = 0;
    #pragma unroll
    for (int kk = 0; kk < 7; kk++) {
        unsigned long long m = __ballot(k == kk);
        if (k == kk) rank = __popcll(m & ((1ull << lane) - 1ull));
        if (lane == kk) wcnt[wid][kk] = __popcll(m);
    }
    __syncthreads();
    int prev = 0;
    #pragma unroll
    for (int w = 0; w < 4; w++) if (w < wid) prev += wcnt[w][k];
    int pos = basep[k * NBLK + blockIdx.x] + prev + rank;
    s2sd[pos] = v; e2[pos] = e;
}

// K3n slim: layer-1 aggregation with precomputed weights; single pass.
__global__ void k3n(const float* __restrict__ x, const float* __restrict__ als,
                    const float* __restrict__ ald, const unsigned* __restrict__ m1k,
                    const int* __restrict__ off, const unsigned* __restrict__ ssd,
                    const float2* __restrict__ w12,
                    float* __restrict__ accx, float* __restrict__ denb) {
    int wid = threadIdx.x >> 6, lane = threadIdx.x & 63;
    int half = lane >> 5, sub = lane & 31, head = sub >> 4, ch = sub & 15;
    int d = blockIdx.x * 8 + wid * 2 + half;
    if (d >= N_NODES) return;
    int beg = off[d], end = off[d + 1];
    float m = funkey(m1k[d * 2 + head]);
    float es = lrelu(als[d * 2 + head] + ald[d * 2 + head]);
    float ws = __expf(es - m);
    float den0 = ws, den1 = 0.f;
    float a0 = ws * x[d * IN_DIM + ch], a1 = 0.f;
    int i = beg;
    for (; i + 7 < end; i += 8) {
        int sv[8]; float wv[8], xv[8];
        #pragma unroll
        for (int t = 0; t < 8; t++) sv[t] = (int)(ssd[i + t] & 0xffffu);
        #pragma unroll
        for (int t = 0; t < 8; t++) {
            float2 w2v = w12[i + t];
            wv[t] = head ? w2v.y : w2v.x;
        }
        #pragma unroll
        for (int t = 0; t < 8; t++) xv[t] = x[sv[t] * IN_DIM + ch];
        den0 += wv[0]; a0 = fmaf(wv[0], xv[0], a0);
        den1 += wv[1]; a1 = fmaf(wv[1], xv[1], a1);
        den0 += wv[2]; a0 = fmaf(wv[2], xv[2], a0);
        den1 += wv[3]; a1 = fmaf(wv[3], xv[3], a1);
        den0 += wv[4]; a0 = fmaf(wv[4], xv[4], a0);
        den1 += wv[5]; a1 = fmaf(wv[5], xv[5], a1);
        den0 += wv[6]; a0 = fmaf(wv[6], xv[6], a0);
        den1 += wv[7]; a1 = fmaf(wv[7], xv[7], a1);
    }
    for (; i < end; i++) {
        int s = (int)(ssd[i] & 0xffffu);
        float2 w2v = w12[i];
        float wv = head ? w2v.y : w2v.x;
        den0 += wv; a0 = fmaf(wv, x[s * IN_DIM + ch], a0);
    }
    accx[d * 32 + sub] = a0 + a1;
    if ((sub & 15) == 0) denb[d * 2 + head] = den0 + den1;
}

// K4n: fused out1-expand then @ W2 -> h2 (f16), al_s2/al_d2. Grid-stride.
__global__ __launch_bounds__(256) void k4n(
    const float* __restrict__ accx, const float* __restrict__ denb,
    const float* __restrict__ W1, const float* __restrict__ b1,
    const float* __restrict__ W2, const float* __restrict__ as2, const float* __restrict__ ad2,
    __half* __restrict__ h2h, float* __restrict__ al_s, float* __restrict__ al_d) {
    __shared__ float W1s[16 * 128];
    __shared__ float W2s[128 * 64];
    __shared__ float st[4][160];
    for (int t = threadIdx.x; t < 16 * 128; t += 256) W1s[t] = W1[t];
    for (int t = threadIdx.x; t < 128 * 64; t += 256) W2s[t] = W2[t];
    __syncthreads();
    int wid = threadIdx.x >> 6, lane = threadIdx.x & 63;
    for (int n = blockIdx.x * 4 + wid; n < N_NODES; n += gridDim.x * 4) {
        if (lane < 32) st[wid][lane] = accx[n * 32 + lane];
        float den0 = denb[n * 2], den1 = denb[n * 2 + 1];
        float ta = 0.f, tb = 0.f;
        #pragma unroll
        for (int i = 0; i < 16; i++) {
            ta = fmaf(st[wid][i],      W1s[i * 128 + lane],      ta);
            tb = fmaf(st[wid][16 + i], W1s[i * 128 + 64 + lane], tb);
        }
        ta = fmaxf(ta / den0 + b1[lane], 0.f);
        tb = fmaxf(tb / den1 + b1[64 + lane], 0.f);
        st[wid][32 + lane] = ta;
        st[wid][96 + lane] = tb;
        float acc = 0.f;
        #pragma unroll 8
        for (int k = 0; k < 128; k++) acc = fmaf(st[wid][32 + k], W2s[k * 64 + lane], acc);
        h2h[n * 64 + lane] = __float2half(acc);
        float ps = wave_reduce_sum(acc * as2[lane]);
        float pd = wave_reduce_sum(acc * ad2[lane]);
        if (lane == 0) { al_s[n] = ps; al_d[n] = pd; }
    }
}

// K5a fused: layer-2 aggregation computing its own softmax weights.
// Phase 1: distributed per-lane max + wave reduce. Phase 2: per-64-edge chunk,
// each lane computes one edge's exp into LDS, all lanes consume as broadcasts.
__global__ __launch_bounds__(64) void k5a(
    const __half* __restrict__ h2h, const float* __restrict__ als, const float* __restrict__ ald,
    const float* __restrict__ b2, const int* __restrict__ off, const unsigned* __restrict__ ssd,
    float* __restrict__ out2) {
    __shared__ float wbuf[64];
    int d = blockIdx.x;
    int lane = threadIdx.x;
    int beg = off[d], end = off[d + 1];
    float adv = ald[d];
    float es = lrelu(als[d] + adv);
    // phase 1: max over in-edges (distributed), exact
    float m = es;
    for (int i = beg + lane; i < end; i += 64) {
        int s = (int)(ssd[i] & 0xffffu);
        m = fmaxf(m, lrelu(als[s] + adv));
    }
    #pragma unroll
    for (int o = 32; o > 0; o >>= 1) m = fmaxf(m, __shfl_xor(m, o, 64));
    // phase 2: chunked weighted sum
    float ws = __expf(es - m);
    float den0 = ws, den1 = 0.f;
    float a0 = ws * __half2float(h2h[d * 64 + lane]), a1 = 0.f;
    for (int c = beg; c < end; c += 64) {
        int idx = c + lane;
        if (idx < end) {
            int s = (int)(ssd[idx] & 0xffffu);
            wbuf[lane] = __expf(lrelu(als[s] + adv) - m);
        }
        int nchunk = end - c; if (nchunk > 64) nchunk = 64;
        int t = 0;
        for (; t + 7 < nchunk; t += 8) {
            int sv[8]; float wv[8], vv[8];
            #pragma unroll
            for (int q = 0; q < 8; q++) sv[q] = (int)(ssd[c + t + q] & 0xffffu);
            #pragma unroll
            for (int q = 0; q < 8; q++) wv[q] = wbuf[t + q];
            #pragma unroll
            for (int q = 0; q < 8; q++) vv[q] = __half2float(h2h[sv[q] * 64 + lane]);
            den0 += wv[0]; a0 = fmaf(wv[0], vv[0], a0);
            den1 += wv[1]; a1 = fmaf(wv[1], vv[1], a1);
            den0 += wv[2]; a0 = fmaf(wv[2], vv[2], a0);
            den1 += wv[3]; a1 = fmaf(wv[3], vv[3], a1);
            den0 += wv[4]; a0 = fmaf(wv[4], vv[4], a0);
            den1 += wv[5]; a1 = fmaf(wv[5], vv[5], a1);
            den0 += wv[6]; a0 = fmaf(wv[6], vv[6], a0);
            den1 += wv[7]; a1 = fmaf(wv[7], vv[7], a1);
        }
        for (; t < nchunk; t++) {
            int s = (int)(ssd[c + t] & 0xffffu);
            float wv = wbuf[t];
            den0 += wv; a0 = fmaf(wv, __half2float(h2h[s * 64 + lane]), a0);
        }
    }
    out2[d * 64 + lane] = fmaxf((a0 + a1) / (den0 + den1) + b2[lane], 0.f);
}

// K5b: U/V from out2 @ mW1; stored f16. Grid-stride persistent blocks.
__global__ __launch_bounds__(256) void k5b(const float* __restrict__ out2,
                                           const float* __restrict__ mW1,
                                           const float* __restrict__ mb1,
                                           __half* __restrict__ Uh, __half* __restrict__ Vh) {
    __shared__ float Ws[128 * 64];
    __shared__ float o2s[4][64];
    for (int t = threadIdx.x; t < 128 * 64; t += 256) Ws[t] = mW1[t];
    __syncthreads();
    int wid = threadIdx.x >> 6, lane = threadIdx.x & 63;
    for (int n = blockIdx.x * 4 + wid; n < N_NODES; n += gridDim.x * 4) {
        o2s[wid][lane] = out2[n * 64 + lane];
        float au = mb1[lane], av = 0.f;
        #pragma unroll 8
        for (int k = 0; k < 64; k++) {
            float ov = o2s[wid][k];
            au = fmaf(ov, Ws[k * 64 + lane], au);
            av = fmaf(ov, Ws[(64 + k) * 64 + lane], av);
        }
        Uh[n * 64 + lane] = __float2half(au);
        Vh[n * 64 + lane] = __float2half(av);
    }
}

// K7h: edge MLP via f16 MFMA, 32 edges/wave (best measured variant),
// single-product f16 weights in LDS, XCD swizzle.
__global__ __launch_bounds__(512) void k7h(
    const unsigned* __restrict__ s2sd, const int* __restrict__ e2,
    const __half* __restrict__ Uh, const __half* __restrict__ Vh,
    const __half* __restrict__ W2th, const __half* __restrict__ W3th,
    const float* __restrict__ mb2, const float* __restrict__ mb3,
    const float* __restrict__ mW4, const float* __restrict__ mb4,
    float* __restrict__ out)
{
    __shared__ unsigned short Wf[2][4096];
    __shared__ float mbS[3][64];
    const int t = threadIdx.x;
    {
        int mA = t >> 8, kb = (t >> 6) & 3, l = t & 63;
        int src = (mA * 32 + (l & 31)) * 64 + kb * 16 + (l >> 5) * 8;
        *(uint4*)&Wf[0][t * 8] = *(const uint4*)(W2th + src);
        *(uint4*)&Wf[1][t * 8] = *(const uint4*)(W3th + src);
        if (t < 64) mbS[0][t] = mb2[t];
        else if (t < 128) mbS[1][t - 64] = mb3[t - 64];
        else if (t < 192) mbS[2][t - 128] = mW4[t - 128];
    }
    __syncthreads();

    const int nb = gridDim.x, q8 = nb >> 3, r8 = nb & 7;
    const int xcd = blockIdx.x & 7, bidx = blockIdx.x >> 3;
    const int wg = (xcd < r8) ? xcd * (q8 + 1) + bidx
                              : r8 * (q8 + 1) + (xcd - r8) * q8 + bidx;

    const int wid = t >> 6, lane = t & 63;
    const int tbase = wg * 256 + wid * 32;
    const int l31 = lane & 31;
    const int h = lane >> 5;
    const int ksub = h * 8;

    unsigned sd = s2sd[tbase + l31];
    int rA = (int)(sd & 0xffffu);
    int cA = (int)(sd >> 16);
    const __half* urow = Uh + (size_t)rA * 64 + ksub;
    const __half* vrow = Vh + (size_t)cA * 64 + ksub;

    f32x16 c2[2];
    #pragma unroll
    for (int mA = 0; mA < 2; mA++)
        #pragma unroll
        for (int q = 0; q < 4; q++) {
            float4 b = *(const float4*)&mbS[0][mA * 32 + 4 * h + q * 8];
            c2[mA][q * 4 + 0] = b.x; c2[mA][q * 4 + 1] = b.y;
            c2[mA][q * 4 + 2] = b.z; c2[mA][q * 4 + 3] = b.w;
        }

    #pragma unroll
    for (int kb = 0; kb < 4; kb++) {
        H8 uvu, vvu, zz;
        uvu.u4 = *(const uint4*)(urow + kb * 16);
        vvu.u4 = *(const uint4*)(vrow + kb * 16);
        {
            half8v s = uvu.v + vvu.v;
            #pragma unroll
            for (int j = 0; j < 8; j++) {
                _Float16 a = s[j];
                zz.v[j] = a > (_Float16)0 ? a : (_Float16)0;
            }
        }
        #pragma unroll
        for (int mA = 0; mA < 2; mA++) {
            const int f = (mA * 4 + kb) * 64 + lane;
            half8v ah = *(const half8v*)&Wf[0][f * 8];
            c2[mA] = __builtin_amdgcn_mfma_f32_32x32x16_f16(ah, zz.v, c2[mA], 0, 0, 0);
        }
    }

    half8v B3[4];
    #pragma unroll
    for (int kbp = 0; kbp < 4; kbp++) {
        const int mAs = kbp >> 1, kbl = kbp & 1;
        half8v t8;
        #pragma unroll
        for (int b = 0; b < 4; b++) {
            float u = fmaxf(c2[mAs][8 * kbl + b], 0.f);
            float v = fmaxf(c2[mAs][8 * kbl + 4 + b], 0.f);
            float su = __shfl_xor(u, 32, 64);
            float sv = __shfl_xor(v, 32, 64);
            t8[b]     = (_Float16)(h ? sv : u);
            t8[4 + b] = (_Float16)(h ? v : su);
        }
        B3[kbp] = t8;
    }

    f32x16 c3[2];
    #pragma unroll
    for (int mA = 0; mA < 2; mA++)
        #pragma unroll
        for (int q = 0; q < 4; q++) {
            float4 b = *(const float4*)&mbS[1][mA * 32 + 4 * h + q * 8];
            c3[mA][q * 4 + 0] = b.x; c3[mA][q * 4 + 1] = b.y;
            c3[mA][q * 4 + 2] = b.z; c3[mA][q * 4 + 3] = b.w;
        }

    #pragma unroll
    for (int kbp = 0; kbp < 4; kbp++) {
        #pragma unroll
        for (int mA = 0; mA < 2; mA++) {
            const int f = (mA * 4 + kbp) * 64 + lane;
            half8v ah = *(const half8v*)&Wf[1][f * 8];
            c3[mA] = __builtin_amdgcn_mfma_f32_32x32x16_f16(ah, B3[kbp], c3[mA], 0, 0, 0);
        }
    }

    float p = 0.f;
    #pragma unroll
    for (int mA = 0; mA < 2; mA++)
        #pragma unroll
        for (int q = 0; q < 4; q++) {
            float4 w4 = *(const float4*)&mbS[2][mA * 32 + 4 * h + q * 8];
            p = fmaf(fmaxf(c3[mA][q * 4 + 0], 0.f), w4.x, p);
            p = fmaf(fmaxf(c3[mA][q * 4 + 1], 0.f), w4.y, p);
            p = fmaf(fmaxf(c3[mA][q * 4 + 2], 0.f), w4.z, p);
            p = fmaf(fmaxf(c3[mA][q * 4 + 3], 0.f), w4.w, p);
        }
    p += __shfl_xor(p, 32, 64);
    int eA = e2[tbase + l31];
    if (lane < 32) out[eA] = p + mb4[0];
}

extern "C" void kernel_launch(void* const* d_in, const int* in_sizes, int n_in,
                              void* d_out, int out_size, void* d_ws, size_t ws_size,
                              hipStream_t stream) {
    const float* x   = (const float*)d_in[0];
    const int*   ei  = (const int*)d_in[1];
    const float* W1  = (const float*)d_in[2];
    const float* as1 = (const float*)d_in[3];
    const float* ad1 = (const float*)d_in[4];
    const float* b1  = (const float*)d_in[5];
    const float* W2  = (const float*)d_in[6];
    const float* as2 = (const float*)d_in[7];
    const float* ad2 = (const float*)d_in[8];
    const float* b2  = (const float*)d_in[9];
    const float* mW1 = (const float*)d_in[10];
    const float* mb1 = (const float*)d_in[11];
    const float* mW2 = (const float*)d_in[12];
    const float* mb2 = (const float*)d_in[13];
    const float* mW3 = (const float*)d_in[14];
    const float* mb3 = (const float*)d_in[15];
    const float* mW4 = (const float*)d_in[16];
    const float* mb4 = (const float*)d_in[17];
    float* out = (float*)d_out;
    const int* row = ei;             // src
    const int* col = ei + N_EDGES;   // dst

    char* w = (char*)d_ws;
    __half*   Uh    = (__half*)w;                     // 6.4 MB, k5b->k7h
    __half*   Vh    = (__half*)(w + 6400000);         // 6.4 MB, k5b->k7h
    float*    out2  = (float*)(w + 12800000);         // 12.8 MB, k5a->k5b
    __half*   h2h   = (__half*)(w + 25600000);        // 6.4 MB, k4n->k5a
    unsigned* ssd   = (unsigned*)(w + 32000000);      // 6.4 MB (CSR order, dst<<16|src)
    int*      eid   = (int*)(w + 38400000);           // 6.4 MB (dead after p_scatter)
    unsigned* s2sd  = (unsigned*)(w + 44800000);      // 6.4 MB (2D order)
    int*      eid2  = (int*)(w + 51200000);           // 6.4 MB
    int*      offp  = (int*)(w + 57800000);           // 0.2 MB + 4
    float*    al_s2 = (float*)(w + 58200064);
    float*    al_d2 = (float*)(w + 58400064);
    int*      bsum  = (int*)(w + 58600064);           // scan temps
    float*    qs    = (float*)(w + 58605056);
    float*    qd    = (float*)(w + 58605184);
    __half*   W2th  = (__half*)(w + 58605312);
    __half*   W3th  = W2th + 4096;                    // 16 KB total
    int*      cnt   = (int*)(w + 58638080);           // 7*NBLK*4 = 175 KB
    int*      basep = (int*)(w + 58813080);           // 175 KB -> ends 58,988,080
    int*      cnt1  = (int*)(w + 58988992);           // NB1*NBLK*4 = 1.225 MB
    int*      basep1= (int*)(w + 60214000);           // 1.225 MB
    int*      bsumA = (int*)(w + 61439008);           // ~5 KB
    unsigned* m1k   = (unsigned*)(w + 61500000);      // 0.4 MB (layer-1 max keys)
    // overlays:
    float*    accx  = (float*)(w + 12800000);         // k3n->k4n (inside out2)
    float*    denb  = (float*)(w + 19200000);
    float*    al_s1 = (float*)(w + 19600000);
    float*    al_d1 = (float*)(w + 20000000);
    unsigned long long* tmp = (unsigned long long*)(w + 44800000);  // overlays s2sd+eid2 (dead after k_sort2b)
    float2*   w12   = (float2*)(w + 44800000);        // 12.8 MB, b_mw1->k3n (over tmp; dead before p_scatter)

    k_prep<<<65, 64, 0, stream>>>(W1, as1, ad1, qs, qd, mW2, mW3, W2th, W3th);
    k1n<<<(N_NODES + 255) / 256, 256, 0, stream>>>(x, qs, qd, al_s1, al_d1);
    // per-block level-1 bucket counts (dst>>10)
    s_hist1<<<NBLK, 256, 0, stream>>>(col, cnt1);
    // level-1 bucket bases
    {
        int n1 = NB1 * NBLK;                          // 306250
        int nb1 = (n1 + SCAN_B - 1) / SCAN_B;         // 1197
        int nb2 = (nb1 + SCAN_B - 1) / SCAN_B;        // 5
        g_scan1<<<nb1, SCAN_B, 0, stream>>>(cnt1, basep1, bsumA, n1);
        g_scan1<<<nb2, SCAN_B, 0, stream>>>(bsumA, bsumA, bsum, nb1);
        k_scan2<<<1, SCAN_B, 0, stream>>>(bsum, nb2);
        g_add<<<nb2, SCAN_B, 0, stream>>>(bsumA, bsum, nb1);
        g_add<<<nb1, SCAN_B, 0, stream>>>(basep1, bsumA, n1);
    }
    // hierarchical scatter: edges -> bucket-major tmp -> per-bucket sort (deg+offp internal)
    s_scatter1<<<NBLK, 256, 0, stream>>>(row, col, basep1, tmp);
    k_sort2b<<<NB1, 1024, 0, stream>>>(tmp, basep1, offp, ssd, eid);
    // layer-1 attention weights (bucket-local max + weights), then slim aggregation
    b_mw1<<<(N_NODES + 255) / 256, 256, 0, stream>>>(ssd, offp, al_s1, al_d1, m1k, w12);
    k3n<<<N_NODES / 8, 256, 0, stream>>>(x, al_s1, al_d1, m1k, offp, ssd, w12, accx, denb);
    // 7-bucket src partition for k7h (w12 now dead; s2sd/eid2 overwrite it)
    p_hist<<<NBLK, 256, 0, stream>>>(ssd, cnt);
    {
        int n = 7 * NBLK;                             // 43750
        int nbk = (n + SCAN_B - 1) / SCAN_B;          // 171
        g_scan1<<<nbk, SCAN_B, 0, stream>>>(cnt, basep, bsum, n);
        k_scan2<<<1, SCAN_B, 0, stream>>>(bsum, nbk);
        g_add<<<nbk, SCAN_B, 0, stream>>>(basep, bsum, n);
    }
    p_scatter<<<NBLK, 256, 0, stream>>>(ssd, eid, basep, s2sd, eid2);
    k4n<<<768, 256, 0, stream>>>(accx, denb, W1, b1, W2, as2, ad2, h2h, al_s2, al_d2);
    // layer-2 aggregation (computes its own softmax weights in-kernel)
    k5a<<<N_NODES, 64, 0, stream>>>(h2h, al_s2, al_d2, b2, offp, ssd, out2);
    k5b<<<1024, 256, 0, stream>>>(out2, mW1, mb1, Uh, Vh);
    k7h<<<NBLK, 512, 0, stream>>>(s2sd, eid2, Uh, Vh,
                                  W2th, W3th,
                                  mb2, mb3, mW4, mb4, out);
}

// Round 21
// 337.758 us; speedup vs baseline: 1.3723x; 1.1136x over previous
//
#include <hip/hip_runtime.h>
#include <hip/hip_bf16.h>
#include <hip/hip_fp16.h>
#include <math.h>

#define N_NODES 50000
#define N_EDGES 1600000
#define IN_DIM 16
#define HID 64
#define NBLK 6250          // N_EDGES / 256
#define NB1 49             // level-1 scatter buckets (dst>>10)

typedef __attribute__((ext_vector_type(8))) _Float16 half8v;
typedef __attribute__((ext_vector_type(16))) float f32x16;

union H8 { uint4 u4; half8v v; };

__device__ __forceinline__ float lrelu(float v) { return v > 0.f ? v : 0.2f * v; }

__device__ __forceinline__ float wave_reduce_sum(float v) {
    #pragma unroll
    for (int off = 32; off > 0; off >>= 1) v += __shfl_down(v, off, 64);
    return v;
}

// k_prep: block 64 = qprep (qs/qd vectors); blocks 0..63 = f16 weight transpose rows
__global__ void k_prep(const float* __restrict__ W1, const float* __restrict__ as1,
                       const float* __restrict__ ad1, float* __restrict__ qs, float* __restrict__ qd,
                       const float* __restrict__ mW2, const float* __restrict__ mW3,
                       __half* __restrict__ W2th, __half* __restrict__ W3th) {
    int t = threadIdx.x;
    if (blockIdx.x == 64) {
        if (t < 32) {
            int i = t >> 1, h = t & 1;
            float s = 0.f, d = 0.f;
            for (int c = 0; c < 64; c++) {
                float w = W1[i * 128 + h * 64 + c];
                s = fmaf(w, as1[h * 64 + c], s);
                d = fmaf(w, ad1[h * 64 + c], d);
            }
            qs[i * 2 + h] = s; qd[i * 2 + h] = d;
        }
    } else {
        int b = blockIdx.x;
        W2th[b * 64 + t] = __float2half(mW2[t * 64 + b]);
        W3th[b * 64 + t] = __float2half(mW3[t * 64 + b]);
    }
}

// k1n: alpha terms per node
__global__ void k1n(const float* __restrict__ x, const float* __restrict__ qs,
                    const float* __restrict__ qd, float* __restrict__ al_s, float* __restrict__ al_d) {
    int n = blockIdx.x * 256 + threadIdx.x;
    if (n >= N_NODES) return;
    float s0 = 0.f, s1 = 0.f, d0 = 0.f, d1 = 0.f;
    #pragma unroll
    for (int i = 0; i < IN_DIM; i++) {
        float xv = x[n * IN_DIM + i];
        s0 = fmaf(xv, qs[i * 2 + 0], s0);
        s1 = fmaf(xv, qs[i * 2 + 1], s1);
        d0 = fmaf(xv, qd[i * 2 + 0], d0);
        d1 = fmaf(xv, qd[i * 2 + 1], d1);
    }
    al_s[n * 2 + 0] = s0; al_s[n * 2 + 1] = s1;
    al_d[n * 2 + 0] = d0; al_d[n * 2 + 1] = d1;
}

#define SCAN_B 256
__global__ void k_scan2(int* __restrict__ bsum, int nblocks) {
    __shared__ int sh[SCAN_B];
    int v = (threadIdx.x < nblocks) ? bsum[threadIdx.x] : 0;
    sh[threadIdx.x] = v;
    __syncthreads();
    for (int o = 1; o < SCAN_B; o <<= 1) {
        int t = (threadIdx.x >= o) ? sh[threadIdx.x - o] : 0;
        __syncthreads();
        sh[threadIdx.x] += t;
        __syncthreads();
    }
    if (threadIdx.x < nblocks) bsum[threadIdx.x] = sh[threadIdx.x] - v;
}

__global__ void g_scan1(const int* __restrict__ in, int* __restrict__ out,
                        int* __restrict__ bsum, int n) {
    __shared__ int sh[SCAN_B];
    int gid = blockIdx.x * SCAN_B + threadIdx.x;
    int v = (gid < n) ? in[gid] : 0;
    sh[threadIdx.x] = v;
    __syncthreads();
    for (int o = 1; o < SCAN_B; o <<= 1) {
        int t = (threadIdx.x >= o) ? sh[threadIdx.x - o] : 0;
        __syncthreads();
        sh[threadIdx.x] += t;
        __syncthreads();
    }
    int incl = sh[threadIdx.x];
    if (gid < n) out[gid] = incl - v;
    if (threadIdx.x == SCAN_B - 1) bsum[blockIdx.x] = incl;
}
__global__ void g_add(int* __restrict__ out, const int* __restrict__ bsum, int n) {
    int gid = blockIdx.x * SCAN_B + threadIdx.x;
    if (gid < n) out[gid] += bsum[blockIdx.x];
}

// ---- hierarchical CSR scatter ----
__global__ __launch_bounds__(256) void s_hist1(const int* __restrict__ dst,
                                               int* __restrict__ cnt1) {
    __shared__ int c[NB1];
    if (threadIdx.x < NB1) c[threadIdx.x] = 0;
    __syncthreads();
    int e = blockIdx.x * 256 + threadIdx.x;
    atomicAdd(&c[dst[e] >> 10], 1);
    __syncthreads();
    if (threadIdx.x < NB1) cnt1[threadIdx.x * NBLK + blockIdx.x] = c[threadIdx.x];
}

__global__ __launch_bounds__(256) void s_scatter1(const int* __restrict__ src,
                                                  const int* __restrict__ dst,
                                                  const int* __restrict__ basep1,
                                                  unsigned long long* __restrict__ tmp) {
    __shared__ int c[NB1], base[NB1];
    if (threadIdx.x < NB1) c[threadIdx.x] = 0;
    __syncthreads();
    int e = blockIdx.x * 256 + threadIdx.x;
    int d = dst[e], s = src[e];
    int k = d >> 10;
    int rank = atomicAdd(&c[k], 1);
    __syncthreads();
    if (threadIdx.x < NB1) base[threadIdx.x] = basep1[threadIdx.x * NBLK + blockIdx.x];
    __syncthreads();
    unsigned long long v = ((unsigned long long)e << 32) |
                           (((unsigned)d << 16) | (unsigned)s);
    tmp[base[k] + rank] = v;
}

// k_sort2b: one block per dst-bucket. Pass A: LDS deg count; LDS scan -> offp;
// Pass B: scatter to exact CSR slots via LDS cursors. No global atomics.
__global__ __launch_bounds__(1024) void k_sort2b(const unsigned long long* __restrict__ tmp,
                                                 const int* __restrict__ basep1,
                                                 int* __restrict__ offp,
                                                 unsigned* __restrict__ ssd,
                                                 int* __restrict__ eid) {
    __shared__ int cnt[1024];
    int b = blockIdx.x, t = threadIdx.x;
    int d0 = b << 10;
    int nd = N_NODES - d0; if (nd > 1024) nd = 1024;
    cnt[t] = 0;
    __syncthreads();
    int ebeg = basep1[b * NBLK];
    int eend = (b == NB1 - 1) ? N_EDGES : basep1[(b + 1) * NBLK];
    for (int i = ebeg + t; i < eend; i += 1024) {
        unsigned lo = (unsigned)tmp[i];
        atomicAdd(&cnt[(lo >> 16) - d0], 1);
    }
    __syncthreads();
    int v = cnt[t];
    for (int o = 1; o < 1024; o <<= 1) {
        int tv = (t >= o) ? cnt[t - o] : 0;
        __syncthreads();
        cnt[t] += tv;
        __syncthreads();
    }
    int cur = ebeg + cnt[t] - v;     // exclusive prefix -> global CSR offset
    if (t < nd) offp[d0 + t] = cur;
    if (b == NB1 - 1 && t == 0) offp[N_NODES] = N_EDGES;
    __syncthreads();
    cnt[t] = cur;
    __syncthreads();
    for (int i = ebeg + t; i < eend; i += 1024) {
        unsigned long long v64 = tmp[i];
        unsigned lo = (unsigned)v64;
        int pos = atomicAdd(&cnt[(lo >> 16) - d0], 1);
        ssd[pos] = lo;
        eid[pos] = (int)(v64 >> 32);
    }
}

// K3n fused: layer-1 aggregation computing its own softmax weights.
// Per dst: 32 lanes (head = sub>>4, ch = sub&15). Phase 1: per-head distributed
// max (16 lanes, shfl-reduce). Phase 2: per-16-edge chunks, each of the 32 lanes
// computes one (edge,head) exp, broadcast via shfl.
__global__ void k3n(const float* __restrict__ x, const float* __restrict__ als,
                    const float* __restrict__ ald,
                    const int* __restrict__ off, const unsigned* __restrict__ ssd,
                    float* __restrict__ accx, float* __restrict__ denb) {
    int wid = threadIdx.x >> 6, lane = threadIdx.x & 63;
    int half = lane >> 5, sub = lane & 31, head = sub >> 4, ch = sub & 15;
    int d = blockIdx.x * 8 + wid * 2 + half;
    if (d >= N_NODES) return;
    int beg = off[d], end = off[d + 1];
    float adv = ald[d * 2 + head];
    float es = lrelu(als[d * 2 + head] + adv);
    // phase 1: per-head max over in-edges, distributed across this head's 16 lanes
    float m = es;
    for (int i = beg + ch; i < end; i += 16) {
        int s = (int)(ssd[i] & 0xffffu);
        m = fmaxf(m, lrelu(als[s * 2 + head] + adv));
    }
    #pragma unroll
    for (int o = 1; o < 16; o <<= 1) m = fmaxf(m, __shfl_xor(m, o, 64));
    // phase 2: chunked weighted sum; lane computes exp for edge (sub&15) of its head
    float ws = __expf(es - m);
    float den0 = ws, den1 = 0.f;
    float a0 = ws * x[d * IN_DIM + ch], a1 = 0.f;
    const int srcb = (lane & 32) + (head << 4);   // lane holding w for my head, edge t
    for (int c = beg; c < end; c += 16) {
        int nchunk = end - c; if (nchunk > 16) nchunk = 16;
        float wexp = 0.f;
        if ((sub & 15) < nchunk) {
            int s = (int)(ssd[c + (sub & 15)] & 0xffffu);
            wexp = __expf(lrelu(als[s * 2 + head] + adv) - m);
        }
        if (nchunk == 16) {
            int sv[16];
            #pragma unroll
            for (int t = 0; t < 16; t++) sv[t] = (int)(ssd[c + t] & 0xffffu);
            #pragma unroll
            for (int t = 0; t < 16; t++) {
                float wv = __shfl(wexp, srcb + t, 64);
                float xv = x[sv[t] * IN_DIM + ch];
                if (t & 1) { den1 += wv; a1 = fmaf(wv, xv, a1); }
                else       { den0 += wv; a0 = fmaf(wv, xv, a0); }
            }
        } else {
            for (int t = 0; t < nchunk; t++) {
                float wv = __shfl(wexp, srcb + t, 64);
                int s = (int)(ssd[c + t] & 0xffffu);
                den0 += wv; a0 = fmaf(wv, x[s * IN_DIM + ch], a0);
            }
        }
    }
    accx[d * 32 + sub] = a0 + a1;
    if ((sub & 15) == 0) denb[d * 2 + head] = den0 + den1;
}

// K4n: fused out1-expand then @ W2 -> h2 (f16), al_s2/al_d2. Grid-stride.
__global__ __launch_bounds__(256) void k4n(
    const float* __restrict__ accx, const float* __restrict__ denb,
    const float* __restrict__ W1, const float* __restrict__ b1,
    const float* __restrict__ W2, const float* __restrict__ as2, const float* __restrict__ ad2,
    __half* __restrict__ h2h, float* __restrict__ al_s, float* __restrict__ al_d) {
    __shared__ float W1s[16 * 128];
    __shared__ float W2s[128 * 64];
    __shared__ float st[4][160];
    for (int t = threadIdx.x; t < 16 * 128; t += 256) W1s[t] = W1[t];
    for (int t = threadIdx.x; t < 128 * 64; t += 256) W2s[t] = W2[t];
    __syncthreads();
    int wid = threadIdx.x >> 6, lane = threadIdx.x & 63;
    for (int n = blockIdx.x * 4 + wid; n < N_NODES; n += gridDim.x * 4) {
        if (lane < 32) st[wid][lane] = accx[n * 32 + lane];
        float den0 = denb[n * 2], den1 = denb[n * 2 + 1];
        float ta = 0.f, tb = 0.f;
        #pragma unroll
        for (int i = 0; i < 16; i++) {
            ta = fmaf(st[wid][i],      W1s[i * 128 + lane],      ta);
            tb = fmaf(st[wid][16 + i], W1s[i * 128 + 64 + lane], tb);
        }
        ta = fmaxf(ta / den0 + b1[lane], 0.f);
        tb = fmaxf(tb / den1 + b1[64 + lane], 0.f);
        st[wid][32 + lane] = ta;
        st[wid][96 + lane] = tb;
        float acc = 0.f;
        #pragma unroll 8
        for (int k = 0; k < 128; k++) acc = fmaf(st[wid][32 + k], W2s[k * 64 + lane], acc);
        h2h[n * 64 + lane] = __float2half(acc);
        float ps = wave_reduce_sum(acc * as2[lane]);
        float pd = wave_reduce_sum(acc * ad2[lane]);
        if (lane == 0) { al_s[n] = ps; al_d[n] = pd; }
    }
}

// K5a fused: layer-2 aggregation computing its own softmax weights.
__global__ __launch_bounds__(64) void k5a(
    const __half* __restrict__ h2h, const float* __restrict__ als, const float* __restrict__ ald,
    const float* __restrict__ b2, const int* __restrict__ off, const unsigned* __restrict__ ssd,
    float* __restrict__ out2) {
    __shared__ float wbuf[64];
    int d = blockIdx.x;
    int lane = threadIdx.x;
    int beg = off[d], end = off[d + 1];
    float adv = ald[d];
    float es = lrelu(als[d] + adv);
    // phase 1: max over in-edges (distributed), exact
    float m = es;
    for (int i = beg + lane; i < end; i += 64) {
        int s = (int)(ssd[i] & 0xffffu);
        m = fmaxf(m, lrelu(als[s] + adv));
    }
    #pragma unroll
    for (int o = 32; o > 0; o >>= 1) m = fmaxf(m, __shfl_xor(m, o, 64));
    // phase 2: chunked weighted sum
    float ws = __expf(es - m);
    float den0 = ws, den1 = 0.f;
    float a0 = ws * __half2float(h2h[d * 64 + lane]), a1 = 0.f;
    for (int c = beg; c < end; c += 64) {
        int idx = c + lane;
        if (idx < end) {
            int s = (int)(ssd[idx] & 0xffffu);
            wbuf[lane] = __expf(lrelu(als[s] + adv) - m);
        }
        int nchunk = end - c; if (nchunk > 64) nchunk = 64;
        int t = 0;
        for (; t + 7 < nchunk; t += 8) {
            int sv[8]; float wv[8], vv[8];
            #pragma unroll
            for (int q = 0; q < 8; q++) sv[q] = (int)(ssd[c + t + q] & 0xffffu);
            #pragma unroll
            for (int q = 0; q < 8; q++) wv[q] = wbuf[t + q];
            #pragma unroll
            for (int q = 0; q < 8; q++) vv[q] = __half2float(h2h[sv[q] * 64 + lane]);
            den0 += wv[0]; a0 = fmaf(wv[0], vv[0], a0);
            den1 += wv[1]; a1 = fmaf(wv[1], vv[1], a1);
            den0 += wv[2]; a0 = fmaf(wv[2], vv[2], a0);
            den1 += wv[3]; a1 = fmaf(wv[3], vv[3], a1);
            den0 += wv[4]; a0 = fmaf(wv[4], vv[4], a0);
            den1 += wv[5]; a1 = fmaf(wv[5], vv[5], a1);
            den0 += wv[6]; a0 = fmaf(wv[6], vv[6], a0);
            den1 += wv[7]; a1 = fmaf(wv[7], vv[7], a1);
        }
        for (; t < nchunk; t++) {
            int s = (int)(ssd[c + t] & 0xffffu);
            float wv = wbuf[t];
            den0 += wv; a0 = fmaf(wv, __half2float(h2h[s * 64 + lane]), a0);
        }
    }
    out2[d * 64 + lane] = fmaxf((a0 + a1) / (den0 + den1) + b2[lane], 0.f);
}

// K5b: U/V from out2 @ mW1; stored f16. Grid-stride persistent blocks.
__global__ __launch_bounds__(256) void k5b(const float* __restrict__ out2,
                                           const float* __restrict__ mW1,
                                           const float* __restrict__ mb1,
                                           __half* __restrict__ Uh, __half* __restrict__ Vh) {
    __shared__ float Ws[128 * 64];
    __shared__ float o2s[4][64];
    for (int t = threadIdx.x; t < 128 * 64; t += 256) Ws[t] = mW1[t];
    __syncthreads();
    int wid = threadIdx.x >> 6, lane = threadIdx.x & 63;
    for (int n = blockIdx.x * 4 + wid; n < N_NODES; n += gridDim.x * 4) {
        o2s[wid][lane] = out2[n * 64 + lane];
        float au = mb1[lane], av = 0.f;
        #pragma unroll 8
        for (int k = 0; k < 64; k++) {
            float ov = o2s[wid][k];
            au = fmaf(ov, Ws[k * 64 + lane], au);
            av = fmaf(ov, Ws[(64 + k) * 64 + lane], av);
        }
        Uh[n * 64 + lane] = __float2half(au);
        Vh[n * 64 + lane] = __float2half(av);
    }
}

// K7h: edge MLP via f16 MFMA, 32 edges/wave, CSR order (no src partition),
// single-product f16 weights in LDS, XCD swizzle.
__global__ __launch_bounds__(512) void k7h(
    const unsigned* __restrict__ ssd, const int* __restrict__ eid,
    const __half* __restrict__ Uh, const __half* __restrict__ Vh,
    const __half* __restrict__ W2th, const __half* __restrict__ W3th,
    const float* __restrict__ mb2, const float* __restrict__ mb3,
    const float* __restrict__ mW4, const float* __restrict__ mb4,
    float* __restrict__ out)
{
    __shared__ unsigned short Wf[2][4096];
    __shared__ float mbS[3][64];
    const int t = threadIdx.x;
    {
        int mA = t >> 8, kb = (t >> 6) & 3, l = t & 63;
        int src = (mA * 32 + (l & 31)) * 64 + kb * 16 + (l >> 5) * 8;
        *(uint4*)&Wf[0][t * 8] = *(const uint4*)(W2th + src);
        *(uint4*)&Wf[1][t * 8] = *(const uint4*)(W3th + src);
        if (t < 64) mbS[0][t] = mb2[t];
        else if (t < 128) mbS[1][t - 64] = mb3[t - 64];
        else if (t < 192) mbS[2][t - 128] = mW4[t - 128];
    }
    __syncthreads();

    const int nb = gridDim.x, q8 = nb >> 3, r8 = nb & 7;
    const int xcd = blockIdx.x & 7, bidx = blockIdx.x >> 3;
    const int wg = (xcd < r8) ? xcd * (q8 + 1) + bidx
                              : r8 * (q8 + 1) + (xcd - r8) * q8 + bidx;

    const int wid = t >> 6, lane = t & 63;
    const int tbase = wg * 256 + wid * 32;
    const int l31 = lane & 31;
    const int h = lane >> 5;
    const int ksub = h * 8;

    unsigned sd = ssd[tbase + l31];
    int rA = (int)(sd & 0xffffu);
    int cA = (int)(sd >> 16);
    const __half* urow = Uh + (size_t)rA * 64 + ksub;
    const __half* vrow = Vh + (size_t)cA * 64 + ksub;

    f32x16 c2[2];
    #pragma unroll
    for (int mA = 0; mA < 2; mA++)
        #pragma unroll
        for (int q = 0; q < 4; q++) {
            float4 b = *(const float4*)&mbS[0][mA * 32 + 4 * h + q * 8];
            c2[mA][q * 4 + 0] = b.x; c2[mA][q * 4 + 1] = b.y;
            c2[mA][q * 4 + 2] = b.z; c2[mA][q * 4 + 3] = b.w;
        }

    #pragma unroll
    for (int kb = 0; kb < 4; kb++) {
        H8 uvu, vvu, zz;
        uvu.u4 = *(const uint4*)(urow + kb * 16);
        vvu.u4 = *(const uint4*)(vrow + kb * 16);
        {
            half8v s = uvu.v + vvu.v;
            #pragma unroll
            for (int j = 0; j < 8; j++) {
                _Float16 a = s[j];
                zz.v[j] = a > (_Float16)0 ? a : (_Float16)0;
            }
        }
        #pragma unroll
        for (int mA = 0; mA < 2; mA++) {
            const int f = (mA * 4 + kb) * 64 + lane;
            half8v ah = *(const half8v*)&Wf[0][f * 8];
            c2[mA] = __builtin_amdgcn_mfma_f32_32x32x16_f16(ah, zz.v, c2[mA], 0, 0, 0);
        }
    }

    half8v B3[4];
    #pragma unroll
    for (int kbp = 0; kbp < 4; kbp++) {
        const int mAs = kbp >> 1, kbl = kbp & 1;
        half8v t8;
        #pragma unroll
        for (int b = 0; b < 4; b++) {
            float u = fmaxf(c2[mAs][8 * kbl + b], 0.f);
            float v = fmaxf(c2[mAs][8 * kbl + 4 + b], 0.f);
            float su = __shfl_xor(u, 32, 64);
            float sv = __shfl_xor(v, 32, 64);
            t8[b]     = (_Float16)(h ? sv : u);
            t8[4 + b] = (_Float16)(h ? v : su);
        }
        B3[kbp] = t8;
    }

    f32x16 c3[2];
    #pragma unroll
    for (int mA = 0; mA < 2; mA++)
        #pragma unroll
        for (int q = 0; q < 4; q++) {
            float4 b = *(const float4*)&mbS[1][mA * 32 + 4 * h + q * 8];
            c3[mA][q * 4 + 0] = b.x; c3[mA][q * 4 + 1] = b.y;
            c3[mA][q * 4 + 2] = b.z; c3[mA][q * 4 + 3] = b.w;
        }

    #pragma unroll
    for (int kbp = 0; kbp < 4; kbp++) {
        #pragma unroll
        for (int mA = 0; mA < 2; mA++) {
            const int f = (mA * 4 + kbp) * 64 + lane;
            half8v ah = *(const half8v*)&Wf[1][f * 8];
            c3[mA] = __builtin_amdgcn_mfma_f32_32x32x16_f16(ah, B3[kbp], c3[mA], 0, 0, 0);
        }
    }

    float p = 0.f;
    #pragma unroll
    for (int mA = 0; mA < 2; mA++)
        #pragma unroll
        for (int q = 0; q < 4; q++) {
            float4 w4 = *(const float4*)&mbS[2][mA * 32 + 4 * h + q * 8];
            p = fmaf(fmaxf(c3[mA][q * 4 + 0], 0.f), w4.x, p);
            p = fmaf(fmaxf(c3[mA][q * 4 + 1], 0.f), w4.y, p);
            p = fmaf(fmaxf(c3[mA][q * 4 + 2], 0.f), w4.z, p);
            p = fmaf(fmaxf(c3[mA][q * 4 + 3], 0.f), w4.w, p);
        }
    p += __shfl_xor(p, 32, 64);
    int eA = eid[tbase + l31];
    if (lane < 32) out[eA] = p + mb4[0];
}

extern "C" void kernel_launch(void* const* d_in, const int* in_sizes, int n_in,
                              void* d_out, int out_size, void* d_ws, size_t ws_size,
                              hipStream_t stream) {
    const float* x   = (const float*)d_in[0];
    const int*   ei  = (const int*)d_in[1];
    const float* W1  = (const float*)d_in[2];
    const float* as1 = (const float*)d_in[3];
    const float* ad1 = (const float*)d_in[4];
    const float* b1  = (const float*)d_in[5];
    const float* W2  = (const float*)d_in[6];
    const float* as2 = (const float*)d_in[7];
    const float* ad2 = (const float*)d_in[8];
    const float* b2  = (const float*)d_in[9];
    const float* mW1 = (const float*)d_in[10];
    const float* mb1 = (const float*)d_in[11];
    const float* mW2 = (const float*)d_in[12];
    const float* mb2 = (const float*)d_in[13];
    const float* mW3 = (const float*)d_in[14];
    const float* mb3 = (const float*)d_in[15];
    const float* mW4 = (const float*)d_in[16];
    const float* mb4 = (const float*)d_in[17];
    float* out = (float*)d_out;
    const int* row = ei;             // src
    const int* col = ei + N_EDGES;   // dst

    char* w = (char*)d_ws;
    __half*   Uh    = (__half*)w;                     // 6.4 MB, k5b->k7h
    __half*   Vh    = (__half*)(w + 6400000);         // 6.4 MB, k5b->k7h
    float*    out2  = (float*)(w + 12800000);         // 12.8 MB, k5a->k5b
    __half*   h2h   = (__half*)(w + 25600000);        // 6.4 MB, k4n->k5a
    unsigned* ssd   = (unsigned*)(w + 32000000);      // 6.4 MB (CSR order, dst<<16|src)
    int*      eid   = (int*)(w + 38400000);           // 6.4 MB (CSR order)
    unsigned long long* tmp = (unsigned long long*)(w + 44800000);  // 12.8 MB, s_scatter1->k_sort2b
    int*      offp  = (int*)(w + 57800000);           // 0.2 MB + 4
    float*    al_s2 = (float*)(w + 58200064);
    float*    al_d2 = (float*)(w + 58400064);
    int*      bsum  = (int*)(w + 58600064);           // scan temps
    float*    qs    = (float*)(w + 58605056);
    float*    qd    = (float*)(w + 58605184);
    __half*   W2th  = (__half*)(w + 58605312);
    __half*   W3th  = W2th + 4096;                    // 16 KB total
    int*      cnt1  = (int*)(w + 58988992);           // NB1*NBLK*4 = 1.225 MB
    int*      basep1= (int*)(w + 60214000);           // 1.225 MB
    int*      bsumA = (int*)(w + 61439008);           // ~5 KB
    // overlays:
    float*    accx  = (float*)(w + 12800000);         // k3n->k4n (inside out2)
    float*    denb  = (float*)(w + 19200000);
    float*    al_s1 = (float*)(w + 19600000);
    float*    al_d1 = (float*)(w + 20000000);

    k_prep<<<65, 64, 0, stream>>>(W1, as1, ad1, qs, qd, mW2, mW3, W2th, W3th);
    k1n<<<(N_NODES + 255) / 256, 256, 0, stream>>>(x, qs, qd, al_s1, al_d1);
    // per-block level-1 bucket counts (dst>>10)
    s_hist1<<<NBLK, 256, 0, stream>>>(col, cnt1);
    // level-1 bucket bases
    {
        int n1 = NB1 * NBLK;                          // 306250
        int nb1 = (n1 + SCAN_B - 1) / SCAN_B;         // 1197
        int nb2 = (nb1 + SCAN_B - 1) / SCAN_B;        // 5
        g_scan1<<<nb1, SCAN_B, 0, stream>>>(cnt1, basep1, bsumA, n1);
        g_scan1<<<nb2, SCAN_B, 0, stream>>>(bsumA, bsumA, bsum, nb1);
        k_scan2<<<1, SCAN_B, 0, stream>>>(bsum, nb2);
        g_add<<<nb2, SCAN_B, 0, stream>>>(bsumA, bsum, nb1);
        g_add<<<nb1, SCAN_B, 0, stream>>>(basep1, bsumA, n1);
    }
    // hierarchical scatter: edges -> bucket-major tmp -> per-bucket sort (deg+offp internal)
    s_scatter1<<<NBLK, 256, 0, stream>>>(row, col, basep1, tmp);
    k_sort2b<<<NB1, 1024, 0, stream>>>(tmp, basep1, offp, ssd, eid);
    // layer-1 aggregation (computes its own softmax weights in-kernel)
    k3n<<<N_NODES / 8, 256, 0, stream>>>(x, al_s1, al_d1, offp, ssd, accx, denb);
    k4n<<<768, 256, 0, stream>>>(accx, denb, W1, b1, W2, as2, ad2, h2h, al_s2, al_d2);
    // layer-2 aggregation (computes its own softmax weights in-kernel)
    k5a<<<N_NODES, 64, 0, stream>>>(h2h, al_s2, al_d2, b2, offp, ssd, out2);
    k5b<<<1024, 256, 0, stream>>>(out2, mW1, mb1, Uh, Vh);
    k7h<<<NBLK, 512, 0, stream>>>(ssd, eid, Uh, Vh,
                                  W2th, W3th,
                                  mb2, mb3, mW4, mb4, out);
}

// Round 22
// 326.455 us; speedup vs baseline: 1.4198x; 1.0346x over previous
//
#include <hip/hip_runtime.h>
#include <hip/hip_bf16.h>
#include <hip/hip_fp16.h>
#include <math.h>

#define N_NODES 50000
#define N_EDGES 1600000
#define IN_DIM 16
#define HID 64
#define NBLK 6250          // N_EDGES / 256
#define NB1 49             // level-1 scatter buckets (dst>>10)
#define SM_SHIFT 20.0f     // fixed softmax shift; e <= ~10 with 5-sigma margin

typedef __attribute__((ext_vector_type(8))) _Float16 half8v;
typedef __attribute__((ext_vector_type(16))) float f32x16;

union H8 { uint4 u4; half8v v; };

__device__ __forceinline__ float lrelu(float v) { return v > 0.f ? v : 0.2f * v; }

__device__ __forceinline__ float wave_reduce_sum(float v) {
    #pragma unroll
    for (int off = 32; off > 0; off >>= 1) v += __shfl_down(v, off, 64);
    return v;
}

// k_prep: block 64 = qprep (qs/qd vectors); blocks 0..63 = f16 weight transpose rows
__global__ void k_prep(const float* __restrict__ W1, const float* __restrict__ as1,
                       const float* __restrict__ ad1, float* __restrict__ qs, float* __restrict__ qd,
                       const float* __restrict__ mW2, const float* __restrict__ mW3,
                       __half* __restrict__ W2th, __half* __restrict__ W3th) {
    int t = threadIdx.x;
    if (blockIdx.x == 64) {
        if (t < 32) {
            int i = t >> 1, h = t & 1;
            float s = 0.f, d = 0.f;
            for (int c = 0; c < 64; c++) {
                float w = W1[i * 128 + h * 64 + c];
                s = fmaf(w, as1[h * 64 + c], s);
                d = fmaf(w, ad1[h * 64 + c], d);
            }
            qs[i * 2 + h] = s; qd[i * 2 + h] = d;
        }
    } else {
        int b = blockIdx.x;
        W2th[b * 64 + t] = __float2half(mW2[t * 64 + b]);
        W3th[b * 64 + t] = __float2half(mW3[t * 64 + b]);
    }
}

// k1n: alpha terms per node
__global__ void k1n(const float* __restrict__ x, const float* __restrict__ qs,
                    const float* __restrict__ qd, float* __restrict__ al_s, float* __restrict__ al_d) {
    int n = blockIdx.x * 256 + threadIdx.x;
    if (n >= N_NODES) return;
    float s0 = 0.f, s1 = 0.f, d0 = 0.f, d1 = 0.f;
    #pragma unroll
    for (int i = 0; i < IN_DIM; i++) {
        float xv = x[n * IN_DIM + i];
        s0 = fmaf(xv, qs[i * 2 + 0], s0);
        s1 = fmaf(xv, qs[i * 2 + 1], s1);
        d0 = fmaf(xv, qd[i * 2 + 0], d0);
        d1 = fmaf(xv, qd[i * 2 + 1], d1);
    }
    al_s[n * 2 + 0] = s0; al_s[n * 2 + 1] = s1;
    al_d[n * 2 + 0] = d0; al_d[n * 2 + 1] = d1;
}

#define SCAN_B 256
__global__ void k_scan2(int* __restrict__ bsum, int nblocks) {
    __shared__ int sh[SCAN_B];
    int v = (threadIdx.x < nblocks) ? bsum[threadIdx.x] : 0;
    sh[threadIdx.x] = v;
    __syncthreads();
    for (int o = 1; o < SCAN_B; o <<= 1) {
        int t = (threadIdx.x >= o) ? sh[threadIdx.x - o] : 0;
        __syncthreads();
        sh[threadIdx.x] += t;
        __syncthreads();
    }
    if (threadIdx.x < nblocks) bsum[threadIdx.x] = sh[threadIdx.x] - v;
}

__global__ void g_scan1(const int* __restrict__ in, int* __restrict__ out,
                        int* __restrict__ bsum, int n) {
    __shared__ int sh[SCAN_B];
    int gid = blockIdx.x * SCAN_B + threadIdx.x;
    int v = (gid < n) ? in[gid] : 0;
    sh[threadIdx.x] = v;
    __syncthreads();
    for (int o = 1; o < SCAN_B; o <<= 1) {
        int t = (threadIdx.x >= o) ? sh[threadIdx.x - o] : 0;
        __syncthreads();
        sh[threadIdx.x] += t;
        __syncthreads();
    }
    int incl = sh[threadIdx.x];
    if (gid < n) out[gid] = incl - v;
    if (threadIdx.x == SCAN_B - 1) bsum[blockIdx.x] = incl;
}
__global__ void g_add(int* __restrict__ out, const int* __restrict__ bsum, int n) {
    int gid = blockIdx.x * SCAN_B + threadIdx.x;
    if (gid < n) out[gid] += bsum[blockIdx.x];
}

// ---- hierarchical CSR scatter ----
__global__ __launch_bounds__(256) void s_hist1(const int* __restrict__ dst,
                                               int* __restrict__ cnt1) {
    __shared__ int c[NB1];
    if (threadIdx.x < NB1) c[threadIdx.x] = 0;
    __syncthreads();
    int e = blockIdx.x * 256 + threadIdx.x;
    atomicAdd(&c[dst[e] >> 10], 1);
    __syncthreads();
    if (threadIdx.x < NB1) cnt1[threadIdx.x * NBLK + blockIdx.x] = c[threadIdx.x];
}

__global__ __launch_bounds__(256) void s_scatter1(const int* __restrict__ src,
                                                  const int* __restrict__ dst,
                                                  const int* __restrict__ basep1,
                                                  unsigned long long* __restrict__ tmp) {
    __shared__ int c[NB1], base[NB1];
    if (threadIdx.x < NB1) c[threadIdx.x] = 0;
    __syncthreads();
    int e = blockIdx.x * 256 + threadIdx.x;
    int d = dst[e], s = src[e];
    int k = d >> 10;
    int rank = atomicAdd(&c[k], 1);
    __syncthreads();
    if (threadIdx.x < NB1) base[threadIdx.x] = basep1[threadIdx.x * NBLK + blockIdx.x];
    __syncthreads();
    unsigned long long v = ((unsigned long long)e << 32) |
                           (((unsigned)d << 16) | (unsigned)s);
    tmp[base[k] + rank] = v;
}

// k_sort2b: one block per dst-bucket. Pass A: LDS deg count; LDS scan -> offp;
// Pass B: scatter to exact CSR slots via LDS cursors. No global atomics.
__global__ __launch_bounds__(1024) void k_sort2b(const unsigned long long* __restrict__ tmp,
                                                 const int* __restrict__ basep1,
                                                 int* __restrict__ offp,
                                                 unsigned* __restrict__ ssd,
                                                 int* __restrict__ eid) {
    __shared__ int cnt[1024];
    int b = blockIdx.x, t = threadIdx.x;
    int d0 = b << 10;
    int nd = N_NODES - d0; if (nd > 1024) nd = 1024;
    cnt[t] = 0;
    __syncthreads();
    int ebeg = basep1[b * NBLK];
    int eend = (b == NB1 - 1) ? N_EDGES : basep1[(b + 1) * NBLK];
    for (int i = ebeg + t; i < eend; i += 1024) {
        unsigned lo = (unsigned)tmp[i];
        atomicAdd(&cnt[(lo >> 16) - d0], 1);
    }
    __syncthreads();
    int v = cnt[t];
    for (int o = 1; o < 1024; o <<= 1) {
        int tv = (t >= o) ? cnt[t - o] : 0;
        __syncthreads();
        cnt[t] += tv;
        __syncthreads();
    }
    int cur = ebeg + cnt[t] - v;     // exclusive prefix -> global CSR offset
    if (t < nd) offp[d0 + t] = cur;
    if (b == NB1 - 1 && t == 0) offp[N_NODES] = N_EDGES;
    __syncthreads();
    cnt[t] = cur;
    __syncthreads();
    for (int i = ebeg + t; i < eend; i += 1024) {
        unsigned long long v64 = tmp[i];
        unsigned lo = (unsigned)v64;
        int pos = atomicAdd(&cnt[(lo >> 16) - d0], 1);
        ssd[pos] = lo;
        eid[pos] = (int)(v64 >> 32);
    }
}

// K3n: layer-1 aggregation, fixed-shift softmax (no max pass).
// Per dst: 32 lanes (head = sub>>4, ch = sub&15). Per-16-edge chunks, each of
// the 32 lanes computes one (edge,head) exp, broadcast via shfl.
__global__ void k3n(const float* __restrict__ x, const float* __restrict__ als,
                    const float* __restrict__ ald,
                    const int* __restrict__ off, const unsigned* __restrict__ ssd,
                    float* __restrict__ accx, float* __restrict__ denb) {
    int wid = threadIdx.x >> 6, lane = threadIdx.x & 63;
    int half = lane >> 5, sub = lane & 31, head = sub >> 4, ch = sub & 15;
    int d = blockIdx.x * 8 + wid * 2 + half;
    if (d >= N_NODES) return;
    int beg = off[d], end = off[d + 1];
    float adv = ald[d * 2 + head];
    float es = lrelu(als[d * 2 + head] + adv);
    float ws = __expf(es - SM_SHIFT);
    float den0 = ws, den1 = 0.f;
    float a0 = ws * x[d * IN_DIM + ch], a1 = 0.f;
    const int srcb = (lane & 32) + (head << 4);   // lane holding w for my head, edge t
    for (int c = beg; c < end; c += 16) {
        int nchunk = end - c; if (nchunk > 16) nchunk = 16;
        float wexp = 0.f;
        if ((sub & 15) < nchunk) {
            int s = (int)(ssd[c + (sub & 15)] & 0xffffu);
            wexp = __expf(lrelu(als[s * 2 + head] + adv) - SM_SHIFT);
        }
        if (nchunk == 16) {
            int sv[16];
            #pragma unroll
            for (int t = 0; t < 16; t++) sv[t] = (int)(ssd[c + t] & 0xffffu);
            #pragma unroll
            for (int t = 0; t < 16; t++) {
                float wv = __shfl(wexp, srcb + t, 64);
                float xv = x[sv[t] * IN_DIM + ch];
                if (t & 1) { den1 += wv; a1 = fmaf(wv, xv, a1); }
                else       { den0 += wv; a0 = fmaf(wv, xv, a0); }
            }
        } else {
            for (int t = 0; t < nchunk; t++) {
                float wv = __shfl(wexp, srcb + t, 64);
                int s = (int)(ssd[c + t] & 0xffffu);
                den0 += wv; a0 = fmaf(wv, x[s * IN_DIM + ch], a0);
            }
        }
    }
    accx[d * 32 + sub] = a0 + a1;
    if ((sub & 15) == 0) denb[d * 2 + head] = den0 + den1;
}

// K4n: fused out1-expand then @ W2 -> h2 (f16), al_s2/al_d2. Grid-stride.
__global__ __launch_bounds__(256) void k4n(
    const float* __restrict__ accx, const float* __restrict__ denb,
    const float* __restrict__ W1, const float* __restrict__ b1,
    const float* __restrict__ W2, const float* __restrict__ as2, const float* __restrict__ ad2,
    __half* __restrict__ h2h, float* __restrict__ al_s, float* __restrict__ al_d) {
    __shared__ float W1s[16 * 128];
    __shared__ float W2s[128 * 64];
    __shared__ float st[4][160];
    for (int t = threadIdx.x; t < 16 * 128; t += 256) W1s[t] = W1[t];
    for (int t = threadIdx.x; t < 128 * 64; t += 256) W2s[t] = W2[t];
    __syncthreads();
    int wid = threadIdx.x >> 6, lane = threadIdx.x & 63;
    for (int n = blockIdx.x * 4 + wid; n < N_NODES; n += gridDim.x * 4) {
        if (lane < 32) st[wid][lane] = accx[n * 32 + lane];
        float den0 = denb[n * 2], den1 = denb[n * 2 + 1];
        float ta = 0.f, tb = 0.f;
        #pragma unroll
        for (int i = 0; i < 16; i++) {
            ta = fmaf(st[wid][i],      W1s[i * 128 + lane],      ta);
            tb = fmaf(st[wid][16 + i], W1s[i * 128 + 64 + lane], tb);
        }
        ta = fmaxf(ta / den0 + b1[lane], 0.f);
        tb = fmaxf(tb / den1 + b1[64 + lane], 0.f);
        st[wid][32 + lane] = ta;
        st[wid][96 + lane] = tb;
        float acc = 0.f;
        #pragma unroll 8
        for (int k = 0; k < 128; k++) acc = fmaf(st[wid][32 + k], W2s[k * 64 + lane], acc);
        h2h[n * 64 + lane] = __float2half(acc);
        float ps = wave_reduce_sum(acc * as2[lane]);
        float pd = wave_reduce_sum(acc * ad2[lane]);
        if (lane == 0) { al_s[n] = ps; al_d[n] = pd; }
    }
}

// K5a: layer-2 aggregation, fixed-shift softmax (no max pass).
__global__ __launch_bounds__(64) void k5a(
    const __half* __restrict__ h2h, const float* __restrict__ als, const float* __restrict__ ald,
    const float* __restrict__ b2, const int* __restrict__ off, const unsigned* __restrict__ ssd,
    float* __restrict__ out2) {
    __shared__ float wbuf[64];
    int d = blockIdx.x;
    int lane = threadIdx.x;
    int beg = off[d], end = off[d + 1];
    float adv = ald[d];
    float es = lrelu(als[d] + adv);
    float ws = __expf(es - SM_SHIFT);
    float den0 = ws, den1 = 0.f;
    float a0 = ws * __half2float(h2h[d * 64 + lane]), a1 = 0.f;
    for (int c = beg; c < end; c += 64) {
        int idx = c + lane;
        if (idx < end) {
            int s = (int)(ssd[idx] & 0xffffu);
            wbuf[lane] = __expf(lrelu(als[s] + adv) - SM_SHIFT);
        }
        int nchunk = end - c; if (nchunk > 64) nchunk = 64;
        int t = 0;
        for (; t + 7 < nchunk; t += 8) {
            int sv[8]; float wv[8], vv[8];
            #pragma unroll
            for (int q = 0; q < 8; q++) sv[q] = (int)(ssd[c + t + q] & 0xffffu);
            #pragma unroll
            for (int q = 0; q < 8; q++) wv[q] = wbuf[t + q];
            #pragma unroll
            for (int q = 0; q < 8; q++) vv[q] = __half2float(h2h[sv[q] * 64 + lane]);
            den0 += wv[0]; a0 = fmaf(wv[0], vv[0], a0);
            den1 += wv[1]; a1 = fmaf(wv[1], vv[1], a1);
            den0 += wv[2]; a0 = fmaf(wv[2], vv[2], a0);
            den1 += wv[3]; a1 = fmaf(wv[3], vv[3], a1);
            den0 += wv[4]; a0 = fmaf(wv[4], vv[4], a0);
            den1 += wv[5]; a1 = fmaf(wv[5], vv[5], a1);
            den0 += wv[6]; a0 = fmaf(wv[6], vv[6], a0);
            den1 += wv[7]; a1 = fmaf(wv[7], vv[7], a1);
        }
        for (; t < nchunk; t++) {
            int s = (int)(ssd[c + t] & 0xffffu);
            float wv = wbuf[t];
            den0 += wv; a0 = fmaf(wv, __half2float(h2h[s * 64 + lane]), a0);
        }
    }
    out2[d * 64 + lane] = fmaxf((a0 + a1) / (den0 + den1) + b2[lane], 0.f);
}

// K5b: U/V from out2 @ mW1; stored f16. Grid-stride persistent blocks.
__global__ __launch_bounds__(256) void k5b(const float* __restrict__ out2,
                                           const float* __restrict__ mW1,
                                           const float* __restrict__ mb1,
                                           __half* __restrict__ Uh, __half* __restrict__ Vh) {
    __shared__ float Ws[128 * 64];
    __shared__ float o2s[4][64];
    for (int t = threadIdx.x; t < 128 * 64; t += 256) Ws[t] = mW1[t];
    __syncthreads();
    int wid = threadIdx.x >> 6, lane = threadIdx.x & 63;
    for (int n = blockIdx.x * 4 + wid; n < N_NODES; n += gridDim.x * 4) {
        o2s[wid][lane] = out2[n * 64 + lane];
        float au = mb1[lane], av = 0.f;
        #pragma unroll 8
        for (int k = 0; k < 64; k++) {
            float ov = o2s[wid][k];
            au = fmaf(ov, Ws[k * 64 + lane], au);
            av = fmaf(ov, Ws[(64 + k) * 64 + lane], av);
        }
        Uh[n * 64 + lane] = __float2half(au);
        Vh[n * 64 + lane] = __float2half(av);
    }
}

// K7h: edge MLP via f16 MFMA, 32 edges/wave, CSR order,
// single-product f16 weights in LDS, XCD swizzle.
__global__ __launch_bounds__(512) void k7h(
    const unsigned* __restrict__ ssd, const int* __restrict__ eid,
    const __half* __restrict__ Uh, const __half* __restrict__ Vh,
    const __half* __restrict__ W2th, const __half* __restrict__ W3th,
    const float* __restrict__ mb2, const float* __restrict__ mb3,
    const float* __restrict__ mW4, const float* __restrict__ mb4,
    float* __restrict__ out)
{
    __shared__ unsigned short Wf[2][4096];
    __shared__ float mbS[3][64];
    const int t = threadIdx.x;
    {
        int mA = t >> 8, kb = (t >> 6) & 3, l = t & 63;
        int src = (mA * 32 + (l & 31)) * 64 + kb * 16 + (l >> 5) * 8;
        *(uint4*)&Wf[0][t * 8] = *(const uint4*)(W2th + src);
        *(uint4*)&Wf[1][t * 8] = *(const uint4*)(W3th + src);
        if (t < 64) mbS[0][t] = mb2[t];
        else if (t < 128) mbS[1][t - 64] = mb3[t - 64];
        else if (t < 192) mbS[2][t - 128] = mW4[t - 128];
    }
    __syncthreads();

    const int nb = gridDim.x, q8 = nb >> 3, r8 = nb & 7;
    const int xcd = blockIdx.x & 7, bidx = blockIdx.x >> 3;
    const int wg = (xcd < r8) ? xcd * (q8 + 1) + bidx
                              : r8 * (q8 + 1) + (xcd - r8) * q8 + bidx;

    const int wid = t >> 6, lane = t & 63;
    const int tbase = wg * 256 + wid * 32;
    const int l31 = lane & 31;
    const int h = lane >> 5;
    const int ksub = h * 8;

    unsigned sd = ssd[tbase + l31];
    int rA = (int)(sd & 0xffffu);
    int cA = (int)(sd >> 16);
    const __half* urow = Uh + (size_t)rA * 64 + ksub;
    const __half* vrow = Vh + (size_t)cA * 64 + ksub;

    f32x16 c2[2];
    #pragma unroll
    for (int mA = 0; mA < 2; mA++)
        #pragma unroll
        for (int q = 0; q < 4; q++) {
            float4 b = *(const float4*)&mbS[0][mA * 32 + 4 * h + q * 8];
            c2[mA][q * 4 + 0] = b.x; c2[mA][q * 4 + 1] = b.y;
            c2[mA][q * 4 + 2] = b.z; c2[mA][q * 4 + 3] = b.w;
        }

    #pragma unroll
    for (int kb = 0; kb < 4; kb++) {
        H8 uvu, vvu, zz;
        uvu.u4 = *(const uint4*)(urow + kb * 16);
        vvu.u4 = *(const uint4*)(vrow + kb * 16);
        {
            half8v s = uvu.v + vvu.v;
            #pragma unroll
            for (int j = 0; j < 8; j++) {
                _Float16 a = s[j];
                zz.v[j] = a > (_Float16)0 ? a : (_Float16)0;
            }
        }
        #pragma unroll
        for (int mA = 0; mA < 2; mA++) {
            const int f = (mA * 4 + kb) * 64 + lane;
            half8v ah = *(const half8v*)&Wf[0][f * 8];
            c2[mA] = __builtin_amdgcn_mfma_f32_32x32x16_f16(ah, zz.v, c2[mA], 0, 0, 0);
        }
    }

    half8v B3[4];
    #pragma unroll
    for (int kbp = 0; kbp < 4; kbp++) {
        const int mAs = kbp >> 1, kbl = kbp & 1;
        half8v t8;
        #pragma unroll
        for (int b = 0; b < 4; b++) {
            float u = fmaxf(c2[mAs][8 * kbl + b], 0.f);
            float v = fmaxf(c2[mAs][8 * kbl + 4 + b], 0.f);
            float su = __shfl_xor(u, 32, 64);
            float sv = __shfl_xor(v, 32, 64);
            t8[b]     = (_Float16)(h ? sv : u);
            t8[4 + b] = (_Float16)(h ? v : su);
        }
        B3[kbp] = t8;
    }

    f32x16 c3[2];
    #pragma unroll
    for (int mA = 0; mA < 2; mA++)
        #pragma unroll
        for (int q = 0; q < 4; q++) {
            float4 b = *(const float4*)&mbS[1][mA * 32 + 4 * h + q * 8];
            c3[mA][q * 4 + 0] = b.x; c3[mA][q * 4 + 1] = b.y;
            c3[mA][q * 4 + 2] = b.z; c3[mA][q * 4 + 3] = b.w;
        }

    #pragma unroll
    for (int kbp = 0; kbp < 4; kbp++) {
        #pragma unroll
        for (int mA = 0; mA < 2; mA++) {
            const int f = (mA * 4 + kbp) * 64 + lane;
            half8v ah = *(const half8v*)&Wf[1][f * 8];
            c3[mA] = __builtin_amdgcn_mfma_f32_32x32x16_f16(ah, B3[kbp], c3[mA], 0, 0, 0);
        }
    }

    float p = 0.f;
    #pragma unroll
    for (int mA = 0; mA < 2; mA++)
        #pragma unroll
        for (int q = 0; q < 4; q++) {
            float4 w4 = *(const float4*)&mbS[2][mA * 32 + 4 * h + q * 8];
            p = fmaf(fmaxf(c3[mA][q * 4 + 0], 0.f), w4.x, p);
            p = fmaf(fmaxf(c3[mA][q * 4 + 1], 0.f), w4.y, p);
            p = fmaf(fmaxf(c3[mA][q * 4 + 2], 0.f), w4.z, p);
            p = fmaf(fmaxf(c3[mA][q * 4 + 3], 0.f), w4.w, p);
        }
    p += __shfl_xor(p, 32, 64);
    int eA = eid[tbase + l31];
    if (lane < 32) out[eA] = p + mb4[0];
}

extern "C" void kernel_launch(void* const* d_in, const int* in_sizes, int n_in,
                              void* d_out, int out_size, void* d_ws, size_t ws_size,
                              hipStream_t stream) {
    const float* x   = (const float*)d_in[0];
    const int*   ei  = (const int*)d_in[1];
    const float* W1  = (const float*)d_in[2];
    const float* as1 = (const float*)d_in[3];
    const float* ad1 = (const float*)d_in[4];
    const float* b1  = (const float*)d_in[5];
    const float* W2  = (const float*)d_in[6];
    const float* as2 = (const float*)d_in[7];
    const float* ad2 = (const float*)d_in[8];
    const float* b2  = (const float*)d_in[9];
    const float* mW1 = (const float*)d_in[10];
    const float* mb1 = (const float*)d_in[11];
    const float* mW2 = (const float*)d_in[12];
    const float* mb2 = (const float*)d_in[13];
    const float* mW3 = (const float*)d_in[14];
    const float* mb3 = (const float*)d_in[15];
    const float* mW4 = (const float*)d_in[16];
    const float* mb4 = (const float*)d_in[17];
    float* out = (float*)d_out;
    const int* row = ei;             // src
    const int* col = ei + N_EDGES;   // dst

    char* w = (char*)d_ws;
    __half*   Uh    = (__half*)w;                     // 6.4 MB, k5b->k7h
    __half*   Vh    = (__half*)(w + 6400000);         // 6.4 MB, k5b->k7h
    float*    out2  = (float*)(w + 12800000);         // 12.8 MB, k5a->k5b
    __half*   h2h   = (__half*)(w + 25600000);        // 6.4 MB, k4n->k5a
    unsigned* ssd   = (unsigned*)(w + 32000000);      // 6.4 MB (CSR order, dst<<16|src)
    int*      eid   = (int*)(w + 38400000);           // 6.4 MB (CSR order)
    unsigned long long* tmp = (unsigned long long*)(w + 44800000);  // 12.8 MB, s_scatter1->k_sort2b
    int*      offp  = (int*)(w + 57800000);           // 0.2 MB + 4
    float*    al_s2 = (float*)(w + 58200064);
    float*    al_d2 = (float*)(w + 58400064);
    int*      bsum  = (int*)(w + 58600064);           // scan temps
    float*    qs    = (float*)(w + 58605056);
    float*    qd    = (float*)(w + 58605184);
    __half*   W2th  = (__half*)(w + 58605312);
    __half*   W3th  = W2th + 4096;                    // 16 KB total
    int*      cnt1  = (int*)(w + 58988992);           // NB1*NBLK*4 = 1.225 MB
    int*      basep1= (int*)(w + 60214000);           // 1.225 MB
    int*      bsumA = (int*)(w + 61439008);           // ~5 KB
    // overlays:
    float*    accx  = (float*)(w + 12800000);         // k3n->k4n (inside out2)
    float*    denb  = (float*)(w + 19200000);
    float*    al_s1 = (float*)(w + 19600000);
    float*    al_d1 = (float*)(w + 20000000);

    k_prep<<<65, 64, 0, stream>>>(W1, as1, ad1, qs, qd, mW2, mW3, W2th, W3th);
    k1n<<<(N_NODES + 255) / 256, 256, 0, stream>>>(x, qs, qd, al_s1, al_d1);
    // per-block level-1 bucket counts (dst>>10)
    s_hist1<<<NBLK, 256, 0, stream>>>(col, cnt1);
    // level-1 bucket bases
    {
        int n1 = NB1 * NBLK;                          // 306250
        int nb1 = (n1 + SCAN_B - 1) / SCAN_B;         // 1197
        int nb2 = (nb1 + SCAN_B - 1) / SCAN_B;        // 5
        g_scan1<<<nb1, SCAN_B, 0, stream>>>(cnt1, basep1, bsumA, n1);
        g_scan1<<<nb2, SCAN_B, 0, stream>>>(bsumA, bsumA, bsum, nb1);
        k_scan2<<<1, SCAN_B, 0, stream>>>(bsum, nb2);
        g_add<<<nb2, SCAN_B, 0, stream>>>(bsumA, bsum, nb1);
        g_add<<<nb1, SCAN_B, 0, stream>>>(basep1, bsumA, n1);
    }
    // hierarchical scatter: edges -> bucket-major tmp -> per-bucket sort (deg+offp internal)
    s_scatter1<<<NBLK, 256, 0, stream>>>(row, col, basep1, tmp);
    k_sort2b<<<NB1, 1024, 0, stream>>>(tmp, basep1, offp, ssd, eid);
    // layer-1 aggregation (fixed-shift softmax, in-kernel weights)
    k3n<<<N_NODES / 8, 256, 0, stream>>>(x, al_s1, al_d1, offp, ssd, accx, denb);
    k4n<<<768, 256, 0, stream>>>(accx, denb, W1, b1, W2, as2, ad2, h2h, al_s2, al_d2);
    // layer-2 aggregation (fixed-shift softmax, in-kernel weights)
    k5a<<<N_NODES, 64, 0, stream>>>(h2h, al_s2, al_d2, b2, offp, ssd, out2);
    k5b<<<1024, 256, 0, stream>>>(out2, mW1, mb1, Uh, Vh);
    k7h<<<NBLK, 512, 0, stream>>>(ssd, eid, Uh, Vh,
                                  W2th, W3th,
                                  mb2, mb3, mW4, mb4, out);
}

// Round 23
// 307.239 us; speedup vs baseline: 1.5086x; 1.0625x over previous
//
#include <hip/hip_runtime.h>
#include <hip/hip_bf16.h>
#include <hip/hip_fp16.h>
#include <math.h>

#define N_NODES 50000
#define N_EDGES 1600000
#define IN_DIM 16
#define HID 64
#define NBLK 6250          // N_EDGES / 256
#define NB1 49             // level-1 scatter buckets (dst>>10)
#define SM_SHIFT 20.0f     // fixed softmax shift; e <= ~10 with 5-sigma margin

typedef __attribute__((ext_vector_type(8))) _Float16 half8v;
typedef __attribute__((ext_vector_type(16))) float f32x16;

union H8 { uint4 u4; half8v v; };

__device__ __forceinline__ float lrelu(float v) { return v > 0.f ? v : 0.2f * v; }

__device__ __forceinline__ float wave_reduce_sum(float v) {
    #pragma unroll
    for (int off = 32; off > 0; off >>= 1) v += __shfl_down(v, off, 64);
    return v;
}

// k_prep: block 64 = qprep (qs/qd vectors); blocks 0..63 = f16 weight transpose rows
__global__ void k_prep(const float* __restrict__ W1, const float* __restrict__ as1,
                       const float* __restrict__ ad1, float* __restrict__ qs, float* __restrict__ qd,
                       const float* __restrict__ mW2, const float* __restrict__ mW3,
                       __half* __restrict__ W2th, __half* __restrict__ W3th) {
    int t = threadIdx.x;
    if (blockIdx.x == 64) {
        if (t < 32) {
            int i = t >> 1, h = t & 1;
            float s = 0.f, d = 0.f;
            for (int c = 0; c < 64; c++) {
                float w = W1[i * 128 + h * 64 + c];
                s = fmaf(w, as1[h * 64 + c], s);
                d = fmaf(w, ad1[h * 64 + c], d);
            }
            qs[i * 2 + h] = s; qd[i * 2 + h] = d;
        }
    } else {
        int b = blockIdx.x;
        W2th[b * 64 + t] = __float2half(mW2[t * 64 + b]);
        W3th[b * 64 + t] = __float2half(mW3[t * 64 + b]);
    }
}

// k1n: alpha terms per node
__global__ void k1n(const float* __restrict__ x, const float* __restrict__ qs,
                    const float* __restrict__ qd, float* __restrict__ al_s, float* __restrict__ al_d) {
    int n = blockIdx.x * 256 + threadIdx.x;
    if (n >= N_NODES) return;
    float s0 = 0.f, s1 = 0.f, d0 = 0.f, d1 = 0.f;
    #pragma unroll
    for (int i = 0; i < IN_DIM; i++) {
        float xv = x[n * IN_DIM + i];
        s0 = fmaf(xv, qs[i * 2 + 0], s0);
        s1 = fmaf(xv, qs[i * 2 + 1], s1);
        d0 = fmaf(xv, qd[i * 2 + 0], d0);
        d1 = fmaf(xv, qd[i * 2 + 1], d1);
    }
    al_s[n * 2 + 0] = s0; al_s[n * 2 + 1] = s1;
    al_d[n * 2 + 0] = d0; al_d[n * 2 + 1] = d1;
}

#define SCAN_B 256
__global__ void k_scan2(int* __restrict__ bsum, int nblocks) {
    __shared__ int sh[SCAN_B];
    int v = (threadIdx.x < nblocks) ? bsum[threadIdx.x] : 0;
    sh[threadIdx.x] = v;
    __syncthreads();
    for (int o = 1; o < SCAN_B; o <<= 1) {
        int t = (threadIdx.x >= o) ? sh[threadIdx.x - o] : 0;
        __syncthreads();
        sh[threadIdx.x] += t;
        __syncthreads();
    }
    if (threadIdx.x < nblocks) bsum[threadIdx.x] = sh[threadIdx.x] - v;
}

__global__ void g_scan1(const int* __restrict__ in, int* __restrict__ out,
                        int* __restrict__ bsum, int n) {
    __shared__ int sh[SCAN_B];
    int gid = blockIdx.x * SCAN_B + threadIdx.x;
    int v = (gid < n) ? in[gid] : 0;
    sh[threadIdx.x] = v;
    __syncthreads();
    for (int o = 1; o < SCAN_B; o <<= 1) {
        int t = (threadIdx.x >= o) ? sh[threadIdx.x - o] : 0;
        __syncthreads();
        sh[threadIdx.x] += t;
        __syncthreads();
    }
    int incl = sh[threadIdx.x];
    if (gid < n) out[gid] = incl - v;
    if (threadIdx.x == SCAN_B - 1) bsum[blockIdx.x] = incl;
}
__global__ void g_add(int* __restrict__ out, const int* __restrict__ bsum, int n) {
    int gid = blockIdx.x * SCAN_B + threadIdx.x;
    if (gid < n) out[gid] += bsum[blockIdx.x];
}

// ---- hierarchical CSR scatter (u32 payload: dst<<16 | src; no edge ids) ----
__global__ __launch_bounds__(256) void s_hist1(const int* __restrict__ dst,
                                               int* __restrict__ cnt1) {
    __shared__ int c[NB1];
    if (threadIdx.x < NB1) c[threadIdx.x] = 0;
    __syncthreads();
    int e = blockIdx.x * 256 + threadIdx.x;
    atomicAdd(&c[dst[e] >> 10], 1);
    __syncthreads();
    if (threadIdx.x < NB1) cnt1[threadIdx.x * NBLK + blockIdx.x] = c[threadIdx.x];
}

__global__ __launch_bounds__(256) void s_scatter1(const int* __restrict__ src,
                                                  const int* __restrict__ dst,
                                                  const int* __restrict__ basep1,
                                                  unsigned* __restrict__ tmp) {
    __shared__ int c[NB1], base[NB1];
    if (threadIdx.x < NB1) c[threadIdx.x] = 0;
    __syncthreads();
    int e = blockIdx.x * 256 + threadIdx.x;
    int d = dst[e], s = src[e];
    int k = d >> 10;
    int rank = atomicAdd(&c[k], 1);
    __syncthreads();
    if (threadIdx.x < NB1) base[threadIdx.x] = basep1[threadIdx.x * NBLK + blockIdx.x];
    __syncthreads();
    tmp[base[k] + rank] = ((unsigned)d << 16) | (unsigned)s;
}

// k_sort2b: one block per dst-bucket. Pass A: LDS deg count; LDS scan -> offp;
// Pass B: scatter to exact CSR slots via LDS cursors. No global atomics.
__global__ __launch_bounds__(1024) void k_sort2b(const unsigned* __restrict__ tmp,
                                                 const int* __restrict__ basep1,
                                                 int* __restrict__ offp,
                                                 unsigned* __restrict__ ssd) {
    __shared__ int cnt[1024];
    int b = blockIdx.x, t = threadIdx.x;
    int d0 = b << 10;
    int nd = N_NODES - d0; if (nd > 1024) nd = 1024;
    cnt[t] = 0;
    __syncthreads();
    int ebeg = basep1[b * NBLK];
    int eend = (b == NB1 - 1) ? N_EDGES : basep1[(b + 1) * NBLK];
    for (int i = ebeg + t; i < eend; i += 1024) {
        atomicAdd(&cnt[(tmp[i] >> 16) - d0], 1);
    }
    __syncthreads();
    int v = cnt[t];
    for (int o = 1; o < 1024; o <<= 1) {
        int tv = (t >= o) ? cnt[t - o] : 0;
        __syncthreads();
        cnt[t] += tv;
        __syncthreads();
    }
    int cur = ebeg + cnt[t] - v;     // exclusive prefix -> global CSR offset
    if (t < nd) offp[d0 + t] = cur;
    if (b == NB1 - 1 && t == 0) offp[N_NODES] = N_EDGES;
    __syncthreads();
    cnt[t] = cur;
    __syncthreads();
    for (int i = ebeg + t; i < eend; i += 1024) {
        unsigned lo = tmp[i];
        int pos = atomicAdd(&cnt[(lo >> 16) - d0], 1);
        ssd[pos] = lo;
    }
}

// K3n: layer-1 aggregation, fixed-shift softmax (no max pass).
__global__ void k3n(const float* __restrict__ x, const float* __restrict__ als,
                    const float* __restrict__ ald,
                    const int* __restrict__ off, const unsigned* __restrict__ ssd,
                    float* __restrict__ accx, float* __restrict__ denb) {
    int wid = threadIdx.x >> 6, lane = threadIdx.x & 63;
    int half = lane >> 5, sub = lane & 31, head = sub >> 4, ch = sub & 15;
    int d = blockIdx.x * 8 + wid * 2 + half;
    if (d >= N_NODES) return;
    int beg = off[d], end = off[d + 1];
    float adv = ald[d * 2 + head];
    float es = lrelu(als[d * 2 + head] + adv);
    float ws = __expf(es - SM_SHIFT);
    float den0 = ws, den1 = 0.f;
    float a0 = ws * x[d * IN_DIM + ch], a1 = 0.f;
    const int srcb = (lane & 32) + (head << 4);   // lane holding w for my head, edge t
    for (int c = beg; c < end; c += 16) {
        int nchunk = end - c; if (nchunk > 16) nchunk = 16;
        float wexp = 0.f;
        if ((sub & 15) < nchunk) {
            int s = (int)(ssd[c + (sub & 15)] & 0xffffu);
            wexp = __expf(lrelu(als[s * 2 + head] + adv) - SM_SHIFT);
        }
        if (nchunk == 16) {
            int sv[16];
            #pragma unroll
            for (int t = 0; t < 16; t++) sv[t] = (int)(ssd[c + t] & 0xffffu);
            #pragma unroll
            for (int t = 0; t < 16; t++) {
                float wv = __shfl(wexp, srcb + t, 64);
                float xv = x[sv[t] * IN_DIM + ch];
                if (t & 1) { den1 += wv; a1 = fmaf(wv, xv, a1); }
                else       { den0 += wv; a0 = fmaf(wv, xv, a0); }
            }
        } else {
            for (int t = 0; t < nchunk; t++) {
                float wv = __shfl(wexp, srcb + t, 64);
                int s = (int)(ssd[c + t] & 0xffffu);
                den0 += wv; a0 = fmaf(wv, x[s * IN_DIM + ch], a0);
            }
        }
    }
    accx[d * 32 + sub] = a0 + a1;
    if ((sub & 15) == 0) denb[d * 2 + head] = den0 + den1;
}

// K4n: fused out1-expand then @ W2 -> h2 (f16), al_s2/al_d2. Grid-stride.
__global__ __launch_bounds__(256) void k4n(
    const float* __restrict__ accx, const float* __restrict__ denb,
    const float* __restrict__ W1, const float* __restrict__ b1,
    const float* __restrict__ W2, const float* __restrict__ as2, const float* __restrict__ ad2,
    __half* __restrict__ h2h, float* __restrict__ al_s, float* __restrict__ al_d) {
    __shared__ float W1s[16 * 128];
    __shared__ float W2s[128 * 64];
    __shared__ float st[4][160];
    for (int t = threadIdx.x; t < 16 * 128; t += 256) W1s[t] = W1[t];
    for (int t = threadIdx.x; t < 128 * 64; t += 256) W2s[t] = W2[t];
    __syncthreads();
    int wid = threadIdx.x >> 6, lane = threadIdx.x & 63;
    for (int n = blockIdx.x * 4 + wid; n < N_NODES; n += gridDim.x * 4) {
        if (lane < 32) st[wid][lane] = accx[n * 32 + lane];
        float den0 = denb[n * 2], den1 = denb[n * 2 + 1];
        float ta = 0.f, tb = 0.f;
        #pragma unroll
        for (int i = 0; i < 16; i++) {
            ta = fmaf(st[wid][i],      W1s[i * 128 + lane],      ta);
            tb = fmaf(st[wid][16 + i], W1s[i * 128 + 64 + lane], tb);
        }
        ta = fmaxf(ta / den0 + b1[lane], 0.f);
        tb = fmaxf(tb / den1 + b1[64 + lane], 0.f);
        st[wid][32 + lane] = ta;
        st[wid][96 + lane] = tb;
        float acc = 0.f;
        #pragma unroll 8
        for (int k = 0; k < 128; k++) acc = fmaf(st[wid][32 + k], W2s[k * 64 + lane], acc);
        h2h[n * 64 + lane] = __float2half(acc);
        float ps = wave_reduce_sum(acc * as2[lane]);
        float pd = wave_reduce_sum(acc * ad2[lane]);
        if (lane == 0) { al_s[n] = ps; al_d[n] = pd; }
    }
}

// K5a: layer-2 aggregation, fixed-shift softmax (no max pass).
__global__ __launch_bounds__(64) void k5a(
    const __half* __restrict__ h2h, const float* __restrict__ als, const float* __restrict__ ald,
    const float* __restrict__ b2, const int* __restrict__ off, const unsigned* __restrict__ ssd,
    float* __restrict__ out2) {
    __shared__ float wbuf[64];
    int d = blockIdx.x;
    int lane = threadIdx.x;
    int beg = off[d], end = off[d + 1];
    float adv = ald[d];
    float es = lrelu(als[d] + adv);
    float ws = __expf(es - SM_SHIFT);
    float den0 = ws, den1 = 0.f;
    float a0 = ws * __half2float(h2h[d * 64 + lane]), a1 = 0.f;
    for (int c = beg; c < end; c += 64) {
        int idx = c + lane;
        if (idx < end) {
            int s = (int)(ssd[idx] & 0xffffu);
            wbuf[lane] = __expf(lrelu(als[s] + adv) - SM_SHIFT);
        }
        int nchunk = end - c; if (nchunk > 64) nchunk = 64;
        int t = 0;
        for (; t + 7 < nchunk; t += 8) {
            int sv[8]; float wv[8], vv[8];
            #pragma unroll
            for (int q = 0; q < 8; q++) sv[q] = (int)(ssd[c + t + q] & 0xffffu);
            #pragma unroll
            for (int q = 0; q < 8; q++) wv[q] = wbuf[t + q];
            #pragma unroll
            for (int q = 0; q < 8; q++) vv[q] = __half2float(h2h[sv[q] * 64 + lane]);
            den0 += wv[0]; a0 = fmaf(wv[0], vv[0], a0);
            den1 += wv[1]; a1 = fmaf(wv[1], vv[1], a1);
            den0 += wv[2]; a0 = fmaf(wv[2], vv[2], a0);
            den1 += wv[3]; a1 = fmaf(wv[3], vv[3], a1);
            den0 += wv[4]; a0 = fmaf(wv[4], vv[4], a0);
            den1 += wv[5]; a1 = fmaf(wv[5], vv[5], a1);
            den0 += wv[6]; a0 = fmaf(wv[6], vv[6], a0);
            den1 += wv[7]; a1 = fmaf(wv[7], vv[7], a1);
        }
        for (; t < nchunk; t++) {
            int s = (int)(ssd[c + t] & 0xffffu);
            float wv = wbuf[t];
            den0 += wv; a0 = fmaf(wv, __half2float(h2h[s * 64 + lane]), a0);
        }
    }
    out2[d * 64 + lane] = fmaxf((a0 + a1) / (den0 + den1) + b2[lane], 0.f);
}

// K5b: U/V from out2 @ mW1; stored f16. Grid-stride persistent blocks.
__global__ __launch_bounds__(256) void k5b(const float* __restrict__ out2,
                                           const float* __restrict__ mW1,
                                           const float* __restrict__ mb1,
                                           __half* __restrict__ Uh, __half* __restrict__ Vh) {
    __shared__ float Ws[128 * 64];
    __shared__ float o2s[4][64];
    for (int t = threadIdx.x; t < 128 * 64; t += 256) Ws[t] = mW1[t];
    __syncthreads();
    int wid = threadIdx.x >> 6, lane = threadIdx.x & 63;
    for (int n = blockIdx.x * 4 + wid; n < N_NODES; n += gridDim.x * 4) {
        o2s[wid][lane] = out2[n * 64 + lane];
        float au = mb1[lane], av = 0.f;
        #pragma unroll 8
        for (int k = 0; k < 64; k++) {
            float ov = o2s[wid][k];
            au = fmaf(ov, Ws[k * 64 + lane], au);
            av = fmaf(ov, Ws[(64 + k) * 64 + lane], av);
        }
        Uh[n * 64 + lane] = __float2half(au);
        Vh[n * 64 + lane] = __float2half(av);
    }
}

// K7j: edge MLP via f16 MFMA, 32 edges/wave, ORIGINAL edge order:
// reads row/col directly, writes out[e] coalesced. No index plumbing.
__global__ __launch_bounds__(512) void k7j(
    const int* __restrict__ row, const int* __restrict__ col,
    const __half* __restrict__ Uh, const __half* __restrict__ Vh,
    const __half* __restrict__ W2th, const __half* __restrict__ W3th,
    const float* __restrict__ mb2, const float* __restrict__ mb3,
    const float* __restrict__ mW4, const float* __restrict__ mb4,
    float* __restrict__ out)
{
    __shared__ unsigned short Wf[2][4096];
    __shared__ float mbS[3][64];
    const int t = threadIdx.x;
    {
        int mA = t >> 8, kb = (t >> 6) & 3, l = t & 63;
        int src = (mA * 32 + (l & 31)) * 64 + kb * 16 + (l >> 5) * 8;
        *(uint4*)&Wf[0][t * 8] = *(const uint4*)(W2th + src);
        *(uint4*)&Wf[1][t * 8] = *(const uint4*)(W3th + src);
        if (t < 64) mbS[0][t] = mb2[t];
        else if (t < 128) mbS[1][t - 64] = mb3[t - 64];
        else if (t < 192) mbS[2][t - 128] = mW4[t - 128];
    }
    __syncthreads();

    const int wid = t >> 6, lane = t & 63;
    const int tbase = blockIdx.x * 256 + wid * 32;
    const int l31 = lane & 31;
    const int h = lane >> 5;
    const int ksub = h * 8;

    int rA = row[tbase + l31];
    int cA = col[tbase + l31];
    const __half* urow = Uh + (size_t)rA * 64 + ksub;
    const __half* vrow = Vh + (size_t)cA * 64 + ksub;

    f32x16 c2[2];
    #pragma unroll
    for (int mA = 0; mA < 2; mA++)
        #pragma unroll
        for (int q = 0; q < 4; q++) {
            float4 b = *(const float4*)&mbS[0][mA * 32 + 4 * h + q * 8];
            c2[mA][q * 4 + 0] = b.x; c2[mA][q * 4 + 1] = b.y;
            c2[mA][q * 4 + 2] = b.z; c2[mA][q * 4 + 3] = b.w;
        }

    #pragma unroll
    for (int kb = 0; kb < 4; kb++) {
        H8 uvu, vvu, zz;
        uvu.u4 = *(const uint4*)(urow + kb * 16);
        vvu.u4 = *(const uint4*)(vrow + kb * 16);
        {
            half8v s = uvu.v + vvu.v;
            #pragma unroll
            for (int j = 0; j < 8; j++) {
                _Float16 a = s[j];
                zz.v[j] = a > (_Float16)0 ? a : (_Float16)0;
            }
        }
        #pragma unroll
        for (int mA = 0; mA < 2; mA++) {
            const int f = (mA * 4 + kb) * 64 + lane;
            half8v ah = *(const half8v*)&Wf[0][f * 8];
            c2[mA] = __builtin_amdgcn_mfma_f32_32x32x16_f16(ah, zz.v, c2[mA], 0, 0, 0);
        }
    }

    half8v B3[4];
    #pragma unroll
    for (int kbp = 0; kbp < 4; kbp++) {
        const int mAs = kbp >> 1, kbl = kbp & 1;
        half8v t8;
        #pragma unroll
        for (int b = 0; b < 4; b++) {
            float u = fmaxf(c2[mAs][8 * kbl + b], 0.f);
            float v = fmaxf(c2[mAs][8 * kbl + 4 + b], 0.f);
            float su = __shfl_xor(u, 32, 64);
            float sv = __shfl_xor(v, 32, 64);
            t8[b]     = (_Float16)(h ? sv : u);
            t8[4 + b] = (_Float16)(h ? v : su);
        }
        B3[kbp] = t8;
    }

    f32x16 c3[2];
    #pragma unroll
    for (int mA = 0; mA < 2; mA++)
        #pragma unroll
        for (int q = 0; q < 4; q++) {
            float4 b = *(const float4*)&mbS[1][mA * 32 + 4 * h + q * 8];
            c3[mA][q * 4 + 0] = b.x; c3[mA][q * 4 + 1] = b.y;
            c3[mA][q * 4 + 2] = b.z; c3[mA][q * 4 + 3] = b.w;
        }

    #pragma unroll
    for (int kbp = 0; kbp < 4; kbp++) {
        #pragma unroll
        for (int mA = 0; mA < 2; mA++) {
            const int f = (mA * 4 + kbp) * 64 + lane;
            half8v ah = *(const half8v*)&Wf[1][f * 8];
            c3[mA] = __builtin_amdgcn_mfma_f32_32x32x16_f16(ah, B3[kbp], c3[mA], 0, 0, 0);
        }
    }

    float p = 0.f;
    #pragma unroll
    for (int mA = 0; mA < 2; mA++)
        #pragma unroll
        for (int q = 0; q < 4; q++) {
            float4 w4 = *(const float4*)&mbS[2][mA * 32 + 4 * h + q * 8];
            p = fmaf(fmaxf(c3[mA][q * 4 + 0], 0.f), w4.x, p);
            p = fmaf(fmaxf(c3[mA][q * 4 + 1], 0.f), w4.y, p);
            p = fmaf(fmaxf(c3[mA][q * 4 + 2], 0.f), w4.z, p);
            p = fmaf(fmaxf(c3[mA][q * 4 + 3], 0.f), w4.w, p);
        }
    p += __shfl_xor(p, 32, 64);
    if (lane < 32) out[tbase + l31] = p + mb4[0];
}

extern "C" void kernel_launch(void* const* d_in, const int* in_sizes, int n_in,
                              void* d_out, int out_size, void* d_ws, size_t ws_size,
                              hipStream_t stream) {
    const float* x   = (const float*)d_in[0];
    const int*   ei  = (const int*)d_in[1];
    const float* W1  = (const float*)d_in[2];
    const float* as1 = (const float*)d_in[3];
    const float* ad1 = (const float*)d_in[4];
    const float* b1  = (const float*)d_in[5];
    const float* W2  = (const float*)d_in[6];
    const float* as2 = (const float*)d_in[7];
    const float* ad2 = (const float*)d_in[8];
    const float* b2  = (const float*)d_in[9];
    const float* mW1 = (const float*)d_in[10];
    const float* mb1 = (const float*)d_in[11];
    const float* mW2 = (const float*)d_in[12];
    const float* mb2 = (const float*)d_in[13];
    const float* mW3 = (const float*)d_in[14];
    const float* mb3 = (const float*)d_in[15];
    const float* mW4 = (const float*)d_in[16];
    const float* mb4 = (const float*)d_in[17];
    float* out = (float*)d_out;
    const int* row = ei;             // src
    const int* col = ei + N_EDGES;   // dst

    char* w = (char*)d_ws;
    __half*   Uh    = (__half*)w;                     // 6.4 MB, k5b->k7j
    __half*   Vh    = (__half*)(w + 6400000);         // 6.4 MB, k5b->k7j
    float*    out2  = (float*)(w + 12800000);         // 12.8 MB, k5a->k5b
    __half*   h2h   = (__half*)(w + 25600000);        // 6.4 MB, k4n->k5a
    unsigned* ssd   = (unsigned*)(w + 32000000);      // 6.4 MB (CSR order, dst<<16|src)
    unsigned* tmp   = (unsigned*)(w + 38400000);      // 6.4 MB, s_scatter1->k_sort2b
    int*      offp  = (int*)(w + 57800000);           // 0.2 MB + 4
    float*    al_s2 = (float*)(w + 58200064);
    float*    al_d2 = (float*)(w + 58400064);
    int*      bsum  = (int*)(w + 58600064);           // scan temps
    float*    qs    = (float*)(w + 58605056);
    float*    qd    = (float*)(w + 58605184);
    __half*   W2th  = (__half*)(w + 58605312);
    __half*   W3th  = W2th + 4096;                    // 16 KB total
    int*      cnt1  = (int*)(w + 58988992);           // NB1*NBLK*4 = 1.225 MB
    int*      basep1= (int*)(w + 60214000);           // 1.225 MB
    int*      bsumA = (int*)(w + 61439008);           // ~5 KB
    // overlays:
    float*    accx  = (float*)(w + 12800000);         // k3n->k4n (inside out2)
    float*    denb  = (float*)(w + 19200000);
    float*    al_s1 = (float*)(w + 19600000);
    float*    al_d1 = (float*)(w + 20000000);

    k_prep<<<65, 64, 0, stream>>>(W1, as1, ad1, qs, qd, mW2, mW3, W2th, W3th);
    k1n<<<(N_NODES + 255) / 256, 256, 0, stream>>>(x, qs, qd, al_s1, al_d1);
    // per-block level-1 bucket counts (dst>>10)
    s_hist1<<<NBLK, 256, 0, stream>>>(col, cnt1);
    // level-1 bucket bases
    {
        int n1 = NB1 * NBLK;                          // 306250
        int nb1 = (n1 + SCAN_B - 1) / SCAN_B;         // 1197
        int nb2 = (nb1 + SCAN_B - 1) / SCAN_B;        // 5
        g_scan1<<<nb1, SCAN_B, 0, stream>>>(cnt1, basep1, bsumA, n1);
        g_scan1<<<nb2, SCAN_B, 0, stream>>>(bsumA, bsumA, bsum, nb1);
        k_scan2<<<1, SCAN_B, 0, stream>>>(bsum, nb2);
        g_add<<<nb2, SCAN_B, 0, stream>>>(bsumA, bsum, nb1);
        g_add<<<nb1, SCAN_B, 0, stream>>>(basep1, bsumA, n1);
    }
    // hierarchical scatter: edges -> bucket-major tmp (u32) -> per-bucket sort
    s_scatter1<<<NBLK, 256, 0, stream>>>(row, col, basep1, tmp);
    k_sort2b<<<NB1, 1024, 0, stream>>>(tmp, basep1, offp, ssd);
    // layer-1 aggregation (fixed-shift softmax, in-kernel weights)
    k3n<<<N_NODES / 8, 256, 0, stream>>>(x, al_s1, al_d1, offp, ssd, accx, denb);
    k4n<<<768, 256, 0, stream>>>(accx, denb, W1, b1, W2, as2, ad2, h2h, al_s2, al_d2);
    // layer-2 aggregation (fixed-shift softmax, in-kernel weights)
    k5a<<<N_NODES, 64, 0, stream>>>(h2h, al_s2, al_d2, b2, offp, ssd, out2);
    k5b<<<1024, 256, 0, stream>>>(out2, mW1, mb1, Uh, Vh);
    // edge MLP in ORIGINAL edge order: coalesced row/col reads and out writes
    k7j<<<NBLK, 512, 0, stream>>>(row, col, Uh, Vh,
                                  W2th, W3th,
                                  mb2, mb3, mW4, mb4, out);
}

// Round 24
// 292.577 us; speedup vs baseline: 1.5842x; 1.0501x over previous
//
#include <hip/hip_runtime.h>
#include <hip/hip_bf16.h>
#include <hip/hip_fp16.h>
#include <math.h>

#define N_NODES 50000
#define N_EDGES 1600000
#define NEBLK 1563         // ceil(N_EDGES / 1024) hist/scatter blocks
#define NB1 98             // level-1 scatter buckets (dst>>9, 512 dsts each)
#define IN_DIM 16
#define HID 64
#define SM_SHIFT 20.0f     // fixed softmax shift; e <= ~10 with 5-sigma margin

typedef __attribute__((ext_vector_type(8))) _Float16 half8v;
typedef __attribute__((ext_vector_type(16))) float f32x16;

union H8 { uint4 u4; half8v v; };

__device__ __forceinline__ float lrelu(float v) { return v > 0.f ? v : 0.2f * v; }

__device__ __forceinline__ float wave_reduce_sum(float v) {
    #pragma unroll
    for (int off = 32; off > 0; off >>= 1) v += __shfl_down(v, off, 64);
    return v;
}

// k_prep: block 64 = qprep (qs/qd vectors); blocks 0..63 = f16 weight transpose rows
__global__ void k_prep(const float* __restrict__ W1, const float* __restrict__ as1,
                       const float* __restrict__ ad1, float* __restrict__ qs, float* __restrict__ qd,
                       const float* __restrict__ mW2, const float* __restrict__ mW3,
                       __half* __restrict__ W2th, __half* __restrict__ W3th) {
    int t = threadIdx.x;
    if (blockIdx.x == 64) {
        if (t < 32) {
            int i = t >> 1, h = t & 1;
            float s = 0.f, d = 0.f;
            for (int c = 0; c < 64; c++) {
                float w = W1[i * 128 + h * 64 + c];
                s = fmaf(w, as1[h * 64 + c], s);
                d = fmaf(w, ad1[h * 64 + c], d);
            }
            qs[i * 2 + h] = s; qd[i * 2 + h] = d;
        }
    } else {
        int b = blockIdx.x;
        W2th[b * 64 + t] = __float2half(mW2[t * 64 + b]);
        W3th[b * 64 + t] = __float2half(mW3[t * 64 + b]);
    }
}

// k1n: alpha terms per node
__global__ void k1n(const float* __restrict__ x, const float* __restrict__ qs,
                    const float* __restrict__ qd, float* __restrict__ al_s, float* __restrict__ al_d) {
    int n = blockIdx.x * 256 + threadIdx.x;
    if (n >= N_NODES) return;
    float s0 = 0.f, s1 = 0.f, d0 = 0.f, d1 = 0.f;
    #pragma unroll
    for (int i = 0; i < IN_DIM; i++) {
        float xv = x[n * IN_DIM + i];
        s0 = fmaf(xv, qs[i * 2 + 0], s0);
        s1 = fmaf(xv, qs[i * 2 + 1], s1);
        d0 = fmaf(xv, qd[i * 2 + 0], d0);
        d1 = fmaf(xv, qd[i * 2 + 1], d1);
    }
    al_s[n * 2 + 0] = s0; al_s[n * 2 + 1] = s1;
    al_d[n * 2 + 0] = d0; al_d[n * 2 + 1] = d1;
}

#define SCAN_B 256
__global__ void k_scan2(int* __restrict__ bsum, int nblocks) {
    __shared__ int sh[SCAN_B];
    int v = (threadIdx.x < nblocks) ? bsum[threadIdx.x] : 0;
    sh[threadIdx.x] = v;
    __syncthreads();
    for (int o = 1; o < SCAN_B; o <<= 1) {
        int t = (threadIdx.x >= o) ? sh[threadIdx.x - o] : 0;
        __syncthreads();
        sh[threadIdx.x] += t;
        __syncthreads();
    }
    if (threadIdx.x < nblocks) bsum[threadIdx.x] = sh[threadIdx.x] - v;
}

__global__ void g_scan1(const int* __restrict__ in, int* __restrict__ out,
                        int* __restrict__ bsum, int n) {
    __shared__ int sh[SCAN_B];
    int gid = blockIdx.x * SCAN_B + threadIdx.x;
    int v = (gid < n) ? in[gid] : 0;
    sh[threadIdx.x] = v;
    __syncthreads();
    for (int o = 1; o < SCAN_B; o <<= 1) {
        int t = (threadIdx.x >= o) ? sh[threadIdx.x - o] : 0;
        __syncthreads();
        sh[threadIdx.x] += t;
        __syncthreads();
    }
    int incl = sh[threadIdx.x];
    if (gid < n) out[gid] = incl - v;
    if (threadIdx.x == SCAN_B - 1) bsum[blockIdx.x] = incl;
}
__global__ void g_add(int* __restrict__ out, const int* __restrict__ bsum, int n) {
    int gid = blockIdx.x * SCAN_B + threadIdx.x;
    if (gid < n) out[gid] += bsum[blockIdx.x];
}

// ---- hierarchical CSR scatter (u32 payload: dst<<16 | src; 4 edges/thread) ----
__global__ __launch_bounds__(256) void s_hist1(const int* __restrict__ dst,
                                               int* __restrict__ cnt1) {
    __shared__ int c[NB1];
    if (threadIdx.x < NB1) c[threadIdx.x] = 0;
    __syncthreads();
    int base = blockIdx.x * 1024 + threadIdx.x;
    #pragma unroll
    for (int q = 0; q < 4; q++) {
        int e = base + q * 256;
        if (e < N_EDGES) atomicAdd(&c[dst[e] >> 9], 1);
    }
    __syncthreads();
    if (threadIdx.x < NB1) cnt1[threadIdx.x * NEBLK + blockIdx.x] = c[threadIdx.x];
}

__global__ __launch_bounds__(256) void s_scatter1(const int* __restrict__ src,
                                                  const int* __restrict__ dst,
                                                  const int* __restrict__ basep1,
                                                  unsigned* __restrict__ tmp) {
    __shared__ int c[NB1], base[NB1];
    if (threadIdx.x < NB1) c[threadIdx.x] = 0;
    __syncthreads();
    int bstart = blockIdx.x * 1024;
    int rank[4]; unsigned val[4]; int kk[4];
    #pragma unroll
    for (int q = 0; q < 4; q++) {
        int e = bstart + q * 256 + threadIdx.x;
        if (e < N_EDGES) {
            int d = dst[e], s = src[e];
            kk[q] = d >> 9;
            val[q] = ((unsigned)d << 16) | (unsigned)s;
            rank[q] = atomicAdd(&c[kk[q]], 1);
        } else kk[q] = -1;
    }
    __syncthreads();
    if (threadIdx.x < NB1) base[threadIdx.x] = basep1[threadIdx.x * NEBLK + blockIdx.x];
    __syncthreads();
    #pragma unroll
    for (int q = 0; q < 4; q++)
        if (kk[q] >= 0) tmp[base[kk[q]] + rank[q]] = val[q];
}

// k_sort2b: one block per 512-dst bucket. Pass A: LDS deg count; LDS scan -> offp;
// Pass B: scatter to exact CSR slots via LDS cursors. No global atomics.
__global__ __launch_bounds__(1024) void k_sort2b(const unsigned* __restrict__ tmp,
                                                 const int* __restrict__ basep1,
                                                 int* __restrict__ offp,
                                                 unsigned* __restrict__ ssd) {
    __shared__ int cnt[512];
    int b = blockIdx.x, t = threadIdx.x;
    int d0 = b << 9;
    int nd = N_NODES - d0; if (nd > 512) nd = 512;
    if (t < 512) cnt[t] = 0;
    __syncthreads();
    int ebeg = basep1[b * NEBLK];
    int eend = (b == NB1 - 1) ? N_EDGES : basep1[(b + 1) * NEBLK];
    for (int i = ebeg + t; i < eend; i += 1024)
        atomicAdd(&cnt[(tmp[i] >> 16) - d0], 1);
    __syncthreads();
    int v = (t < 512) ? cnt[t] : 0;
    for (int o = 1; o < 512; o <<= 1) {
        int tv = (t >= o && t < 512) ? cnt[t - o] : 0;
        __syncthreads();
        if (t < 512) cnt[t] += tv;
        __syncthreads();
    }
    int cur = ebeg + ((t < 512) ? cnt[t] : 0) - v;   // exclusive prefix -> CSR offset
    if (t < nd) offp[d0 + t] = cur;
    if (b == NB1 - 1 && t == 0) offp[N_NODES] = N_EDGES;
    __syncthreads();
    if (t < 512) cnt[t] = cur;
    __syncthreads();
    for (int i = ebeg + t; i < eend; i += 1024) {
        unsigned lo = tmp[i];
        int pos = atomicAdd(&cnt[(lo >> 16) - d0], 1);
        ssd[pos] = lo;
    }
}

// K3n: layer-1 aggregation, fixed-shift softmax (no max pass).
__global__ void k3n(const float* __restrict__ x, const float* __restrict__ als,
                    const float* __restrict__ ald,
                    const int* __restrict__ off, const unsigned* __restrict__ ssd,
                    float* __restrict__ accx, float* __restrict__ denb) {
    int wid = threadIdx.x >> 6, lane = threadIdx.x & 63;
    int half = lane >> 5, sub = lane & 31, head = sub >> 4, ch = sub & 15;
    int d = blockIdx.x * 8 + wid * 2 + half;
    if (d >= N_NODES) return;
    int beg = off[d], end = off[d + 1];
    float adv = ald[d * 2 + head];
    float es = lrelu(als[d * 2 + head] + adv);
    float ws = __expf(es - SM_SHIFT);
    float den0 = ws, den1 = 0.f;
    float a0 = ws * x[d * IN_DIM + ch], a1 = 0.f;
    const int srcb = (lane & 32) + (head << 4);   // lane holding w for my head, edge t
    for (int c = beg; c < end; c += 16) {
        int nchunk = end - c; if (nchunk > 16) nchunk = 16;
        float wexp = 0.f;
        if ((sub & 15) < nchunk) {
            int s = (int)(ssd[c + (sub & 15)] & 0xffffu);
            wexp = __expf(lrelu(als[s * 2 + head] + adv) - SM_SHIFT);
        }
        if (nchunk == 16) {
            int sv[16];
            #pragma unroll
            for (int t = 0; t < 16; t++) sv[t] = (int)(ssd[c + t] & 0xffffu);
            #pragma unroll
            for (int t = 0; t < 16; t++) {
                float wv = __shfl(wexp, srcb + t, 64);
                float xv = x[sv[t] * IN_DIM + ch];
                if (t & 1) { den1 += wv; a1 = fmaf(wv, xv, a1); }
                else       { den0 += wv; a0 = fmaf(wv, xv, a0); }
            }
        } else {
            for (int t = 0; t < nchunk; t++) {
                float wv = __shfl(wexp, srcb + t, 64);
                int s = (int)(ssd[c + t] & 0xffffu);
                den0 += wv; a0 = fmaf(wv, x[s * IN_DIM + ch], a0);
            }
        }
    }
    accx[d * 32 + sub] = a0 + a1;
    if ((sub & 15) == 0) denb[d * 2 + head] = den0 + den1;
}

// K4n: fused out1-expand then @ W2 -> h2 (f16), al_s2/al_d2. Grid-stride.
__global__ __launch_bounds__(256) void k4n(
    const float* __restrict__ accx, const float* __restrict__ denb,
    const float* __restrict__ W1, const float* __restrict__ b1,
    const float* __restrict__ W2, const float* __restrict__ as2, const float* __restrict__ ad2,
    __half* __restrict__ h2h, float* __restrict__ al_s, float* __restrict__ al_d) {
    __shared__ float W1s[16 * 128];
    __shared__ float W2s[128 * 64];
    __shared__ float st[4][160];
    for (int t = threadIdx.x; t < 16 * 128; t += 256) W1s[t] = W1[t];
    for (int t = threadIdx.x; t < 128 * 64; t += 256) W2s[t] = W2[t];
    __syncthreads();
    int wid = threadIdx.x >> 6, lane = threadIdx.x & 63;
    for (int n = blockIdx.x * 4 + wid; n < N_NODES; n += gridDim.x * 4) {
        if (lane < 32) st[wid][lane] = accx[n * 32 + lane];
        float den0 = denb[n * 2], den1 = denb[n * 2 + 1];
        float ta = 0.f, tb = 0.f;
        #pragma unroll
        for (int i = 0; i < 16; i++) {
            ta = fmaf(st[wid][i],      W1s[i * 128 + lane],      ta);
            tb = fmaf(st[wid][16 + i], W1s[i * 128 + 64 + lane], tb);
        }
        ta = fmaxf(ta / den0 + b1[lane], 0.f);
        tb = fmaxf(tb / den1 + b1[64 + lane], 0.f);
        st[wid][32 + lane] = ta;
        st[wid][96 + lane] = tb;
        float acc = 0.f;
        #pragma unroll 8
        for (int k = 0; k < 128; k++) acc = fmaf(st[wid][32 + k], W2s[k * 64 + lane], acc);
        h2h[n * 64 + lane] = __float2half(acc);
        float ps = wave_reduce_sum(acc * as2[lane]);
        float pd = wave_reduce_sum(acc * ad2[lane]);
        if (lane == 0) { al_s[n] = ps; al_d[n] = pd; }
    }
}

// K5a: layer-2 aggregation, fixed-shift softmax (no max pass).
__global__ __launch_bounds__(64) void k5a(
    const __half* __restrict__ h2h, const float* __restrict__ als, const float* __restrict__ ald,
    const float* __restrict__ b2, const int* __restrict__ off, const unsigned* __restrict__ ssd,
    float* __restrict__ out2) {
    __shared__ float wbuf[64];
    int d = blockIdx.x;
    int lane = threadIdx.x;
    int beg = off[d], end = off[d + 1];
    float adv = ald[d];
    float es = lrelu(als[d] + adv);
    float ws = __expf(es - SM_SHIFT);
    float den0 = ws, den1 = 0.f;
    float a0 = ws * __half2float(h2h[d * 64 + lane]), a1 = 0.f;
    for (int c = beg; c < end; c += 64) {
        int idx = c + lane;
        if (idx < end) {
            int s = (int)(ssd[idx] & 0xffffu);
            wbuf[lane] = __expf(lrelu(als[s] + adv) - SM_SHIFT);
        }
        int nchunk = end - c; if (nchunk > 64) nchunk = 64;
        int t = 0;
        for (; t + 7 < nchunk; t += 8) {
            int sv[8]; float wv[8], vv[8];
            #pragma unroll
            for (int q = 0; q < 8; q++) sv[q] = (int)(ssd[c + t + q] & 0xffffu);
            #pragma unroll
            for (int q = 0; q < 8; q++) wv[q] = wbuf[t + q];
            #pragma unroll
            for (int q = 0; q < 8; q++) vv[q] = __half2float(h2h[sv[q] * 64 + lane]);
            den0 += wv[0]; a0 = fmaf(wv[0], vv[0], a0);
            den1 += wv[1]; a1 = fmaf(wv[1], vv[1], a1);
            den0 += wv[2]; a0 = fmaf(wv[2], vv[2], a0);
            den1 += wv[3]; a1 = fmaf(wv[3], vv[3], a1);
            den0 += wv[4]; a0 = fmaf(wv[4], vv[4], a0);
            den1 += wv[5]; a1 = fmaf(wv[5], vv[5], a1);
            den0 += wv[6]; a0 = fmaf(wv[6], vv[6], a0);
            den1 += wv[7]; a1 = fmaf(wv[7], vv[7], a1);
        }
        for (; t < nchunk; t++) {
            int s = (int)(ssd[c + t] & 0xffffu);
            float wv = wbuf[t];
            den0 += wv; a0 = fmaf(wv, __half2float(h2h[s * 64 + lane]), a0);
        }
    }
    out2[d * 64 + lane] = fmaxf((a0 + a1) / (den0 + den1) + b2[lane], 0.f);
}

// K5b: U/V from out2 @ mW1; stored f16. Grid-stride persistent blocks.
__global__ __launch_bounds__(256) void k5b(const float* __restrict__ out2,
                                           const float* __restrict__ mW1,
                                           const float* __restrict__ mb1,
                                           __half* __restrict__ Uh, __half* __restrict__ Vh) {
    __shared__ float Ws[128 * 64];
    __shared__ float o2s[4][64];
    for (int t = threadIdx.x; t < 128 * 64; t += 256) Ws[t] = mW1[t];
    __syncthreads();
    int wid = threadIdx.x >> 6, lane = threadIdx.x & 63;
    for (int n = blockIdx.x * 4 + wid; n < N_NODES; n += gridDim.x * 4) {
        o2s[wid][lane] = out2[n * 64 + lane];
        float au = mb1[lane], av = 0.f;
        #pragma unroll 8
        for (int k = 0; k < 64; k++) {
            float ov = o2s[wid][k];
            au = fmaf(ov, Ws[k * 64 + lane], au);
            av = fmaf(ov, Ws[(64 + k) * 64 + lane], av);
        }
        Uh[n * 64 + lane] = __float2half(au);
        Vh[n * 64 + lane] = __float2half(av);
    }
}

// K7j: edge MLP via f16 MFMA, 32 edges/wave, ORIGINAL edge order:
// reads row/col directly, writes out[e] coalesced. No index plumbing.
__global__ __launch_bounds__(512) void k7j(
    const int* __restrict__ row, const int* __restrict__ col,
    const __half* __restrict__ Uh, const __half* __restrict__ Vh,
    const __half* __restrict__ W2th, const __half* __restrict__ W3th,
    const float* __restrict__ mb2, const float* __restrict__ mb3,
    const float* __restrict__ mW4, const float* __restrict__ mb4,
    float* __restrict__ out)
{
    __shared__ unsigned short Wf[2][4096];
    __shared__ float mbS[3][64];
    const int t = threadIdx.x;
    {
        int mA = t >> 8, kb = (t >> 6) & 3, l = t & 63;
        int src = (mA * 32 + (l & 31)) * 64 + kb * 16 + (l >> 5) * 8;
        *(uint4*)&Wf[0][t * 8] = *(const uint4*)(W2th + src);
        *(uint4*)&Wf[1][t * 8] = *(const uint4*)(W3th + src);
        if (t < 64) mbS[0][t] = mb2[t];
        else if (t < 128) mbS[1][t - 64] = mb3[t - 64];
        else if (t < 192) mbS[2][t - 128] = mW4[t - 128];
    }
    __syncthreads();

    const int wid = t >> 6, lane = t & 63;
    const int tbase = blockIdx.x * 256 + wid * 32;
    const int l31 = lane & 31;
    const int h = lane >> 5;
    const int ksub = h * 8;

    int rA = row[tbase + l31];
    int cA = col[tbase + l31];
    const __half* urow = Uh + (size_t)rA * 64 + ksub;
    const __half* vrow = Vh + (size_t)cA * 64 + ksub;

    f32x16 c2[2];
    #pragma unroll
    for (int mA = 0; mA < 2; mA++)
        #pragma unroll
        for (int q = 0; q < 4; q++) {
            float4 b = *(const float4*)&mbS[0][mA * 32 + 4 * h + q * 8];
            c2[mA][q * 4 + 0] = b.x; c2[mA][q * 4 + 1] = b.y;
            c2[mA][q * 4 + 2] = b.z; c2[mA][q * 4 + 3] = b.w;
        }

    #pragma unroll
    for (int kb = 0; kb < 4; kb++) {
        H8 uvu, vvu, zz;
        uvu.u4 = *(const uint4*)(urow + kb * 16);
        vvu.u4 = *(const uint4*)(vrow + kb * 16);
        {
            half8v s = uvu.v + vvu.v;
            #pragma unroll
            for (int j = 0; j < 8; j++) {
                _Float16 a = s[j];
                zz.v[j] = a > (_Float16)0 ? a : (_Float16)0;
            }
        }
        #pragma unroll
        for (int mA = 0; mA < 2; mA++) {
            const int f = (mA * 4 + kb) * 64 + lane;
            half8v ah = *(const half8v*)&Wf[0][f * 8];
            c2[mA] = __builtin_amdgcn_mfma_f32_32x32x16_f16(ah, zz.v, c2[mA], 0, 0, 0);
        }
    }

    half8v B3[4];
    #pragma unroll
    for (int kbp = 0; kbp < 4; kbp++) {
        const int mAs = kbp >> 1, kbl = kbp & 1;
        half8v t8;
        #pragma unroll
        for (int b = 0; b < 4; b++) {
            float u = fmaxf(c2[mAs][8 * kbl + b], 0.f);
            float v = fmaxf(c2[mAs][8 * kbl + 4 + b], 0.f);
            float su = __shfl_xor(u, 32, 64);
            float sv = __shfl_xor(v, 32, 64);
            t8[b]     = (_Float16)(h ? sv : u);
            t8[4 + b] = (_Float16)(h ? v : su);
        }
        B3[kbp] = t8;
    }

    f32x16 c3[2];
    #pragma unroll
    for (int mA = 0; mA < 2; mA++)
        #pragma unroll
        for (int q = 0; q < 4; q++) {
            float4 b = *(const float4*)&mbS[1][mA * 32 + 4 * h + q * 8];
            c3[mA][q * 4 + 0] = b.x; c3[mA][q * 4 + 1] = b.y;
            c3[mA][q * 4 + 2] = b.z; c3[mA][q * 4 + 3] = b.w;
        }

    #pragma unroll
    for (int kbp = 0; kbp < 4; kbp++) {
        #pragma unroll
        for (int mA = 0; mA < 2; mA++) {
            const int f = (mA * 4 + kbp) * 64 + lane;
            half8v ah = *(const half8v*)&Wf[1][f * 8];
            c3[mA] = __builtin_amdgcn_mfma_f32_32x32x16_f16(ah, B3[kbp], c3[mA], 0, 0, 0);
        }
    }

    float p = 0.f;
    #pragma unroll
    for (int mA = 0; mA < 2; mA++)
        #pragma unroll
        for (int q = 0; q < 4; q++) {
            float4 w4 = *(const float4*)&mbS[2][mA * 32 + 4 * h + q * 8];
            p = fmaf(fmaxf(c3[mA][q * 4 + 0], 0.f), w4.x, p);
            p = fmaf(fmaxf(c3[mA][q * 4 + 1], 0.f), w4.y, p);
            p = fmaf(fmaxf(c3[mA][q * 4 + 2], 0.f), w4.z, p);
            p = fmaf(fmaxf(c3[mA][q * 4 + 3], 0.f), w4.w, p);
        }
    p += __shfl_xor(p, 32, 64);
    if (lane < 32) out[tbase + l31] = p + mb4[0];
}

extern "C" void kernel_launch(void* const* d_in, const int* in_sizes, int n_in,
                              void* d_out, int out_size, void* d_ws, size_t ws_size,
                              hipStream_t stream) {
    const float* x   = (const float*)d_in[0];
    const int*   ei  = (const int*)d_in[1];
    const float* W1  = (const float*)d_in[2];
    const float* as1 = (const float*)d_in[3];
    const float* ad1 = (const float*)d_in[4];
    const float* b1  = (const float*)d_in[5];
    const float* W2  = (const float*)d_in[6];
    const float* as2 = (const float*)d_in[7];
    const float* ad2 = (const float*)d_in[8];
    const float* b2  = (const float*)d_in[9];
    const float* mW1 = (const float*)d_in[10];
    const float* mb1 = (const float*)d_in[11];
    const float* mW2 = (const float*)d_in[12];
    const float* mb2 = (const float*)d_in[13];
    const float* mW3 = (const float*)d_in[14];
    const float* mb3 = (const float*)d_in[15];
    const float* mW4 = (const float*)d_in[16];
    const float* mb4 = (const float*)d_in[17];
    float* out = (float*)d_out;
    const int* row = ei;             // src
    const int* col = ei + N_EDGES;   // dst

    char* w = (char*)d_ws;
    __half*   Uh    = (__half*)w;                     // 6.4 MB, k5b->k7j
    __half*   Vh    = (__half*)(w + 6400000);         // 6.4 MB, k5b->k7j
    float*    out2  = (float*)(w + 12800000);         // 12.8 MB, k5a->k5b
    __half*   h2h   = (__half*)(w + 25600000);        // 6.4 MB, k4n->k5a
    unsigned* ssd   = (unsigned*)(w + 32000000);      // 6.4 MB (CSR order, dst<<16|src)
    unsigned* tmp   = (unsigned*)(w + 38400000);      // 6.4 MB, s_scatter1->k_sort2b
    int*      offp  = (int*)(w + 57800000);           // 0.2 MB + 4
    float*    al_s2 = (float*)(w + 58200064);
    float*    al_d2 = (float*)(w + 58400064);
    int*      bsum  = (int*)(w + 58600064);           // scan temps
    float*    qs    = (float*)(w + 58605056);
    float*    qd    = (float*)(w + 58605184);
    __half*   W2th  = (__half*)(w + 58605312);
    __half*   W3th  = W2th + 4096;                    // 16 KB total
    int*      cnt1  = (int*)(w + 58988992);           // NB1*NEBLK*4 = 613 KB
    int*      basep1= (int*)(w + 59989992);           // 613 KB
    int*      bsumA = (int*)(w + 60990992);           // ~2.4 KB
    // overlays:
    float*    accx  = (float*)(w + 12800000);         // k3n->k4n (inside out2)
    float*    denb  = (float*)(w + 19200000);
    float*    al_s1 = (float*)(w + 19600000);
    float*    al_d1 = (float*)(w + 20000000);

    k_prep<<<65, 64, 0, stream>>>(W1, as1, ad1, qs, qd, mW2, mW3, W2th, W3th);
    k1n<<<(N_NODES + 255) / 256, 256, 0, stream>>>(x, qs, qd, al_s1, al_d1);
    // per-block level-1 bucket counts (dst>>9, 4 edges/thread)
    s_hist1<<<NEBLK, 256, 0, stream>>>(col, cnt1);
    // level-1 bucket bases
    {
        int n1 = NB1 * NEBLK;                         // 153174
        int nb1 = (n1 + SCAN_B - 1) / SCAN_B;         // 599
        int nb2 = (nb1 + SCAN_B - 1) / SCAN_B;        // 3
        g_scan1<<<nb1, SCAN_B, 0, stream>>>(cnt1, basep1, bsumA, n1);
        g_scan1<<<nb2, SCAN_B, 0, stream>>>(bsumA, bsumA, bsum, nb1);
        k_scan2<<<1, SCAN_B, 0, stream>>>(bsum, nb2);
        g_add<<<nb2, SCAN_B, 0, stream>>>(bsumA, bsum, nb1);
        g_add<<<nb1, SCAN_B, 0, stream>>>(basep1, bsumA, n1);
    }
    // hierarchical scatter: edges -> bucket-major tmp (u32) -> per-bucket sort
    s_scatter1<<<NEBLK, 256, 0, stream>>>(row, col, basep1, tmp);
    k_sort2b<<<NB1, 1024, 0, stream>>>(tmp, basep1, offp, ssd);
    // layer-1 aggregation (fixed-shift softmax, in-kernel weights)
    k3n<<<N_NODES / 8, 256, 0, stream>>>(x, al_s1, al_d1, offp, ssd, accx, denb);
    k4n<<<768, 256, 0, stream>>>(accx, denb, W1, b1, W2, as2, ad2, h2h, al_s2, al_d2);
    // layer-2 aggregation (fixed-shift softmax, in-kernel weights)
    k5a<<<N_NODES, 64, 0, stream>>>(h2h, al_s2, al_d2, b2, offp, ssd, out2);
    k5b<<<1024, 256, 0, stream>>>(out2, mW1, mb1, Uh, Vh);
    // edge MLP in ORIGINAL edge order: coalesced row/col reads and out writes
    k7j<<<N_EDGES / 256, 512, 0, stream>>>(row, col, Uh, Vh,
                                           W2th, W3th,
                                           mb2, mb3, mW4, mb4, out);
}